// Round 7
// baseline (2550.938 us; speedup 1.0000x reference)
//
#include <hip/hip_runtime.h>
#include <cstdint>

// R7: fix R6 fallback-path aliasing bug (prot GEMM overwrote outbM before mol LN
// read it -> Output 0 garbage). Fallback now: mol gemm->LN->pool THEN prot chain.
// BIG2 merged-GEMM path unchanged (disjoint buffers), gate lowered to 323MB.
// Learned: ws_size in [240.5, 330) MB.

constexpr int H_HEADS = 3;
constexpr float NEG_SLOPE = 0.2f;
constexpr float LN_EPS = 1e-5f;
constexpr int N_MOL = 40000, E_MOL = 80000, C_MOL = 512, G_MOL = 512;
constexpr int N_PROT = 8000, E_PROT = 64000, C_PROT = 1280, G_PROT = 32;
constexpr int LAYERS = 4;
constexpr int MPAD_MOL = 40064;
constexpr int MPAD_PROT = 8064;

typedef unsigned short u16;
typedef __attribute__((ext_vector_type(8))) short short8v;
typedef __attribute__((ext_vector_type(4))) unsigned short ushort4v;
typedef __attribute__((ext_vector_type(4))) float f32x4;

__device__ __forceinline__ float bf2f(u16 s) {
    union { unsigned u; float f; } v; v.u = ((unsigned)s) << 16; return v.f;
}
__device__ __forceinline__ u16 f2bf(float f) {
    union { float f; unsigned u; } v; v.f = f;
    return (u16)((v.u + 0x7fffu + ((v.u >> 16) & 1u)) >> 16);
}

__device__ __forceinline__ void g2l16(const void* g, void* l) {
    __builtin_amdgcn_global_load_lds((const __attribute__((address_space(1))) void*)g,
                                     (__attribute__((address_space(3))) void*)l, 16, 0, 0);
}

// ---------------- small utility kernels ----------------

__global__ void set_int_kernel(int* p, int v, int n) {
    int i = blockIdx.x * blockDim.x + threadIdx.x;
    if (i < n) p[i] = v;
}

__global__ void zero_f32_kernel(float* p, int n) {
    int i = blockIdx.x * blockDim.x + threadIdx.x;
    if (i < n) p[i] = 0.f;
}

__global__ void copy_int_kernel(const int* __restrict__ s, int* __restrict__ d, int n) {
    int i = blockIdx.x * blockDim.x + threadIdx.x;
    if (i < n) d[i] = s[i];
}

__global__ void hist_kernel(const int* __restrict__ keys, int n, int* __restrict__ cnt) {
    int i = blockIdx.x * blockDim.x + threadIdx.x;
    if (i < n) atomicAdd(&cnt[keys[i]], 1);
}

__global__ void scan_kernel(const int* __restrict__ in, int* __restrict__ out, int n) {
    __shared__ int sums[1024];
    const int t = threadIdx.x;
    const int chunk = (n + 1023) / 1024;
    const int start = t * chunk;
    const int end = min(start + chunk, n);
    int s = 0;
    for (int i = start; i < end; ++i) s += in[i];
    sums[t] = s;
    __syncthreads();
    if (t == 0) {
        int acc = 0;
        for (int i = 0; i < 1024; ++i) { int v = sums[i]; sums[i] = acc; acc += v; }
        out[n] = acc;
    }
    __syncthreads();
    int acc = sums[t];
    for (int i = start; i < end; ++i) { out[i] = acc; acc += in[i]; }
}

__global__ void fill_self_kernel(int* __restrict__ pos, int* __restrict__ srcl, int n) {
    int i = blockIdx.x * blockDim.x + threadIdx.x;
    if (i < n) { int slot = atomicAdd(&pos[i], 1); srcl[slot] = i; }
}

__global__ void fill_edge_kernel(const int* __restrict__ src, const int* __restrict__ dst, int e,
                                 int* __restrict__ pos, int* __restrict__ srcl) {
    int i = blockIdx.x * blockDim.x + threadIdx.x;
    if (i < e) { int slot = atomicAdd(&pos[dst[i]], 1); srcl[slot] = src[i]; }
}

__global__ void f32_to_bf16(const float* __restrict__ in, u16* __restrict__ out, int n) {
    int i = blockIdx.x * blockDim.x + threadIdx.x;
    if (i < n) out[i] = f2bf(in[i]);
}

// ---------------- embedding mean -> bf16 ----------------

__global__ void embed_mean_kernel(const int* __restrict__ drug_x, const float* __restrict__ emb,
                                  u16* __restrict__ out) {
    const int n = blockIdx.x;
    __shared__ int idx[9];
    if (threadIdx.x < 9) idx[threadIdx.x] = drug_x[n * 9 + threadIdx.x];
    __syncthreads();
    const int c = threadIdx.x;
    float s = 0.f;
#pragma unroll
    for (int t = 0; t < 9; ++t) s += emb[(size_t)idx[t] * C_MOL + c];
    out[(size_t)n * C_MOL + c] = f2bf(s * (1.f / 9.f));
}

// ---------------- fold attention vectors (hoisted) ----------------

template <int CIN, int COUT>
__global__ __launch_bounds__(256) void fold_attn(const float* __restrict__ W,
                                                 const float* __restrict__ asrc,
                                                 const float* __restrict__ adst,
                                                 float* __restrict__ wsrc, float* __restrict__ wdst) {
    const int i = blockIdx.x;
    const int tid = threadIdx.x;
    __shared__ float rb[8];
    const float* Wr = W + (size_t)i * (H_HEADS * COUT);
    for (int h = 0; h < H_HEADS; ++h) {
        float ss = 0.f, sd = 0.f;
        for (int c = tid; c < COUT; c += 256) {
            const float w = Wr[h * COUT + c];
            ss += w * asrc[h * COUT + c];
            sd += w * adst[h * COUT + c];
        }
        for (int o = 32; o; o >>= 1) { ss += __shfl_down(ss, o); sd += __shfl_down(sd, o); }
        if ((tid & 63) == 0) { rb[tid >> 6] = ss; rb[4 + (tid >> 6)] = sd; }
        __syncthreads();
        if (tid == 0) {
            wsrc[h * CIN + i] = rb[0] + rb[1] + rb[2] + rb[3];
            wdst[h * CIN + i] = rb[4] + rb[5] + rb[6] + rb[7];
        }
        __syncthreads();
    }
}

// ---------------- weight transpose+convert: Wt[n*3C + h*C + k] ----------------

__global__ __launch_bounds__(256) void transposeW(const float* __restrict__ W, u16* __restrict__ Wt,
                                                  int COUT, size_t headStride, int ldn) {
    __shared__ float t[32][33];
    const int h = blockIdx.z;
    const int n0 = blockIdx.x * 32, k0 = blockIdx.y * 32;
    const int tx = threadIdx.x & 31, ty = threadIdx.x >> 5;
#pragma unroll
    for (int q = 0; q < 4; ++q)
        t[ty + q * 8][tx] = W[(size_t)(k0 + ty + q * 8) * (H_HEADS * COUT) + h * COUT + n0 + tx];
    __syncthreads();
#pragma unroll
    for (int q = 0; q < 4; ++q)
        Wt[(size_t)h * headStride + (size_t)(n0 + ty + q * 8) * ldn + k0 + tx] =
            f2bf(t[tx][ty + q * 8]);
}

// ---------------- attention logits (layer 0 only) ----------------

template <int C>
__global__ void attn_logits(const u16* __restrict__ x, const float* __restrict__ wsrc,
                            const float* __restrict__ wdst, float* __restrict__ als,
                            float* __restrict__ ald) {
    constexpr int PER = C / 64;
    const int n = blockIdx.x, lane = threadIdx.x;
    const u16* xr = x + (size_t)n * C + lane * PER;
    float xv[PER];
#pragma unroll
    for (int i = 0; i < PER; i += 4) {
        const ushort4v v = *(const ushort4v*)(xr + i);
        xv[i] = bf2f(v.x); xv[i + 1] = bf2f(v.y); xv[i + 2] = bf2f(v.z); xv[i + 3] = bf2f(v.w);
    }
    for (int h = 0; h < H_HEADS; ++h) {
        const float* ws = wsrc + h * C + lane * PER;
        const float* wd = wdst + h * C + lane * PER;
        float ss = 0.f, sd = 0.f;
#pragma unroll
        for (int i = 0; i < PER; i += 4) {
            const float4 a = *(const float4*)(ws + i);
            const float4 b = *(const float4*)(wd + i);
            ss += xv[i] * a.x + xv[i + 1] * a.y + xv[i + 2] * a.z + xv[i + 3] * a.w;
            sd += xv[i] * b.x + xv[i + 1] * b.y + xv[i + 2] * b.z + xv[i + 3] * b.w;
        }
        for (int o = 32; o; o >>= 1) { ss += __shfl_down(ss, o); sd += __shfl_down(sd, o); }
        if (lane == 0) { als[n * H_HEADS + h] = ss; ald[n * H_HEADS + h] = sd; }
    }
}

// ---------------- fused alpha + aggregate (mol): wave per node ----------------

__global__ __launch_bounds__(256) void agg_alpha_mol(const u16* __restrict__ x,
                                                     const float* __restrict__ als,
                                                     const float* __restrict__ ald,
                                                     const int* __restrict__ indptr,
                                                     const int* __restrict__ srcl,
                                                     u16* __restrict__ agg) {
    const int wv = threadIdx.x >> 6, lane = threadIdx.x & 63;
    const int n = blockIdx.x * 4 + wv;
    const int beg = indptr[n], end = indptr[n + 1];
    float m = -1e30f, zi = 0.f;
    if (lane < H_HEADS) {
        const float ad = ald[n * H_HEADS + lane];
        for (int e = beg; e < end; ++e) {
            float v = als[srcl[e] * H_HEADS + lane] + ad;
            v = v >= 0.f ? v : NEG_SLOPE * v;
            m = fmaxf(m, v);
        }
        float z = 0.f;
        for (int e = beg; e < end; ++e) {
            float v = als[srcl[e] * H_HEADS + lane] + ad;
            v = v >= 0.f ? v : NEG_SLOPE * v;
            z += __expf(v - m);
        }
        zi = 1.f / (z + 1e-16f);
    }
    const float m0 = __shfl(m, 0), m1 = __shfl(m, 1), m2 = __shfl(m, 2);
    const float z0 = __shfl(zi, 0), z1 = __shfl(zi, 1), z2 = __shfl(zi, 2);
    const float ad0 = ald[n * H_HEADS + 0], ad1 = ald[n * H_HEADS + 1], ad2 = ald[n * H_HEADS + 2];
    float acc[H_HEADS][8];
#pragma unroll
    for (int h = 0; h < H_HEADS; ++h)
#pragma unroll
        for (int j = 0; j < 8; ++j) acc[h][j] = 0.f;
    for (int e = beg; e < end; ++e) {
        const int s = srcl[e];
        float v0 = als[s * H_HEADS + 0] + ad0; v0 = v0 >= 0.f ? v0 : NEG_SLOPE * v0;
        float v1 = als[s * H_HEADS + 1] + ad1; v1 = v1 >= 0.f ? v1 : NEG_SLOPE * v1;
        float v2 = als[s * H_HEADS + 2] + ad2; v2 = v2 >= 0.f ? v2 : NEG_SLOPE * v2;
        const float a0 = __expf(v0 - m0) * z0;
        const float a1 = __expf(v1 - m1) * z1;
        const float a2 = __expf(v2 - m2) * z2;
        const short8v row = *(const short8v*)(x + (size_t)s * C_MOL + lane * 8);
#pragma unroll
        for (int j = 0; j < 8; ++j) {
            const float f = bf2f((u16)row[j]);
            acc[0][j] += a0 * f; acc[1][j] += a1 * f; acc[2][j] += a2 * f;
        }
    }
    u16* o = agg + (size_t)n * (3 * C_MOL) + lane * 8;
#pragma unroll
    for (int h = 0; h < H_HEADS; ++h) {
        short8v r;
#pragma unroll
        for (int j = 0; j < 8; ++j) r[j] = (short)f2bf(acc[h][j]);
        *(short8v*)(o + h * C_MOL) = r;
    }
}

// ---------------- fused alpha + aggregate (prot): block per node, 320 thr ----------------

__global__ __launch_bounds__(320) void agg_alpha_prot(const u16* __restrict__ x,
                                                      const float* __restrict__ als,
                                                      const float* __restrict__ ald,
                                                      const int* __restrict__ indptr,
                                                      const int* __restrict__ srcl,
                                                      u16* __restrict__ agg) {
    const int n = blockIdx.x, tid = threadIdx.x;
    const int beg = indptr[n], end = indptr[n + 1];
    __shared__ float mz[6];
    if (tid < H_HEADS) {
        const float ad = ald[n * H_HEADS + tid];
        float m = -1e30f;
        for (int e = beg; e < end; ++e) {
            float v = als[srcl[e] * H_HEADS + tid] + ad;
            v = v >= 0.f ? v : NEG_SLOPE * v;
            m = fmaxf(m, v);
        }
        float z = 0.f;
        for (int e = beg; e < end; ++e) {
            float v = als[srcl[e] * H_HEADS + tid] + ad;
            v = v >= 0.f ? v : NEG_SLOPE * v;
            z += __expf(v - m);
        }
        mz[tid] = m;
        mz[3 + tid] = 1.f / (z + 1e-16f);
    }
    __syncthreads();
    const float m0 = mz[0], m1 = mz[1], m2 = mz[2];
    const float z0 = mz[3], z1 = mz[4], z2 = mz[5];
    const float ad0 = ald[n * H_HEADS + 0], ad1 = ald[n * H_HEADS + 1], ad2 = ald[n * H_HEADS + 2];
    float acc[H_HEADS][4];
#pragma unroll
    for (int h = 0; h < H_HEADS; ++h)
#pragma unroll
        for (int j = 0; j < 4; ++j) acc[h][j] = 0.f;
    for (int e = beg; e < end; ++e) {
        const int s = srcl[e];
        float v0 = als[s * H_HEADS + 0] + ad0; v0 = v0 >= 0.f ? v0 : NEG_SLOPE * v0;
        float v1 = als[s * H_HEADS + 1] + ad1; v1 = v1 >= 0.f ? v1 : NEG_SLOPE * v1;
        float v2 = als[s * H_HEADS + 2] + ad2; v2 = v2 >= 0.f ? v2 : NEG_SLOPE * v2;
        const float a0 = __expf(v0 - m0) * z0;
        const float a1 = __expf(v1 - m1) * z1;
        const float a2 = __expf(v2 - m2) * z2;
        const ushort4v v = *(const ushort4v*)(x + (size_t)s * C_PROT + tid * 4);
        const float f0 = bf2f(v.x), f1 = bf2f(v.y), f2 = bf2f(v.z), f3 = bf2f(v.w);
        acc[0][0] += a0 * f0; acc[0][1] += a0 * f1; acc[0][2] += a0 * f2; acc[0][3] += a0 * f3;
        acc[1][0] += a1 * f0; acc[1][1] += a1 * f1; acc[1][2] += a1 * f2; acc[1][3] += a1 * f3;
        acc[2][0] += a2 * f0; acc[2][1] += a2 * f1; acc[2][2] += a2 * f2; acc[2][3] += a2 * f3;
    }
    u16* o = agg + (size_t)n * (3 * C_PROT) + tid * 4;
#pragma unroll
    for (int h = 0; h < H_HEADS; ++h) {
        ushort4v r;
        r.x = f2bf(acc[h][0]); r.y = f2bf(acc[h][1]); r.z = f2bf(acc[h][2]); r.w = f2bf(acc[h][3]);
        *(ushort4v*)(o + h * C_PROT) = r;
    }
}

// ---------------- GEMM: 128xBN tile, BK=64, dual-problem, XCD-swizzled ----------------

template <int BN>
__global__ __launch_bounds__(BN * 2) void gemm_tile(
    const u16* __restrict__ A0, const u16* __restrict__ B0, u16* __restrict__ C0,
    int N0, int K0, int nx0, int g0,
    const u16* __restrict__ A1, const u16* __restrict__ B1, u16* __restrict__ C1,
    int N1, int K1, int nx1) {
    constexpr int NT = BN * 2;
    constexpr int NW = NT / 64;
    constexpr int NCW = BN / 64;
    constexpr int APW = 128 / NW;
    constexpr int QA = APW / 8;
    constexpr int QB = (BN / NW) / 8;
    constexpr int SEPI = BN + 8;
    constexpr int LDSZ = (8192 + BN * 64) > (64 * SEPI) ? (8192 + BN * 64) : (64 * SEPI);
    __shared__ u16 lds[LDSZ];
    const int tid = threadIdx.x;
    const int w = tid >> 6, l = tid & 63;
    const int wr = w / NCW, wc = w % NCW;
    const int nwg = gridDim.x;
    const int q = nwg >> 3, r = nwg & 7;
    const int xcd = blockIdx.x & 7, idx = blockIdx.x >> 3;
    int wgid = (xcd < r ? xcd * (q + 1) : r * (q + 1) + (xcd - r) * q) + idx;
    const u16 *A, *Bt;
    u16* Cout;
    int N, K, nxch;
    if (wgid < g0) { A = A0; Bt = B0; Cout = C0; N = N0; K = K0; nxch = nx0; }
    else { wgid -= g0; A = A1; Bt = B1; Cout = C1; N = N1; K = K1; nxch = nx1; }
    const int nx = wgid % nxch, my = wgid / nxch;
    const size_t bm = (size_t)my * 128, bn = (size_t)nx * BN;

    const f32x4 zf = {0.f, 0.f, 0.f, 0.f};
    f32x4 acc[4][4];
#pragma unroll
    for (int i = 0; i < 4; ++i)
#pragma unroll
        for (int j = 0; j < 4; ++j) acc[i][j] = zf;

    const int sseg = (l & 7) ^ (l >> 3);
    const u16* Ab = A + (bm + w * APW + (l >> 3)) * (size_t)K + sseg * 8;
    const u16* Bb = Bt + (bn + w * (BN / NW) + (l >> 3)) * (size_t)K + sseg * 8;

    for (int k0 = 0; k0 < K; k0 += 64) {
#pragma unroll
        for (int qq = 0; qq < QA; ++qq)
            g2l16(Ab + k0 + (size_t)qq * 8 * K, lds + (w * QA + qq) * 512);
#pragma unroll
        for (int qq = 0; qq < QB; ++qq)
            g2l16(Bb + k0 + (size_t)qq * 8 * K, lds + 8192 + (w * QB + qq) * 512);
        __syncthreads();
#pragma unroll
        for (int kk = 0; kk < 2; ++kk) {
            const int gs = kk * 4 + (l >> 4);
            const int sg = (gs ^ (l & 7)) * 8;
            short8v af[4], bf8[4];
#pragma unroll
            for (int fm = 0; fm < 4; ++fm) {
                const int row = wr * 64 + fm * 16 + (l & 15);
                af[fm] = *(const short8v*)&lds[row * 64 + sg];
            }
#pragma unroll
            for (int fn = 0; fn < 4; ++fn) {
                const int row = wc * 64 + fn * 16 + (l & 15);
                bf8[fn] = *(const short8v*)&lds[8192 + row * 64 + sg];
            }
#pragma unroll
            for (int fm = 0; fm < 4; ++fm)
#pragma unroll
                for (int fn = 0; fn < 4; ++fn)
                    acc[fm][fn] = __builtin_amdgcn_mfma_f32_16x16x32_bf16(af[fm], bf8[fn],
                                                                          acc[fm][fn], 0, 0, 0);
        }
        __syncthreads();
    }

    constexpr int TPR = NT / 64;
#pragma unroll
    for (int half = 0; half < 2; ++half) {
        if (wr == half) {
#pragma unroll
            for (int fm = 0; fm < 4; ++fm)
#pragma unroll
                for (int fn = 0; fn < 4; ++fn) {
                    const int col = wc * 64 + fn * 16 + (l & 15);
#pragma unroll
                    for (int rr = 0; rr < 4; ++rr)
                        lds[(fm * 16 + (l >> 4) * 4 + rr) * SEPI + col] = f2bf(acc[fm][fn][rr]);
                }
        }
        __syncthreads();
        const int lrow = tid / TPR, lseg = tid % TPR;
        u16* Crow = Cout + (bm + half * 64 + lrow) * (size_t)N + bn + lseg * 32;
        const u16* Lr = lds + lrow * SEPI + lseg * 32;
#pragma unroll
        for (int ii = 0; ii < 4; ++ii)
            *(float4*)(Crow + ii * 8) = *(const float4*)(Lr + ii * 8);
        __syncthreads();
    }
}

// ---------------- fused scale + bias + LayerNorm (+ next-layer logits) ----------------

template <int C, int LOGITS>
__global__ __launch_bounds__(256) void ln_kernel(const u16* __restrict__ acc,
                                                 const float* __restrict__ bias,
                                                 const float* __restrict__ g,
                                                 const float* __restrict__ b,
                                                 u16* __restrict__ xout,
                                                 const float* __restrict__ wsrc_n,
                                                 const float* __restrict__ wdst_n,
                                                 float* __restrict__ als, float* __restrict__ ald) {
    constexpr int PER = C / 256;
    const int n = blockIdx.x, tid = threadIdx.x;
    const u16* ar = acc + (size_t)n * C;
    float vals[PER];
    float s1 = 0.f, s2 = 0.f;
    constexpr float invH = 1.f / (float)H_HEADS;
#pragma unroll
    for (int i = 0; i < PER; ++i) {
        const int c = i * 256 + tid;
        const float v = bf2f(ar[c]) * invH + bias[c];
        vals[i] = v;
        s1 += v;
        s2 += v * v;
    }
    __shared__ float red[2][4];
    __shared__ float red2[4][6];
    for (int o = 32; o; o >>= 1) { s1 += __shfl_down(s1, o); s2 += __shfl_down(s2, o); }
    if ((tid & 63) == 0) { red[0][tid >> 6] = s1; red[1][tid >> 6] = s2; }
    __syncthreads();
    const float t1 = red[0][0] + red[0][1] + red[0][2] + red[0][3];
    const float t2 = red[1][0] + red[1][1] + red[1][2] + red[1][3];
    const float mu = t1 / C;
    const float var = t2 / C - mu * mu;
    const float rstd = rsqrtf(var + LN_EPS);
    u16* xr = xout + (size_t)n * C;
    float ps0 = 0.f, ps1 = 0.f, ps2 = 0.f, pd0 = 0.f, pd1 = 0.f, pd2 = 0.f;
#pragma unroll
    for (int i = 0; i < PER; ++i) {
        const int c = i * 256 + tid;
        const u16 xq16 = f2bf((vals[i] - mu) * rstd * g[c] + b[c]);
        xr[c] = xq16;
        if (LOGITS) {
            const float xq = bf2f(xq16);
            ps0 += xq * wsrc_n[0 * C + c]; pd0 += xq * wdst_n[0 * C + c];
            ps1 += xq * wsrc_n[1 * C + c]; pd1 += xq * wdst_n[1 * C + c];
            ps2 += xq * wsrc_n[2 * C + c]; pd2 += xq * wdst_n[2 * C + c];
        }
    }
    if (LOGITS) {
        for (int o = 32; o; o >>= 1) {
            ps0 += __shfl_down(ps0, o); ps1 += __shfl_down(ps1, o); ps2 += __shfl_down(ps2, o);
            pd0 += __shfl_down(pd0, o); pd1 += __shfl_down(pd1, o); pd2 += __shfl_down(pd2, o);
        }
        __syncthreads();
        if ((tid & 63) == 0) {
            const int wv = tid >> 6;
            red2[wv][0] = ps0; red2[wv][1] = ps1; red2[wv][2] = ps2;
            red2[wv][3] = pd0; red2[wv][4] = pd1; red2[wv][5] = pd2;
        }
        __syncthreads();
        if (tid == 0) {
#pragma unroll
            for (int h = 0; h < H_HEADS; ++h) {
                als[n * H_HEADS + h] = red2[0][h] + red2[1][h] + red2[2][h] + red2[3][h];
                ald[n * H_HEADS + h] =
                    red2[0][3 + h] + red2[1][3 + h] + red2[2][3 + h] + red2[3][3 + h];
            }
        }
    }
}

// ---------------- segmented atomic mean-pool ----------------

template <int C, int S>
__global__ void pool_atomic(const u16* __restrict__ x, const int* __restrict__ goff,
                            float* __restrict__ out, int layer) {
    const int g = blockIdx.x, seg = blockIdx.y;
    const int beg = goff[g], end = goff[g + 1];
    const int len = end - beg;
    const int s0 = beg + (len * seg) / S;
    const int s1 = beg + (len * (seg + 1)) / S;
    if (s0 >= s1) return;
    const float inv = 1.f / fmaxf((float)len, 1.f);
    const int tid = threadIdx.x;
    float a0 = 0.f, a1 = 0.f, a2 = 0.f, a3 = 0.f;
    for (int n = s0; n < s1; ++n) {
        const ushort4v v = *(const ushort4v*)(x + (size_t)n * C + tid * 4);
        a0 += bf2f(v.x); a1 += bf2f(v.y); a2 += bf2f(v.z); a3 += bf2f(v.w);
    }
    float* o = out + ((size_t)g * (LAYERS + 1) + layer) * C + tid * 4;
    atomicAdd(o + 0, a0 * inv);
    atomicAdd(o + 1, a1 * inv);
    atomicAdd(o + 2, a2 * inv);
    atomicAdd(o + 3, a3 * inv);
}

// ---------------- launch ----------------

extern "C" void kernel_launch(void* const* d_in, const int* in_sizes, int n_in, void* d_out,
                              int out_size, void* d_ws, size_t ws_size, hipStream_t stream) {
    const int* drug_x      = (const int*)d_in[0];
    const int* mol_ei      = (const int*)d_in[1];
    const int* mol_batch   = (const int*)d_in[2];
    const float* prot_in   = (const float*)d_in[3];
    const int* prot_ei     = (const int*)d_in[4];
    const int* prot_batch  = (const int*)d_in[5];
    const float* emb       = (const float*)d_in[6];
    const float* mol_W     = (const float*)d_in[7];
    const float* mol_asrc  = (const float*)d_in[8];
    const float* mol_adst  = (const float*)d_in[9];
    const float* mol_bias  = (const float*)d_in[10];
    const float* mol_lng   = (const float*)d_in[11];
    const float* mol_lnb   = (const float*)d_in[12];
    const float* prot_W    = (const float*)d_in[13];
    const float* prot_asrc = (const float*)d_in[14];
    const float* prot_adst = (const float*)d_in[15];
    const float* prot_bias = (const float*)d_in[16];
    const float* prot_lng  = (const float*)d_in[17];
    const float* prot_lnb  = (const float*)d_in[18];

    if (ws_size < (size_t)240500000) return;            // proven lower bound
    const bool BIG2 = ws_size >= (size_t)323000000;     // merged-GEMM path (~322.3MB used)

    char* base = (char*)d_ws;
    size_t off = 0;
    auto alloc = [&](size_t bytes) -> void* {
        void* r = base + off;
        off = (off + bytes + 255) & ~(size_t)255;
        return r;
    };
    u16* x_mol  = (u16*)alloc((size_t)N_MOL * C_MOL * 2);
    u16* x_prot = (u16*)alloc((size_t)N_PROT * C_PROT * 2);
    u16* aggM   = (u16*)alloc((size_t)3 * MPAD_MOL * C_MOL * 2);
    u16* outbM  = (u16*)alloc((size_t)MPAD_MOL * C_MOL * 2);
    u16* WtP    = (u16*)alloc((size_t)H_HEADS * C_PROT * C_PROT * 2);
    u16 *aggP, *outbP, *WtM;
    if (BIG2) {
        aggP  = (u16*)alloc((size_t)3 * MPAD_PROT * C_PROT * 2);
        outbP = (u16*)alloc((size_t)MPAD_PROT * C_PROT * 2);
        WtM   = (u16*)alloc((size_t)H_HEADS * C_MOL * C_MOL * 2);
    } else {
        aggP = aggM; outbP = outbM; WtM = WtP;   // aliased: ordering matters below!
    }
    float* wsrcM = (float*)alloc((size_t)LAYERS * H_HEADS * C_MOL * 4);
    float* wdstM = (float*)alloc((size_t)LAYERS * H_HEADS * C_MOL * 4);
    float* wsrcP = (float*)alloc((size_t)LAYERS * H_HEADS * C_PROT * 4);
    float* wdstP = (float*)alloc((size_t)LAYERS * H_HEADS * C_PROT * 4);
    float* alsM = (float*)alloc((size_t)N_MOL * H_HEADS * 4);
    float* aldM = (float*)alloc((size_t)N_MOL * H_HEADS * 4);
    float* alsP = (float*)alloc((size_t)N_PROT * H_HEADS * 4);
    float* aldP = (float*)alloc((size_t)N_PROT * H_HEADS * 4);
    int* mol_indptr  = (int*)alloc((N_MOL + 1) * 4);
    int* mol_pos     = (int*)alloc(N_MOL * 4);
    int* mol_srcl    = (int*)alloc((E_MOL + N_MOL) * 4);
    int* prot_indptr = (int*)alloc((N_PROT + 1) * 4);
    int* prot_pos    = (int*)alloc(N_PROT * 4);
    int* prot_srcl   = (int*)alloc((E_PROT + N_PROT) * 4);
    int* cnt         = (int*)alloc(N_MOL * 4);
    int* mol_goff    = (int*)alloc((G_MOL + 1) * 4);
    int* prot_goff   = (int*)alloc((G_PROT + 1) * 4);
    int* gcnt        = (int*)alloc(G_MOL * 4);

    float* out_mol  = (float*)d_out;
    float* out_prot = (float*)d_out + (size_t)G_MOL * (LAYERS + 1) * C_MOL;

    zero_f32_kernel<<<(out_size + 255) / 256, 256, 0, stream>>>((float*)d_out, out_size);

    // ---- CSR (incoming lists incl. self loops) ----
    set_int_kernel<<<(N_MOL + 255) / 256, 256, 0, stream>>>(cnt, 1, N_MOL);
    hist_kernel<<<(E_MOL + 255) / 256, 256, 0, stream>>>(mol_ei + E_MOL, E_MOL, cnt);
    scan_kernel<<<1, 1024, 0, stream>>>(cnt, mol_indptr, N_MOL);
    copy_int_kernel<<<(N_MOL + 255) / 256, 256, 0, stream>>>(mol_indptr, mol_pos, N_MOL);
    fill_self_kernel<<<(N_MOL + 255) / 256, 256, 0, stream>>>(mol_pos, mol_srcl, N_MOL);
    fill_edge_kernel<<<(E_MOL + 255) / 256, 256, 0, stream>>>(mol_ei, mol_ei + E_MOL, E_MOL, mol_pos,
                                                              mol_srcl);
    set_int_kernel<<<(N_PROT + 255) / 256, 256, 0, stream>>>(cnt, 1, N_PROT);
    hist_kernel<<<(E_PROT + 255) / 256, 256, 0, stream>>>(prot_ei + E_PROT, E_PROT, cnt);
    scan_kernel<<<1, 1024, 0, stream>>>(cnt, prot_indptr, N_PROT);
    copy_int_kernel<<<(N_PROT + 255) / 256, 256, 0, stream>>>(prot_indptr, prot_pos, N_PROT);
    fill_self_kernel<<<(N_PROT + 255) / 256, 256, 0, stream>>>(prot_pos, prot_srcl, N_PROT);
    fill_edge_kernel<<<(E_PROT + 255) / 256, 256, 0, stream>>>(prot_ei, prot_ei + E_PROT, E_PROT,
                                                               prot_pos, prot_srcl);

    // ---- graph offsets ----
    set_int_kernel<<<(G_MOL + 255) / 256, 256, 0, stream>>>(gcnt, 0, G_MOL);
    hist_kernel<<<(N_MOL + 255) / 256, 256, 0, stream>>>(mol_batch, N_MOL, gcnt);
    scan_kernel<<<1, 1024, 0, stream>>>(gcnt, mol_goff, G_MOL);
    set_int_kernel<<<(G_PROT + 255) / 256, 256, 0, stream>>>(gcnt, 0, G_PROT);
    hist_kernel<<<(N_PROT + 255) / 256, 256, 0, stream>>>(prot_batch, N_PROT, gcnt);
    scan_kernel<<<1, 1024, 0, stream>>>(gcnt, prot_goff, G_PROT);

    // ---- fold attention vectors for all layers ----
    for (int l = 0; l < LAYERS; ++l) {
        fold_attn<C_MOL, C_MOL><<<C_MOL, 256, 0, stream>>>(
            mol_W + (size_t)l * C_MOL * (H_HEADS * C_MOL),
            mol_asrc + (size_t)l * H_HEADS * C_MOL, mol_adst + (size_t)l * H_HEADS * C_MOL,
            wsrcM + (size_t)l * H_HEADS * C_MOL, wdstM + (size_t)l * H_HEADS * C_MOL);
        fold_attn<C_PROT, C_PROT><<<C_PROT, 256, 0, stream>>>(
            prot_W + (size_t)l * C_PROT * (H_HEADS * C_PROT),
            prot_asrc + (size_t)l * H_HEADS * C_PROT, prot_adst + (size_t)l * H_HEADS * C_PROT,
            wsrcP + (size_t)l * H_HEADS * C_PROT, wdstP + (size_t)l * H_HEADS * C_PROT);
    }

    // ---- layer-0 features + logits ----
    f32_to_bf16<<<(N_PROT * C_PROT + 255) / 256, 256, 0, stream>>>(prot_in, x_prot, N_PROT * C_PROT);
    embed_mean_kernel<<<N_MOL, C_MOL, 0, stream>>>(drug_x, emb, x_mol);
    pool_atomic<C_MOL, 8><<<dim3(G_MOL, 8), C_MOL / 4, 0, stream>>>(x_mol, mol_goff, out_mol, 0);
    pool_atomic<C_PROT, 64><<<dim3(G_PROT, 64), C_PROT / 4, 0, stream>>>(x_prot, prot_goff,
                                                                         out_prot, 0);
    attn_logits<C_MOL><<<N_MOL, 64, 0, stream>>>(x_mol, wsrcM, wdstM, alsM, aldM);
    attn_logits<C_PROT><<<N_PROT, 64, 0, stream>>>(x_prot, wsrcP, wdstP, alsP, aldP);

    const int gMol = (C_MOL / 256) * (MPAD_MOL / 128);       // 626
    const int gProt256 = (C_PROT / 256) * (MPAD_PROT / 128); // 315
    const int gProt128 = (C_PROT / 128) * (MPAD_PROT / 128); // 630

    for (int l = 0; l < LAYERS; ++l) {
        const int last = (l == LAYERS - 1);
        const float* WlM = mol_W + (size_t)l * C_MOL * (H_HEADS * C_MOL);
        const float* WlP = prot_W + (size_t)l * C_PROT * (H_HEADS * C_PROT);

        if (BIG2) {
            // disjoint buffers: safe to batch both problems into one GEMM
            transposeW<<<dim3(C_MOL / 32, C_MOL / 32, H_HEADS), 256, 0, stream>>>(
                WlM, WtM, C_MOL, (size_t)C_MOL, 3 * C_MOL);
            transposeW<<<dim3(C_PROT / 32, C_PROT / 32, H_HEADS), 256, 0, stream>>>(
                WlP, WtP, C_PROT, (size_t)C_PROT, 3 * C_PROT);
            agg_alpha_mol<<<N_MOL / 4, 256, 0, stream>>>(x_mol, alsM, aldM, mol_indptr, mol_srcl,
                                                         aggM);
            agg_alpha_prot<<<N_PROT, 320, 0, stream>>>(x_prot, alsP, aldP, prot_indptr, prot_srcl,
                                                       aggP);
            gemm_tile<256><<<gMol + gProt256, 512, 0, stream>>>(
                aggM, WtM, outbM, C_MOL, 3 * C_MOL, C_MOL / 256, gMol,
                aggP, WtP, outbP, C_PROT, 3 * C_PROT, C_PROT / 256);
            if (last) {
                ln_kernel<C_MOL, 0><<<N_MOL, 256, 0, stream>>>(
                    outbM, mol_bias + (size_t)l * C_MOL, mol_lng + (size_t)l * C_MOL,
                    mol_lnb + (size_t)l * C_MOL, x_mol, nullptr, nullptr, nullptr, nullptr);
                ln_kernel<C_PROT, 0><<<N_PROT, 256, 0, stream>>>(
                    outbP, prot_bias + (size_t)l * C_PROT, prot_lng + (size_t)l * C_PROT,
                    prot_lnb + (size_t)l * C_PROT, x_prot, nullptr, nullptr, nullptr, nullptr);
            } else {
                ln_kernel<C_MOL, 1><<<N_MOL, 256, 0, stream>>>(
                    outbM, mol_bias + (size_t)l * C_MOL, mol_lng + (size_t)l * C_MOL,
                    mol_lnb + (size_t)l * C_MOL, x_mol,
                    wsrcM + (size_t)(l + 1) * H_HEADS * C_MOL,
                    wdstM + (size_t)(l + 1) * H_HEADS * C_MOL, alsM, aldM);
                ln_kernel<C_PROT, 1><<<N_PROT, 256, 0, stream>>>(
                    outbP, prot_bias + (size_t)l * C_PROT, prot_lng + (size_t)l * C_PROT,
                    prot_lnb + (size_t)l * C_PROT, x_prot,
                    wsrcP + (size_t)(l + 1) * H_HEADS * C_PROT,
                    wdstP + (size_t)(l + 1) * H_HEADS * C_PROT, alsP, aldP);
            }
        } else {
            // ALIASED buffers (aggP==aggM, outbP==outbM, WtM==WtP):
            // must fully consume mol results before the prot chain overwrites them.
            transposeW<<<dim3(C_MOL / 32, C_MOL / 32, H_HEADS), 256, 0, stream>>>(
                WlM, WtM, C_MOL, (size_t)C_MOL, 3 * C_MOL);
            agg_alpha_mol<<<N_MOL / 4, 256, 0, stream>>>(x_mol, alsM, aldM, mol_indptr, mol_srcl,
                                                         aggM);
            gemm_tile<256><<<gMol, 512, 0, stream>>>(
                aggM, WtM, outbM, C_MOL, 3 * C_MOL, C_MOL / 256, gMol,
                aggM, WtM, outbM, C_MOL, 3 * C_MOL, C_MOL / 256);
            if (last)
                ln_kernel<C_MOL, 0><<<N_MOL, 256, 0, stream>>>(
                    outbM, mol_bias + (size_t)l * C_MOL, mol_lng + (size_t)l * C_MOL,
                    mol_lnb + (size_t)l * C_MOL, x_mol, nullptr, nullptr, nullptr, nullptr);
            else
                ln_kernel<C_MOL, 1><<<N_MOL, 256, 0, stream>>>(
                    outbM, mol_bias + (size_t)l * C_MOL, mol_lng + (size_t)l * C_MOL,
                    mol_lnb + (size_t)l * C_MOL, x_mol,
                    wsrcM + (size_t)(l + 1) * H_HEADS * C_MOL,
                    wdstM + (size_t)(l + 1) * H_HEADS * C_MOL, alsM, aldM);
            pool_atomic<C_MOL, 8><<<dim3(G_MOL, 8), C_MOL / 4, 0, stream>>>(x_mol, mol_goff,
                                                                            out_mol, l + 1);
            // prot chain (overwrites aliased Wt/agg/outb AFTER mol consumed them)
            transposeW<<<dim3(C_PROT / 32, C_PROT / 32, H_HEADS), 256, 0, stream>>>(
                WlP, WtP, C_PROT, (size_t)C_PROT, 3 * C_PROT);
            agg_alpha_prot<<<N_PROT, 320, 0, stream>>>(x_prot, alsP, aldP, prot_indptr, prot_srcl,
                                                       aggP);
            gemm_tile<128><<<gProt128, 256, 0, stream>>>(
                aggP, WtP, outbP, C_PROT, 3 * C_PROT, C_PROT / 128, gProt128,
                aggP, WtP, outbP, C_PROT, 3 * C_PROT, C_PROT / 128);
            if (last)
                ln_kernel<C_PROT, 0><<<N_PROT, 256, 0, stream>>>(
                    outbP, prot_bias + (size_t)l * C_PROT, prot_lng + (size_t)l * C_PROT,
                    prot_lnb + (size_t)l * C_PROT, x_prot, nullptr, nullptr, nullptr, nullptr);
            else
                ln_kernel<C_PROT, 1><<<N_PROT, 256, 0, stream>>>(
                    outbP, prot_bias + (size_t)l * C_PROT, prot_lng + (size_t)l * C_PROT,
                    prot_lnb + (size_t)l * C_PROT, x_prot,
                    wsrcP + (size_t)(l + 1) * H_HEADS * C_PROT,
                    wdstP + (size_t)(l + 1) * H_HEADS * C_PROT, alsP, aldP);
            pool_atomic<C_PROT, 64><<<dim3(G_PROT, 64), C_PROT / 4, 0, stream>>>(
                x_prot, prot_goff, out_prot, l + 1);
        }
        if (BIG2) {
            pool_atomic<C_MOL, 8><<<dim3(G_MOL, 8), C_MOL / 4, 0, stream>>>(x_mol, mol_goff,
                                                                            out_mol, l + 1);
            pool_atomic<C_PROT, 64><<<dim3(G_PROT, 64), C_PROT / 4, 0, stream>>>(
                x_prot, prot_goff, out_prot, l + 1);
        }
    }
}

// Round 8
// 2390.690 us; speedup vs baseline: 1.0670x; 1.0670x over previous
//
#include <hip/hip_runtime.h>
#include <cstdint>

// R8: revert prot GEMM to BN=256 (R5-proven; BN=128 was -12%), un-fuse alpha
// (R6 fusion recomputed 3 exp per thread per edge), fuse fold_attn into
// transposeW (halves W f32 reads; scheduled after the GEMM consuming prev Wt),
// in-place LN (outb eliminated; GEMM row-guarded to Mreal). ws ~201MB.

constexpr int H_HEADS = 3;
constexpr float NEG_SLOPE = 0.2f;
constexpr float LN_EPS = 1e-5f;
constexpr int N_MOL = 40000, E_MOL = 80000, C_MOL = 512, G_MOL = 512;
constexpr int N_PROT = 8000, E_PROT = 64000, C_PROT = 1280, G_PROT = 32;
constexpr int LAYERS = 4;
constexpr int MPAD_MOL = 40064;
constexpr int MPAD_PROT = 8064;

typedef unsigned short u16;
typedef __attribute__((ext_vector_type(8))) short short8v;
typedef __attribute__((ext_vector_type(4))) unsigned short ushort4v;
typedef __attribute__((ext_vector_type(4))) float f32x4;

__device__ __forceinline__ float bf2f(u16 s) {
    union { unsigned u; float f; } v; v.u = ((unsigned)s) << 16; return v.f;
}
__device__ __forceinline__ u16 f2bf(float f) {
    union { float f; unsigned u; } v; v.f = f;
    return (u16)((v.u + 0x7fffu + ((v.u >> 16) & 1u)) >> 16);
}

__device__ __forceinline__ void g2l16(const void* g, void* l) {
    __builtin_amdgcn_global_load_lds((const __attribute__((address_space(1))) void*)g,
                                     (__attribute__((address_space(3))) void*)l, 16, 0, 0);
}

// ---------------- small utility kernels ----------------

__global__ void set_int_kernel(int* p, int v, int n) {
    int i = blockIdx.x * blockDim.x + threadIdx.x;
    if (i < n) p[i] = v;
}

__global__ void zero_f32_kernel(float* p, int n) {
    int i = blockIdx.x * blockDim.x + threadIdx.x;
    if (i < n) p[i] = 0.f;
}

__global__ void copy_int_kernel(const int* __restrict__ s, int* __restrict__ d, int n) {
    int i = blockIdx.x * blockDim.x + threadIdx.x;
    if (i < n) d[i] = s[i];
}

__global__ void hist_kernel(const int* __restrict__ keys, int n, int* __restrict__ cnt) {
    int i = blockIdx.x * blockDim.x + threadIdx.x;
    if (i < n) atomicAdd(&cnt[keys[i]], 1);
}

__global__ void scan_kernel(const int* __restrict__ in, int* __restrict__ out, int n) {
    __shared__ int sums[1024];
    const int t = threadIdx.x;
    const int chunk = (n + 1023) / 1024;
    const int start = t * chunk;
    const int end = min(start + chunk, n);
    int s = 0;
    for (int i = start; i < end; ++i) s += in[i];
    sums[t] = s;
    __syncthreads();
    if (t == 0) {
        int acc = 0;
        for (int i = 0; i < 1024; ++i) { int v = sums[i]; sums[i] = acc; acc += v; }
        out[n] = acc;
    }
    __syncthreads();
    int acc = sums[t];
    for (int i = start; i < end; ++i) { out[i] = acc; acc += in[i]; }
}

__global__ void fill_self_kernel(int* __restrict__ pos, int* __restrict__ srcl, int n) {
    int i = blockIdx.x * blockDim.x + threadIdx.x;
    if (i < n) { int slot = atomicAdd(&pos[i], 1); srcl[slot] = i; }
}

__global__ void fill_edge_kernel(const int* __restrict__ src, const int* __restrict__ dst, int e,
                                 int* __restrict__ pos, int* __restrict__ srcl) {
    int i = blockIdx.x * blockDim.x + threadIdx.x;
    if (i < e) { int slot = atomicAdd(&pos[dst[i]], 1); srcl[slot] = src[i]; }
}

__global__ void f32_to_bf16(const float* __restrict__ in, u16* __restrict__ out, int n) {
    int i = blockIdx.x * blockDim.x + threadIdx.x;
    if (i < n) out[i] = f2bf(in[i]);
}

// ---------------- embedding mean -> bf16 ----------------

__global__ void embed_mean_kernel(const int* __restrict__ drug_x, const float* __restrict__ emb,
                                  u16* __restrict__ out) {
    const int n = blockIdx.x;
    __shared__ int idx[9];
    if (threadIdx.x < 9) idx[threadIdx.x] = drug_x[n * 9 + threadIdx.x];
    __syncthreads();
    const int c = threadIdx.x;
    float s = 0.f;
#pragma unroll
    for (int t = 0; t < 9; ++t) s += emb[(size_t)idx[t] * C_MOL + c];
    out[(size_t)n * C_MOL + c] = f2bf(s * (1.f / 9.f));
}

// ---------------- fused transpose + fold: Wt[n*ldn + h*C + k]; wsrc/wdst += W.a ----------------
// Reads each W element ONCE for both jobs. wsrc/wdst must be pre-zeroed.

__global__ __launch_bounds__(256) void transfold(const float* __restrict__ W, u16* __restrict__ Wt,
                                                 const float* __restrict__ asrc,
                                                 const float* __restrict__ adst,
                                                 float* __restrict__ wsrc, float* __restrict__ wdst,
                                                 int CIN, int COUT, size_t headStride, int ldn) {
    __shared__ float t[32][33];
    __shared__ float rs[8][33], rd[8][33];
    const int h = blockIdx.z;
    const int n0 = blockIdx.x * 32, k0 = blockIdx.y * 32;
    const int tx = threadIdx.x & 31, ty = threadIdx.x >> 5;
#pragma unroll
    for (int q = 0; q < 4; ++q)
        t[ty + q * 8][tx] = W[(size_t)(k0 + ty + q * 8) * (H_HEADS * COUT) + h * COUT + n0 + tx];
    __syncthreads();
    // transposed bf16 store
#pragma unroll
    for (int q = 0; q < 4; ++q)
        Wt[(size_t)h * headStride + (size_t)(n0 + ty + q * 8) * ldn + k0 + tx] =
            f2bf(t[tx][ty + q * 8]);
    // fold partials: thread (tx,ty) handles k=k0+tx, n in {ty, ty+8, ty+16, ty+24}
    float ps = 0.f, pd = 0.f;
    const float* as = asrc + h * COUT + n0;
    const float* ad = adst + h * COUT + n0;
#pragma unroll
    for (int q = 0; q < 4; ++q) {
        const float w = t[tx][ty + q * 8];
        ps += w * as[ty + q * 8];
        pd += w * ad[ty + q * 8];
    }
    rs[ty][tx] = ps;
    rd[ty][tx] = pd;
    __syncthreads();
    if (ty == 0) {
        float s = 0.f, d = 0.f;
#pragma unroll
        for (int j = 0; j < 8; ++j) { s += rs[j][tx]; d += rd[j][tx]; }
        atomicAdd(&wsrc[h * CIN + k0 + tx], s);
        atomicAdd(&wdst[h * CIN + k0 + tx], d);
    }
}

// ---------------- attention logits (layer 0 only) ----------------

template <int C>
__global__ void attn_logits(const u16* __restrict__ x, const float* __restrict__ wsrc,
                            const float* __restrict__ wdst, float* __restrict__ als,
                            float* __restrict__ ald) {
    constexpr int PER = C / 64;
    const int n = blockIdx.x, lane = threadIdx.x;
    const u16* xr = x + (size_t)n * C + lane * PER;
    float xv[PER];
#pragma unroll
    for (int i = 0; i < PER; i += 4) {
        const ushort4v v = *(const ushort4v*)(xr + i);
        xv[i] = bf2f(v.x); xv[i + 1] = bf2f(v.y); xv[i + 2] = bf2f(v.z); xv[i + 3] = bf2f(v.w);
    }
    for (int h = 0; h < H_HEADS; ++h) {
        const float* ws = wsrc + h * C + lane * PER;
        const float* wd = wdst + h * C + lane * PER;
        float ss = 0.f, sd = 0.f;
#pragma unroll
        for (int i = 0; i < PER; i += 4) {
            const float4 a = *(const float4*)(ws + i);
            const float4 b = *(const float4*)(wd + i);
            ss += xv[i] * a.x + xv[i + 1] * a.y + xv[i + 2] * a.z + xv[i + 3] * a.w;
            sd += xv[i] * b.x + xv[i + 1] * b.y + xv[i + 2] * b.z + xv[i + 3] * b.w;
        }
        for (int o = 32; o; o >>= 1) { ss += __shfl_down(ss, o); sd += __shfl_down(sd, o); }
        if (lane == 0) { als[n * H_HEADS + h] = ss; ald[n * H_HEADS + h] = sd; }
    }
}

// ---------------- segment softmax: one thread per (node, head) ----------------

__global__ void alpha_kernel2(const float* __restrict__ als, const float* __restrict__ ald,
                              const int* __restrict__ indptr, const int* __restrict__ srcl,
                              float* __restrict__ alphaw, int n_nodes) {
    const int t = blockIdx.x * blockDim.x + threadIdx.x;
    const int n = t / H_HEADS, h = t - n * H_HEADS;
    if (n >= n_nodes) return;
    const int beg = indptr[n], end = indptr[n + 1];
    const float ad = ald[n * H_HEADS + h];
    float m = -1e30f;
    for (int e = beg; e < end; ++e) {
        float v = als[srcl[e] * H_HEADS + h] + ad;
        v = v >= 0.f ? v : NEG_SLOPE * v;
        m = fmaxf(m, v);
    }
    float z = 0.f;
    for (int e = beg; e < end; ++e) {
        float v = als[srcl[e] * H_HEADS + h] + ad;
        v = v >= 0.f ? v : NEG_SLOPE * v;
        z += __expf(v - m);
    }
    const float zi = 1.f / (z + 1e-16f);
    for (int e = beg; e < end; ++e) {
        float v = als[srcl[e] * H_HEADS + h] + ad;
        v = v >= 0.f ? v : NEG_SLOPE * v;
        alphaw[e * H_HEADS + h] = __expf(v - m) * zi;
    }
}

// ---------------- mol aggregation: wave per node, 16B loads ----------------

__global__ __launch_bounds__(256) void aggregate_mol(const u16* __restrict__ x,
                                                     const float* __restrict__ alphaw,
                                                     const int* __restrict__ indptr,
                                                     const int* __restrict__ srcl,
                                                     u16* __restrict__ agg) {
    const int wv = threadIdx.x >> 6, lane = threadIdx.x & 63;
    const int n = blockIdx.x * 4 + wv;
    const int beg = indptr[n], end = indptr[n + 1];
    float acc[H_HEADS][8];
#pragma unroll
    for (int h = 0; h < H_HEADS; ++h)
#pragma unroll
        for (int j = 0; j < 8; ++j) acc[h][j] = 0.f;
    for (int e = beg; e < end; ++e) {
        const float a0 = alphaw[e * H_HEADS + 0];
        const float a1 = alphaw[e * H_HEADS + 1];
        const float a2 = alphaw[e * H_HEADS + 2];
        const short8v row = *(const short8v*)(x + (size_t)srcl[e] * C_MOL + lane * 8);
#pragma unroll
        for (int j = 0; j < 8; ++j) {
            const float f = bf2f((u16)row[j]);
            acc[0][j] += a0 * f; acc[1][j] += a1 * f; acc[2][j] += a2 * f;
        }
    }
    u16* o = agg + (size_t)n * (3 * C_MOL) + lane * 8;
#pragma unroll
    for (int h = 0; h < H_HEADS; ++h) {
        short8v r;
#pragma unroll
        for (int j = 0; j < 8; ++j) r[j] = (short)f2bf(acc[h][j]);
        *(short8v*)(o + h * C_MOL) = r;
    }
}

// ---------------- prot aggregation: block C/4 = 320 threads per node ----------------

template <int C>
__global__ void aggregate_all3(const u16* __restrict__ x, const float* __restrict__ alphaw,
                               const int* __restrict__ indptr, const int* __restrict__ srcl,
                               u16* __restrict__ agg) {
    const int n = blockIdx.x, tid = threadIdx.x;
    const int beg = indptr[n], end = indptr[n + 1];
    float acc[H_HEADS][4];
#pragma unroll
    for (int h = 0; h < H_HEADS; ++h)
#pragma unroll
        for (int j = 0; j < 4; ++j) acc[h][j] = 0.f;
    for (int e = beg; e < end; ++e) {
        const float a0 = alphaw[e * H_HEADS + 0];
        const float a1 = alphaw[e * H_HEADS + 1];
        const float a2 = alphaw[e * H_HEADS + 2];
        const ushort4v v = *(const ushort4v*)(x + (size_t)srcl[e] * C + tid * 4);
        const float f0 = bf2f(v.x), f1 = bf2f(v.y), f2 = bf2f(v.z), f3 = bf2f(v.w);
        acc[0][0] += a0 * f0; acc[0][1] += a0 * f1; acc[0][2] += a0 * f2; acc[0][3] += a0 * f3;
        acc[1][0] += a1 * f0; acc[1][1] += a1 * f1; acc[1][2] += a1 * f2; acc[1][3] += a1 * f3;
        acc[2][0] += a2 * f0; acc[2][1] += a2 * f1; acc[2][2] += a2 * f2; acc[2][3] += a2 * f3;
    }
    u16* o = agg + (size_t)n * (3 * C) + tid * 4;
#pragma unroll
    for (int h = 0; h < H_HEADS; ++h) {
        ushort4v r;
        r.x = f2bf(acc[h][0]); r.y = f2bf(acc[h][1]); r.z = f2bf(acc[h][2]); r.w = f2bf(acc[h][3]);
        *(ushort4v*)(o + h * C) = r;
    }
}

// ---------------- GEMM: 128x256 tile, BK=64, 8 waves, XCD-swizzled (R5-proven) ----------------
// Row-guarded C-write (Mreal) so output can be the unpadded x buffer.

__global__ __launch_bounds__(512) void gemm256(const u16* __restrict__ A,
                                               const u16* __restrict__ Bt,
                                               u16* __restrict__ Cout,
                                               int N, int K, int nxch, int Mreal) {
    __shared__ u16 lds[24576];
    const int tid = threadIdx.x;
    const int w = tid >> 6, l = tid & 63;
    const int wr = w >> 2, wc = w & 3;
    const int nwg = gridDim.x;
    const int q = nwg >> 3, r = nwg & 7;
    const int xcd = blockIdx.x & 7, idx = blockIdx.x >> 3;
    const int wgid = (xcd < r ? xcd * (q + 1) : r * (q + 1) + (xcd - r) * q) + idx;
    const int nx = wgid % nxch, my = wgid / nxch;
    const size_t bm = (size_t)my * 128, bn = (size_t)nx * 256;

    const f32x4 zf = {0.f, 0.f, 0.f, 0.f};
    f32x4 acc[4][4];
#pragma unroll
    for (int i = 0; i < 4; ++i)
#pragma unroll
        for (int j = 0; j < 4; ++j) acc[i][j] = zf;

    const int sseg = (l & 7) ^ (l >> 3);
    const u16* Ab = A + (bm + w * 16 + (l >> 3)) * (size_t)K + sseg * 8;
    const u16* Bb = Bt + (bn + w * 32 + (l >> 3)) * (size_t)K + sseg * 8;

    for (int k0 = 0; k0 < K; k0 += 64) {
#pragma unroll
        for (int qq = 0; qq < 2; ++qq)
            g2l16(Ab + k0 + (size_t)qq * 8 * K, lds + (w * 2 + qq) * 512);
#pragma unroll
        for (int qq = 0; qq < 4; ++qq)
            g2l16(Bb + k0 + (size_t)qq * 8 * K, lds + 8192 + (w * 4 + qq) * 512);
        __syncthreads();
#pragma unroll
        for (int kk = 0; kk < 2; ++kk) {
            const int gs = kk * 4 + (l >> 4);
            const int sg = (gs ^ (l & 7)) * 8;
            short8v af[4], bf8[4];
#pragma unroll
            for (int fm = 0; fm < 4; ++fm) {
                const int row = wr * 64 + fm * 16 + (l & 15);
                af[fm] = *(const short8v*)&lds[row * 64 + sg];
            }
#pragma unroll
            for (int fn = 0; fn < 4; ++fn) {
                const int row = wc * 64 + fn * 16 + (l & 15);
                bf8[fn] = *(const short8v*)&lds[8192 + row * 64 + sg];
            }
#pragma unroll
            for (int fm = 0; fm < 4; ++fm)
#pragma unroll
                for (int fn = 0; fn < 4; ++fn)
                    acc[fm][fn] = __builtin_amdgcn_mfma_f32_16x16x32_bf16(af[fm], bf8[fn],
                                                                          acc[fm][fn], 0, 0, 0);
        }
        __syncthreads();
    }

#pragma unroll
    for (int half = 0; half < 2; ++half) {
        if (wr == half) {
#pragma unroll
            for (int fm = 0; fm < 4; ++fm)
#pragma unroll
                for (int fn = 0; fn < 4; ++fn) {
                    const int col = wc * 64 + fn * 16 + (l & 15);
#pragma unroll
                    for (int rr = 0; rr < 4; ++rr)
                        lds[(fm * 16 + (l >> 4) * 4 + rr) * 264 + col] = f2bf(acc[fm][fn][rr]);
                }
        }
        __syncthreads();
        const int lrow = tid >> 3, lseg = tid & 7;
        const size_t grow = bm + half * 64 + lrow;
        if (grow < (size_t)Mreal) {
            u16* Crow = Cout + grow * (size_t)N + bn + lseg * 32;
            const u16* Lr = lds + lrow * 264 + lseg * 32;
#pragma unroll
            for (int ii = 0; ii < 4; ++ii)
                *(float4*)(Crow + ii * 8) = *(const float4*)(Lr + ii * 8);
        }
        __syncthreads();
    }
}

// ---------------- in-place scale + bias + LayerNorm (+ next-layer logits) ----------------

template <int C, int LOGITS>
__global__ __launch_bounds__(256) void ln_kernel(u16* __restrict__ x,
                                                 const float* __restrict__ bias,
                                                 const float* __restrict__ g,
                                                 const float* __restrict__ b,
                                                 const float* __restrict__ wsrc_n,
                                                 const float* __restrict__ wdst_n,
                                                 float* __restrict__ als, float* __restrict__ ald) {
    constexpr int PER = C / 256;
    const int n = blockIdx.x, tid = threadIdx.x;
    u16* xr = x + (size_t)n * C;
    float vals[PER];
    float s1 = 0.f, s2 = 0.f;
    constexpr float invH = 1.f / (float)H_HEADS;
#pragma unroll
    for (int i = 0; i < PER; ++i) {
        const int c = i * 256 + tid;
        const float v = bf2f(xr[c]) * invH + bias[c];
        vals[i] = v;
        s1 += v;
        s2 += v * v;
    }
    __shared__ float red[2][4];
    __shared__ float red2[4][6];
    for (int o = 32; o; o >>= 1) { s1 += __shfl_down(s1, o); s2 += __shfl_down(s2, o); }
    if ((tid & 63) == 0) { red[0][tid >> 6] = s1; red[1][tid >> 6] = s2; }
    __syncthreads();
    const float t1 = red[0][0] + red[0][1] + red[0][2] + red[0][3];
    const float t2 = red[1][0] + red[1][1] + red[1][2] + red[1][3];
    const float mu = t1 / C;
    const float var = t2 / C - mu * mu;
    const float rstd = rsqrtf(var + LN_EPS);
    float ps0 = 0.f, ps1 = 0.f, ps2 = 0.f, pd0 = 0.f, pd1 = 0.f, pd2 = 0.f;
#pragma unroll
    for (int i = 0; i < PER; ++i) {
        const int c = i * 256 + tid;
        const u16 xq16 = f2bf((vals[i] - mu) * rstd * g[c] + b[c]);
        xr[c] = xq16;
        if (LOGITS) {
            const float xq = bf2f(xq16);
            ps0 += xq * wsrc_n[0 * C + c]; pd0 += xq * wdst_n[0 * C + c];
            ps1 += xq * wsrc_n[1 * C + c]; pd1 += xq * wdst_n[1 * C + c];
            ps2 += xq * wsrc_n[2 * C + c]; pd2 += xq * wdst_n[2 * C + c];
        }
    }
    if (LOGITS) {
        for (int o = 32; o; o >>= 1) {
            ps0 += __shfl_down(ps0, o); ps1 += __shfl_down(ps1, o); ps2 += __shfl_down(ps2, o);
            pd0 += __shfl_down(pd0, o); pd1 += __shfl_down(pd1, o); pd2 += __shfl_down(pd2, o);
        }
        __syncthreads();
        if ((tid & 63) == 0) {
            const int wv = tid >> 6;
            red2[wv][0] = ps0; red2[wv][1] = ps1; red2[wv][2] = ps2;
            red2[wv][3] = pd0; red2[wv][4] = pd1; red2[wv][5] = pd2;
        }
        __syncthreads();
        if (tid == 0) {
#pragma unroll
            for (int h = 0; h < H_HEADS; ++h) {
                als[n * H_HEADS + h] = red2[0][h] + red2[1][h] + red2[2][h] + red2[3][h];
                ald[n * H_HEADS + h] =
                    red2[0][3 + h] + red2[1][3 + h] + red2[2][3 + h] + red2[3][3 + h];
            }
        }
    }
}

// ---------------- segmented atomic mean-pool ----------------

template <int C, int S>
__global__ void pool_atomic(const u16* __restrict__ x, const int* __restrict__ goff,
                            float* __restrict__ out, int layer) {
    const int g = blockIdx.x, seg = blockIdx.y;
    const int beg = goff[g], end = goff[g + 1];
    const int len = end - beg;
    const int s0 = beg + (len * seg) / S;
    const int s1 = beg + (len * (seg + 1)) / S;
    if (s0 >= s1) return;
    const float inv = 1.f / fmaxf((float)len, 1.f);
    const int tid = threadIdx.x;
    float a0 = 0.f, a1 = 0.f, a2 = 0.f, a3 = 0.f;
    for (int n = s0; n < s1; ++n) {
        const ushort4v v = *(const ushort4v*)(x + (size_t)n * C + tid * 4);
        a0 += bf2f(v.x); a1 += bf2f(v.y); a2 += bf2f(v.z); a3 += bf2f(v.w);
    }
    float* o = out + ((size_t)g * (LAYERS + 1) + layer) * C + tid * 4;
    atomicAdd(o + 0, a0 * inv);
    atomicAdd(o + 1, a1 * inv);
    atomicAdd(o + 2, a2 * inv);
    atomicAdd(o + 3, a3 * inv);
}

// ---------------- launch ----------------

extern "C" void kernel_launch(void* const* d_in, const int* in_sizes, int n_in, void* d_out,
                              int out_size, void* d_ws, size_t ws_size, hipStream_t stream) {
    const int* drug_x      = (const int*)d_in[0];
    const int* mol_ei      = (const int*)d_in[1];
    const int* mol_batch   = (const int*)d_in[2];
    const float* prot_in   = (const float*)d_in[3];
    const int* prot_ei     = (const int*)d_in[4];
    const int* prot_batch  = (const int*)d_in[5];
    const float* emb       = (const float*)d_in[6];
    const float* mol_W     = (const float*)d_in[7];
    const float* mol_asrc  = (const float*)d_in[8];
    const float* mol_adst  = (const float*)d_in[9];
    const float* mol_bias  = (const float*)d_in[10];
    const float* mol_lng   = (const float*)d_in[11];
    const float* mol_lnb   = (const float*)d_in[12];
    const float* prot_W    = (const float*)d_in[13];
    const float* prot_asrc = (const float*)d_in[14];
    const float* prot_adst = (const float*)d_in[15];
    const float* prot_bias = (const float*)d_in[16];
    const float* prot_lng  = (const float*)d_in[17];
    const float* prot_lnb  = (const float*)d_in[18];

    if (ws_size < (size_t)240500000) return;  // proven lower bound; we use ~201MB

    char* base = (char*)d_ws;
    size_t off = 0;
    auto alloc = [&](size_t bytes) -> void* {
        void* r = base + off;
        off = (off + bytes + 255) & ~(size_t)255;
        return r;
    };
    u16* x_mol  = (u16*)alloc((size_t)N_MOL * C_MOL * 2);
    u16* x_prot = (u16*)alloc((size_t)N_PROT * C_PROT * 2);
    u16* agg    = (u16*)alloc((size_t)3 * MPAD_MOL * C_MOL * 2);   // shared mol/prot
    u16* WtM    = (u16*)alloc((size_t)H_HEADS * C_MOL * C_MOL * 2);
    u16* WtP    = (u16*)alloc((size_t)H_HEADS * C_PROT * C_PROT * 2);
    float* wsrcM = (float*)alloc((size_t)LAYERS * H_HEADS * C_MOL * 4);
    float* wdstM = (float*)alloc((size_t)LAYERS * H_HEADS * C_MOL * 4);
    float* wsrcP = (float*)alloc((size_t)LAYERS * H_HEADS * C_PROT * 4);
    float* wdstP = (float*)alloc((size_t)LAYERS * H_HEADS * C_PROT * 4);
    float* alsM = (float*)alloc((size_t)N_MOL * H_HEADS * 4);
    float* aldM = (float*)alloc((size_t)N_MOL * H_HEADS * 4);
    float* alsP = (float*)alloc((size_t)N_PROT * H_HEADS * 4);
    float* aldP = (float*)alloc((size_t)N_PROT * H_HEADS * 4);
    float* alphaw = (float*)alloc((size_t)(E_MOL + N_MOL) * H_HEADS * 4);
    int* mol_indptr  = (int*)alloc((N_MOL + 1) * 4);
    int* mol_pos     = (int*)alloc(N_MOL * 4);
    int* mol_srcl    = (int*)alloc((E_MOL + N_MOL) * 4);
    int* prot_indptr = (int*)alloc((N_PROT + 1) * 4);
    int* prot_pos    = (int*)alloc(N_PROT * 4);
    int* prot_srcl   = (int*)alloc((E_PROT + N_PROT) * 4);
    int* cnt         = (int*)alloc(N_MOL * 4);
    int* mol_goff    = (int*)alloc((G_MOL + 1) * 4);
    int* prot_goff   = (int*)alloc((G_PROT + 1) * 4);
    int* gcnt        = (int*)alloc(G_MOL * 4);

    float* out_mol  = (float*)d_out;
    float* out_prot = (float*)d_out + (size_t)G_MOL * (LAYERS + 1) * C_MOL;

    zero_f32_kernel<<<(out_size + 255) / 256, 256, 0, stream>>>((float*)d_out, out_size);
    // zero fold accumulators (transfold atomically accumulates)
    zero_f32_kernel<<<(LAYERS * H_HEADS * C_MOL + 255) / 256, 256, 0, stream>>>(
        wsrcM, LAYERS * H_HEADS * C_MOL);
    zero_f32_kernel<<<(LAYERS * H_HEADS * C_MOL + 255) / 256, 256, 0, stream>>>(
        wdstM, LAYERS * H_HEADS * C_MOL);
    zero_f32_kernel<<<(LAYERS * H_HEADS * C_PROT + 255) / 256, 256, 0, stream>>>(
        wsrcP, LAYERS * H_HEADS * C_PROT);
    zero_f32_kernel<<<(LAYERS * H_HEADS * C_PROT + 255) / 256, 256, 0, stream>>>(
        wdstP, LAYERS * H_HEADS * C_PROT);

    // ---- CSR (incoming lists incl. self loops) ----
    set_int_kernel<<<(N_MOL + 255) / 256, 256, 0, stream>>>(cnt, 1, N_MOL);
    hist_kernel<<<(E_MOL + 255) / 256, 256, 0, stream>>>(mol_ei + E_MOL, E_MOL, cnt);
    scan_kernel<<<1, 1024, 0, stream>>>(cnt, mol_indptr, N_MOL);
    copy_int_kernel<<<(N_MOL + 255) / 256, 256, 0, stream>>>(mol_indptr, mol_pos, N_MOL);
    fill_self_kernel<<<(N_MOL + 255) / 256, 256, 0, stream>>>(mol_pos, mol_srcl, N_MOL);
    fill_edge_kernel<<<(E_MOL + 255) / 256, 256, 0, stream>>>(mol_ei, mol_ei + E_MOL, E_MOL, mol_pos,
                                                              mol_srcl);
    set_int_kernel<<<(N_PROT + 255) / 256, 256, 0, stream>>>(cnt, 1, N_PROT);
    hist_kernel<<<(E_PROT + 255) / 256, 256, 0, stream>>>(prot_ei + E_PROT, E_PROT, cnt);
    scan_kernel<<<1, 1024, 0, stream>>>(cnt, prot_indptr, N_PROT);
    copy_int_kernel<<<(N_PROT + 255) / 256, 256, 0, stream>>>(prot_indptr, prot_pos, N_PROT);
    fill_self_kernel<<<(N_PROT + 255) / 256, 256, 0, stream>>>(prot_pos, prot_srcl, N_PROT);
    fill_edge_kernel<<<(E_PROT + 255) / 256, 256, 0, stream>>>(prot_ei, prot_ei + E_PROT, E_PROT,
                                                               prot_pos, prot_srcl);

    // ---- graph offsets ----
    set_int_kernel<<<(G_MOL + 255) / 256, 256, 0, stream>>>(gcnt, 0, G_MOL);
    hist_kernel<<<(N_MOL + 255) / 256, 256, 0, stream>>>(mol_batch, N_MOL, gcnt);
    scan_kernel<<<1, 1024, 0, stream>>>(gcnt, mol_goff, G_MOL);
    set_int_kernel<<<(G_PROT + 255) / 256, 256, 0, stream>>>(gcnt, 0, G_PROT);
    hist_kernel<<<(N_PROT + 255) / 256, 256, 0, stream>>>(prot_batch, N_PROT, gcnt);
    scan_kernel<<<1, 1024, 0, stream>>>(gcnt, prot_goff, G_PROT);

    // ---- layer-0 transfold (Wt[0] + wsrc/wdst[0]) ----
    transfold<<<dim3(C_MOL / 32, C_MOL / 32, H_HEADS), 256, 0, stream>>>(
        mol_W, WtM, mol_asrc, mol_adst, wsrcM, wdstM, C_MOL, C_MOL, (size_t)C_MOL, 3 * C_MOL);
    transfold<<<dim3(C_PROT / 32, C_PROT / 32, H_HEADS), 256, 0, stream>>>(
        prot_W, WtP, prot_asrc, prot_adst, wsrcP, wdstP, C_PROT, C_PROT, (size_t)C_PROT,
        3 * C_PROT);

    // ---- layer-0 features + logits ----
    f32_to_bf16<<<(N_PROT * C_PROT + 255) / 256, 256, 0, stream>>>(prot_in, x_prot, N_PROT * C_PROT);
    embed_mean_kernel<<<N_MOL, C_MOL, 0, stream>>>(drug_x, emb, x_mol);
    pool_atomic<C_MOL, 8><<<dim3(G_MOL, 8), C_MOL / 4, 0, stream>>>(x_mol, mol_goff, out_mol, 0);
    pool_atomic<C_PROT, 64><<<dim3(G_PROT, 64), C_PROT / 4, 0, stream>>>(x_prot, prot_goff,
                                                                         out_prot, 0);
    attn_logits<C_MOL><<<N_MOL, 64, 0, stream>>>(x_mol, wsrcM, wdstM, alsM, aldM);
    attn_logits<C_PROT><<<N_PROT, 64, 0, stream>>>(x_prot, wsrcP, wdstP, alsP, aldP);

    const int gMol = (C_MOL / 256) * (MPAD_MOL / 128);   // 626
    const int gProt = (C_PROT / 256) * (MPAD_PROT / 128); // 315

    for (int l = 0; l < LAYERS; ++l) {
        const int last = (l == LAYERS - 1);
        // ---- molecule branch ----
        alpha_kernel2<<<(N_MOL * H_HEADS + 255) / 256, 256, 0, stream>>>(
            alsM, aldM, mol_indptr, mol_srcl, alphaw, N_MOL);
        aggregate_mol<<<N_MOL / 4, 256, 0, stream>>>(x_mol, alphaw, mol_indptr, mol_srcl, agg);
        gemm256<<<gMol, 512, 0, stream>>>(agg, WtM, x_mol, C_MOL, 3 * C_MOL, C_MOL / 256, N_MOL);
        if (!last)  // Wt[l] consumed; compute Wt[l+1] + wsrc/wdst[l+1] before LN needs them
            transfold<<<dim3(C_MOL / 32, C_MOL / 32, H_HEADS), 256, 0, stream>>>(
                mol_W + (size_t)(l + 1) * C_MOL * (H_HEADS * C_MOL), WtM,
                mol_asrc + (size_t)(l + 1) * H_HEADS * C_MOL,
                mol_adst + (size_t)(l + 1) * H_HEADS * C_MOL,
                wsrcM + (size_t)(l + 1) * H_HEADS * C_MOL,
                wdstM + (size_t)(l + 1) * H_HEADS * C_MOL, C_MOL, C_MOL, (size_t)C_MOL, 3 * C_MOL);
        if (last)
            ln_kernel<C_MOL, 0><<<N_MOL, 256, 0, stream>>>(
                x_mol, mol_bias + (size_t)l * C_MOL, mol_lng + (size_t)l * C_MOL,
                mol_lnb + (size_t)l * C_MOL, nullptr, nullptr, nullptr, nullptr);
        else
            ln_kernel<C_MOL, 1><<<N_MOL, 256, 0, stream>>>(
                x_mol, mol_bias + (size_t)l * C_MOL, mol_lng + (size_t)l * C_MOL,
                mol_lnb + (size_t)l * C_MOL, wsrcM + (size_t)(l + 1) * H_HEADS * C_MOL,
                wdstM + (size_t)(l + 1) * H_HEADS * C_MOL, alsM, aldM);
        pool_atomic<C_MOL, 8><<<dim3(G_MOL, 8), C_MOL / 4, 0, stream>>>(x_mol, mol_goff, out_mol,
                                                                        l + 1);
        // ---- protein branch ----
        alpha_kernel2<<<(N_PROT * H_HEADS + 255) / 256, 256, 0, stream>>>(
            alsP, aldP, prot_indptr, prot_srcl, alphaw, N_PROT);
        aggregate_all3<C_PROT><<<N_PROT, C_PROT / 4, 0, stream>>>(x_prot, alphaw, prot_indptr,
                                                                  prot_srcl, agg);
        gemm256<<<gProt, 512, 0, stream>>>(agg, WtP, x_prot, C_PROT, 3 * C_PROT, C_PROT / 256,
                                           N_PROT);
        if (!last)
            transfold<<<dim3(C_PROT / 32, C_PROT / 32, H_HEADS), 256, 0, stream>>>(
                prot_W + (size_t)(l + 1) * C_PROT * (H_HEADS * C_PROT), WtP,
                prot_asrc + (size_t)(l + 1) * H_HEADS * C_PROT,
                prot_adst + (size_t)(l + 1) * H_HEADS * C_PROT,
                wsrcP + (size_t)(l + 1) * H_HEADS * C_PROT,
                wdstP + (size_t)(l + 1) * H_HEADS * C_PROT, C_PROT, C_PROT, (size_t)C_PROT,
                3 * C_PROT);
        if (last)
            ln_kernel<C_PROT, 0><<<N_PROT, 256, 0, stream>>>(
                x_prot, prot_bias + (size_t)l * C_PROT, prot_lng + (size_t)l * C_PROT,
                prot_lnb + (size_t)l * C_PROT, nullptr, nullptr, nullptr, nullptr);
        else
            ln_kernel<C_PROT, 1><<<N_PROT, 256, 0, stream>>>(
                x_prot, prot_bias + (size_t)l * C_PROT, prot_lng + (size_t)l * C_PROT,
                prot_lnb + (size_t)l * C_PROT, wsrcP + (size_t)(l + 1) * H_HEADS * C_PROT,
                wdstP + (size_t)(l + 1) * H_HEADS * C_PROT, alsP, aldP);
        pool_atomic<C_PROT, 64><<<dim3(G_PROT, 64), C_PROT / 4, 0, stream>>>(x_prot, prot_goff,
                                                                             out_prot, l + 1);
    }
}

// Round 9
// 2343.814 us; speedup vs baseline: 1.0884x; 1.0200x over previous
//
#include <hip/hip_runtime.h>
#include <cstdint>

// R9: counted-vmcnt double-buffered GEMM (T4): occupancy counters show 1 block/CU
// (8 waves = 25%), so no implicit inter-block overlap -> explicit prefetch with
// vmcnt(6) hides load latency under MFMA. 96KB LDS dbuf (residency already 1).
// Dual-problem dispatch (prot-first LPT, per-range XCD swizzle) gated ws>=262MB.

constexpr int H_HEADS = 3;
constexpr float NEG_SLOPE = 0.2f;
constexpr float LN_EPS = 1e-5f;
constexpr int N_MOL = 40000, E_MOL = 80000, C_MOL = 512, G_MOL = 512;
constexpr int N_PROT = 8000, E_PROT = 64000, C_PROT = 1280, G_PROT = 32;
constexpr int LAYERS = 4;
constexpr int MPAD_MOL = 40064;
constexpr int MPAD_PROT = 8064;

typedef unsigned short u16;
typedef __attribute__((ext_vector_type(8))) short short8v;
typedef __attribute__((ext_vector_type(4))) unsigned short ushort4v;
typedef __attribute__((ext_vector_type(4))) float f32x4;

__device__ __forceinline__ float bf2f(u16 s) {
    union { unsigned u; float f; } v; v.u = ((unsigned)s) << 16; return v.f;
}
__device__ __forceinline__ u16 f2bf(float f) {
    union { float f; unsigned u; } v; v.f = f;
    return (u16)((v.u + 0x7fffu + ((v.u >> 16) & 1u)) >> 16);
}

__device__ __forceinline__ void g2l16(const void* g, void* l) {
    __builtin_amdgcn_global_load_lds((const __attribute__((address_space(1))) void*)g,
                                     (__attribute__((address_space(3))) void*)l, 16, 0, 0);
}

// ---------------- small utility kernels ----------------

__global__ void set_int_kernel(int* p, int v, int n) {
    int i = blockIdx.x * blockDim.x + threadIdx.x;
    if (i < n) p[i] = v;
}

__global__ void zero_f32_kernel(float* p, int n) {
    int i = blockIdx.x * blockDim.x + threadIdx.x;
    if (i < n) p[i] = 0.f;
}

__global__ void copy_int_kernel(const int* __restrict__ s, int* __restrict__ d, int n) {
    int i = blockIdx.x * blockDim.x + threadIdx.x;
    if (i < n) d[i] = s[i];
}

__global__ void hist_kernel(const int* __restrict__ keys, int n, int* __restrict__ cnt) {
    int i = blockIdx.x * blockDim.x + threadIdx.x;
    if (i < n) atomicAdd(&cnt[keys[i]], 1);
}

__global__ void scan_kernel(const int* __restrict__ in, int* __restrict__ out, int n) {
    __shared__ int sums[1024];
    const int t = threadIdx.x;
    const int chunk = (n + 1023) / 1024;
    const int start = t * chunk;
    const int end = min(start + chunk, n);
    int s = 0;
    for (int i = start; i < end; ++i) s += in[i];
    sums[t] = s;
    __syncthreads();
    if (t == 0) {
        int acc = 0;
        for (int i = 0; i < 1024; ++i) { int v = sums[i]; sums[i] = acc; acc += v; }
        out[n] = acc;
    }
    __syncthreads();
    int acc = sums[t];
    for (int i = start; i < end; ++i) { out[i] = acc; acc += in[i]; }
}

__global__ void fill_self_kernel(int* __restrict__ pos, int* __restrict__ srcl, int n) {
    int i = blockIdx.x * blockDim.x + threadIdx.x;
    if (i < n) { int slot = atomicAdd(&pos[i], 1); srcl[slot] = i; }
}

__global__ void fill_edge_kernel(const int* __restrict__ src, const int* __restrict__ dst, int e,
                                 int* __restrict__ pos, int* __restrict__ srcl) {
    int i = blockIdx.x * blockDim.x + threadIdx.x;
    if (i < e) { int slot = atomicAdd(&pos[dst[i]], 1); srcl[slot] = src[i]; }
}

__global__ void f32_to_bf16(const float* __restrict__ in, u16* __restrict__ out, int n) {
    int i = blockIdx.x * blockDim.x + threadIdx.x;
    if (i < n) out[i] = f2bf(in[i]);
}

// ---------------- embedding mean -> bf16 ----------------

__global__ void embed_mean_kernel(const int* __restrict__ drug_x, const float* __restrict__ emb,
                                  u16* __restrict__ out) {
    const int n = blockIdx.x;
    __shared__ int idx[9];
    if (threadIdx.x < 9) idx[threadIdx.x] = drug_x[n * 9 + threadIdx.x];
    __syncthreads();
    const int c = threadIdx.x;
    float s = 0.f;
#pragma unroll
    for (int t = 0; t < 9; ++t) s += emb[(size_t)idx[t] * C_MOL + c];
    out[(size_t)n * C_MOL + c] = f2bf(s * (1.f / 9.f));
}

// ---------------- fused transpose + fold ----------------

__global__ __launch_bounds__(256) void transfold(const float* __restrict__ W, u16* __restrict__ Wt,
                                                 const float* __restrict__ asrc,
                                                 const float* __restrict__ adst,
                                                 float* __restrict__ wsrc, float* __restrict__ wdst,
                                                 int CIN, int COUT, size_t headStride, int ldn) {
    __shared__ float t[32][33];
    __shared__ float rs[8][33], rd[8][33];
    const int h = blockIdx.z;
    const int n0 = blockIdx.x * 32, k0 = blockIdx.y * 32;
    const int tx = threadIdx.x & 31, ty = threadIdx.x >> 5;
#pragma unroll
    for (int q = 0; q < 4; ++q)
        t[ty + q * 8][tx] = W[(size_t)(k0 + ty + q * 8) * (H_HEADS * COUT) + h * COUT + n0 + tx];
    __syncthreads();
#pragma unroll
    for (int q = 0; q < 4; ++q)
        Wt[(size_t)h * headStride + (size_t)(n0 + ty + q * 8) * ldn + k0 + tx] =
            f2bf(t[tx][ty + q * 8]);
    float ps = 0.f, pd = 0.f;
    const float* as = asrc + h * COUT + n0;
    const float* ad = adst + h * COUT + n0;
#pragma unroll
    for (int q = 0; q < 4; ++q) {
        const float w = t[tx][ty + q * 8];
        ps += w * as[ty + q * 8];
        pd += w * ad[ty + q * 8];
    }
    rs[ty][tx] = ps;
    rd[ty][tx] = pd;
    __syncthreads();
    if (ty == 0) {
        float s = 0.f, d = 0.f;
#pragma unroll
        for (int j = 0; j < 8; ++j) { s += rs[j][tx]; d += rd[j][tx]; }
        atomicAdd(&wsrc[h * CIN + k0 + tx], s);
        atomicAdd(&wdst[h * CIN + k0 + tx], d);
    }
}

// ---------------- attention logits (layer 0 only) ----------------

template <int C>
__global__ void attn_logits(const u16* __restrict__ x, const float* __restrict__ wsrc,
                            const float* __restrict__ wdst, float* __restrict__ als,
                            float* __restrict__ ald) {
    constexpr int PER = C / 64;
    const int n = blockIdx.x, lane = threadIdx.x;
    const u16* xr = x + (size_t)n * C + lane * PER;
    float xv[PER];
#pragma unroll
    for (int i = 0; i < PER; i += 4) {
        const ushort4v v = *(const ushort4v*)(xr + i);
        xv[i] = bf2f(v.x); xv[i + 1] = bf2f(v.y); xv[i + 2] = bf2f(v.z); xv[i + 3] = bf2f(v.w);
    }
    for (int h = 0; h < H_HEADS; ++h) {
        const float* ws = wsrc + h * C + lane * PER;
        const float* wd = wdst + h * C + lane * PER;
        float ss = 0.f, sd = 0.f;
#pragma unroll
        for (int i = 0; i < PER; i += 4) {
            const float4 a = *(const float4*)(ws + i);
            const float4 b = *(const float4*)(wd + i);
            ss += xv[i] * a.x + xv[i + 1] * a.y + xv[i + 2] * a.z + xv[i + 3] * a.w;
            sd += xv[i] * b.x + xv[i + 1] * b.y + xv[i + 2] * b.z + xv[i + 3] * b.w;
        }
        for (int o = 32; o; o >>= 1) { ss += __shfl_down(ss, o); sd += __shfl_down(sd, o); }
        if (lane == 0) { als[n * H_HEADS + h] = ss; ald[n * H_HEADS + h] = sd; }
    }
}

// ---------------- segment softmax: one thread per (node, head) ----------------

__global__ void alpha_kernel2(const float* __restrict__ als, const float* __restrict__ ald,
                              const int* __restrict__ indptr, const int* __restrict__ srcl,
                              float* __restrict__ alphaw, int n_nodes) {
    const int t = blockIdx.x * blockDim.x + threadIdx.x;
    const int n = t / H_HEADS, h = t - n * H_HEADS;
    if (n >= n_nodes) return;
    const int beg = indptr[n], end = indptr[n + 1];
    const float ad = ald[n * H_HEADS + h];
    float m = -1e30f;
    for (int e = beg; e < end; ++e) {
        float v = als[srcl[e] * H_HEADS + h] + ad;
        v = v >= 0.f ? v : NEG_SLOPE * v;
        m = fmaxf(m, v);
    }
    float z = 0.f;
    for (int e = beg; e < end; ++e) {
        float v = als[srcl[e] * H_HEADS + h] + ad;
        v = v >= 0.f ? v : NEG_SLOPE * v;
        z += __expf(v - m);
    }
    const float zi = 1.f / (z + 1e-16f);
    for (int e = beg; e < end; ++e) {
        float v = als[srcl[e] * H_HEADS + h] + ad;
        v = v >= 0.f ? v : NEG_SLOPE * v;
        alphaw[e * H_HEADS + h] = __expf(v - m) * zi;
    }
}

// ---------------- mol aggregation: wave per node, 16B loads ----------------

__global__ __launch_bounds__(256) void aggregate_mol(const u16* __restrict__ x,
                                                     const float* __restrict__ alphaw,
                                                     const int* __restrict__ indptr,
                                                     const int* __restrict__ srcl,
                                                     u16* __restrict__ agg) {
    const int wv = threadIdx.x >> 6, lane = threadIdx.x & 63;
    const int n = blockIdx.x * 4 + wv;
    const int beg = indptr[n], end = indptr[n + 1];
    float acc[H_HEADS][8];
#pragma unroll
    for (int h = 0; h < H_HEADS; ++h)
#pragma unroll
        for (int j = 0; j < 8; ++j) acc[h][j] = 0.f;
    for (int e = beg; e < end; ++e) {
        const float a0 = alphaw[e * H_HEADS + 0];
        const float a1 = alphaw[e * H_HEADS + 1];
        const float a2 = alphaw[e * H_HEADS + 2];
        const short8v row = *(const short8v*)(x + (size_t)srcl[e] * C_MOL + lane * 8);
#pragma unroll
        for (int j = 0; j < 8; ++j) {
            const float f = bf2f((u16)row[j]);
            acc[0][j] += a0 * f; acc[1][j] += a1 * f; acc[2][j] += a2 * f;
        }
    }
    u16* o = agg + (size_t)n * (3 * C_MOL) + lane * 8;
#pragma unroll
    for (int h = 0; h < H_HEADS; ++h) {
        short8v r;
#pragma unroll
        for (int j = 0; j < 8; ++j) r[j] = (short)f2bf(acc[h][j]);
        *(short8v*)(o + h * C_MOL) = r;
    }
}

// ---------------- prot aggregation: block C/4 = 320 threads per node ----------------

template <int C>
__global__ void aggregate_all3(const u16* __restrict__ x, const float* __restrict__ alphaw,
                               const int* __restrict__ indptr, const int* __restrict__ srcl,
                               u16* __restrict__ agg) {
    const int n = blockIdx.x, tid = threadIdx.x;
    const int beg = indptr[n], end = indptr[n + 1];
    float acc[H_HEADS][4];
#pragma unroll
    for (int h = 0; h < H_HEADS; ++h)
#pragma unroll
        for (int j = 0; j < 4; ++j) acc[h][j] = 0.f;
    for (int e = beg; e < end; ++e) {
        const float a0 = alphaw[e * H_HEADS + 0];
        const float a1 = alphaw[e * H_HEADS + 1];
        const float a2 = alphaw[e * H_HEADS + 2];
        const ushort4v v = *(const ushort4v*)(x + (size_t)srcl[e] * C + tid * 4);
        const float f0 = bf2f(v.x), f1 = bf2f(v.y), f2 = bf2f(v.z), f3 = bf2f(v.w);
        acc[0][0] += a0 * f0; acc[0][1] += a0 * f1; acc[0][2] += a0 * f2; acc[0][3] += a0 * f3;
        acc[1][0] += a1 * f0; acc[1][1] += a1 * f1; acc[1][2] += a1 * f2; acc[1][3] += a1 * f3;
        acc[2][0] += a2 * f0; acc[2][1] += a2 * f1; acc[2][2] += a2 * f2; acc[2][3] += a2 * f3;
    }
    u16* o = agg + (size_t)n * (3 * C) + tid * 4;
#pragma unroll
    for (int h = 0; h < H_HEADS; ++h) {
        ushort4v r;
        r.x = f2bf(acc[h][0]); r.y = f2bf(acc[h][1]); r.z = f2bf(acc[h][2]); r.w = f2bf(acc[h][3]);
        *(ushort4v*)(o + h * C) = r;
    }
}

// ---------------- GEMM: 128x256 tile, BK=64, dbuf + counted vmcnt, dual-problem ----------------
// LDS: 2 buffers x (A 16KB + B 32KB) = 96KB -> 1 block/CU (measured: already 1).
// Per wave, 6 global_load_lds per stage -> vmcnt(6) leaves next tile in flight.

__global__ __launch_bounds__(512) void gemm_dual(
    const u16* __restrict__ A0, const u16* __restrict__ B0, u16* __restrict__ C0,
    int N0, int K0, int nx0, int M0, int g0,
    const u16* __restrict__ A1, const u16* __restrict__ B1, u16* __restrict__ C1,
    int N1, int K1, int nx1, int M1) {
    __shared__ u16 lds[49152];  // 96 KB: buf b at lds + b*24576 (A: +0, B: +8192 u16)
    const int tid = threadIdx.x;
    const int w = tid >> 6, l = tid & 63;
    const int wr = w >> 2, wc = w & 3;

    // problem select + per-range bijective XCD swizzle (keeps per-XCD wgid contiguity)
    const int bid = blockIdx.x;
    const u16 *A, *Bt;
    u16* Cout;
    int N, K, nxch, Mreal, base, sz;
    if (bid < g0) { base = 0; sz = g0; A = A0; Bt = B0; Cout = C0; N = N0; K = K0; nxch = nx0; Mreal = M0; }
    else { base = g0; sz = gridDim.x - g0; A = A1; Bt = B1; Cout = C1; N = N1; K = K1; nxch = nx1; Mreal = M1; }
    const int j = bid - base;
    const int q = sz >> 3, r = sz & 7;
    const int xcd = j & 7, idx = j >> 3;
    const int wg = (xcd < r ? xcd * (q + 1) : r * (q + 1) + (xcd - r) * q) + idx;
    const int nx = wg % nxch, my = wg / nxch;
    const size_t bm = (size_t)my * 128, bn = (size_t)nx * 256;

    const f32x4 zf = {0.f, 0.f, 0.f, 0.f};
    f32x4 acc[4][4];
#pragma unroll
    for (int i = 0; i < 4; ++i)
#pragma unroll
        for (int jj = 0; jj < 4; ++jj) acc[i][jj] = zf;

    const int sseg = (l & 7) ^ (l >> 3);
    const u16* Ab = A + (bm + w * 16 + (l >> 3)) * (size_t)K + sseg * 8;
    const u16* Bb = Bt + (bn + w * 32 + (l >> 3)) * (size_t)K + sseg * 8;

    auto stage = [&](int buf, int k0) {
        u16* La = lds + buf * 24576;
#pragma unroll
        for (int qq = 0; qq < 2; ++qq)
            g2l16(Ab + k0 + (size_t)qq * 8 * K, La + (w * 2 + qq) * 512);
#pragma unroll
        for (int qq = 0; qq < 4; ++qq)
            g2l16(Bb + k0 + (size_t)qq * 8 * K, La + 8192 + (w * 4 + qq) * 512);
    };

    const int nt = K >> 6;
    stage(0, 0);
    for (int t = 0; t < nt; ++t) {
        const int cur = t & 1;
        if (t + 1 < nt) {
            stage(cur ^ 1, (t + 1) << 6);
            asm volatile("s_waitcnt vmcnt(6)" ::: "memory");  // current tile's 6 done
        } else {
            asm volatile("s_waitcnt vmcnt(0)" ::: "memory");
        }
        __builtin_amdgcn_s_barrier();
        __builtin_amdgcn_sched_barrier(0);
        const u16* Lb = lds + cur * 24576;
#pragma unroll
        for (int kk = 0; kk < 2; ++kk) {
            const int gs = kk * 4 + (l >> 4);
            const int sg = (gs ^ (l & 7)) * 8;
            short8v af[4], bf8[4];
#pragma unroll
            for (int fm = 0; fm < 4; ++fm) {
                const int row = wr * 64 + fm * 16 + (l & 15);
                af[fm] = *(const short8v*)&Lb[row * 64 + sg];
            }
#pragma unroll
            for (int fn = 0; fn < 4; ++fn) {
                const int row = wc * 64 + fn * 16 + (l & 15);
                bf8[fn] = *(const short8v*)&Lb[8192 + row * 64 + sg];
            }
#pragma unroll
            for (int fm = 0; fm < 4; ++fm)
#pragma unroll
                for (int fn = 0; fn < 4; ++fn)
                    acc[fm][fn] = __builtin_amdgcn_mfma_f32_16x16x32_bf16(af[fm], bf8[fn],
                                                                          acc[fm][fn], 0, 0, 0);
        }
        __builtin_amdgcn_sched_barrier(0);
        __builtin_amdgcn_s_barrier();
    }

    // epilogue: two 64-row halves through LDS (stride 264), coalesced, row-guarded
#pragma unroll
    for (int half = 0; half < 2; ++half) {
        if (wr == half) {
#pragma unroll
            for (int fm = 0; fm < 4; ++fm)
#pragma unroll
                for (int fn = 0; fn < 4; ++fn) {
                    const int col = wc * 64 + fn * 16 + (l & 15);
#pragma unroll
                    for (int rr = 0; rr < 4; ++rr)
                        lds[(fm * 16 + (l >> 4) * 4 + rr) * 264 + col] = f2bf(acc[fm][fn][rr]);
                }
        }
        __syncthreads();
        const int lrow = tid >> 3, lseg = tid & 7;
        const size_t grow = bm + half * 64 + lrow;
        if (grow < (size_t)Mreal) {
            u16* Crow = Cout + grow * (size_t)N + bn + lseg * 32;
            const u16* Lr = lds + lrow * 264 + lseg * 32;
#pragma unroll
            for (int ii = 0; ii < 4; ++ii)
                *(float4*)(Crow + ii * 8) = *(const float4*)(Lr + ii * 8);
        }
        __syncthreads();
    }
}

// ---------------- in-place scale + bias + LayerNorm (+ next-layer logits) ----------------

template <int C, int LOGITS>
__global__ __launch_bounds__(256) void ln_kernel(u16* __restrict__ x,
                                                 const float* __restrict__ bias,
                                                 const float* __restrict__ g,
                                                 const float* __restrict__ b,
                                                 const float* __restrict__ wsrc_n,
                                                 const float* __restrict__ wdst_n,
                                                 float* __restrict__ als, float* __restrict__ ald) {
    constexpr int PER = C / 256;
    const int n = blockIdx.x, tid = threadIdx.x;
    u16* xr = x + (size_t)n * C;
    float vals[PER];
    float s1 = 0.f, s2 = 0.f;
    constexpr float invH = 1.f / (float)H_HEADS;
#pragma unroll
    for (int i = 0; i < PER; ++i) {
        const int c = i * 256 + tid;
        const float v = bf2f(xr[c]) * invH + bias[c];
        vals[i] = v;
        s1 += v;
        s2 += v * v;
    }
    __shared__ float red[2][4];
    __shared__ float red2[4][6];
    for (int o = 32; o; o >>= 1) { s1 += __shfl_down(s1, o); s2 += __shfl_down(s2, o); }
    if ((tid & 63) == 0) { red[0][tid >> 6] = s1; red[1][tid >> 6] = s2; }
    __syncthreads();
    const float t1 = red[0][0] + red[0][1] + red[0][2] + red[0][3];
    const float t2 = red[1][0] + red[1][1] + red[1][2] + red[1][3];
    const float mu = t1 / C;
    const float var = t2 / C - mu * mu;
    const float rstd = rsqrtf(var + LN_EPS);
    float ps0 = 0.f, ps1 = 0.f, ps2 = 0.f, pd0 = 0.f, pd1 = 0.f, pd2 = 0.f;
#pragma unroll
    for (int i = 0; i < PER; ++i) {
        const int c = i * 256 + tid;
        const u16 xq16 = f2bf((vals[i] - mu) * rstd * g[c] + b[c]);
        xr[c] = xq16;
        if (LOGITS) {
            const float xq = bf2f(xq16);
            ps0 += xq * wsrc_n[0 * C + c]; pd0 += xq * wdst_n[0 * C + c];
            ps1 += xq * wsrc_n[1 * C + c]; pd1 += xq * wdst_n[1 * C + c];
            ps2 += xq * wsrc_n[2 * C + c]; pd2 += xq * wdst_n[2 * C + c];
        }
    }
    if (LOGITS) {
        for (int o = 32; o; o >>= 1) {
            ps0 += __shfl_down(ps0, o); ps1 += __shfl_down(ps1, o); ps2 += __shfl_down(ps2, o);
            pd0 += __shfl_down(pd0, o); pd1 += __shfl_down(pd1, o); pd2 += __shfl_down(pd2, o);
        }
        __syncthreads();
        if ((tid & 63) == 0) {
            const int wv = tid >> 6;
            red2[wv][0] = ps0; red2[wv][1] = ps1; red2[wv][2] = ps2;
            red2[wv][3] = pd0; red2[wv][4] = pd1; red2[wv][5] = pd2;
        }
        __syncthreads();
        if (tid == 0) {
#pragma unroll
            for (int h = 0; h < H_HEADS; ++h) {
                als[n * H_HEADS + h] = red2[0][h] + red2[1][h] + red2[2][h] + red2[3][h];
                ald[n * H_HEADS + h] =
                    red2[0][3 + h] + red2[1][3 + h] + red2[2][3 + h] + red2[3][3 + h];
            }
        }
    }
}

// ---------------- segmented atomic mean-pool ----------------

template <int C, int S>
__global__ void pool_atomic(const u16* __restrict__ x, const int* __restrict__ goff,
                            float* __restrict__ out, int layer) {
    const int g = blockIdx.x, seg = blockIdx.y;
    const int beg = goff[g], end = goff[g + 1];
    const int len = end - beg;
    const int s0 = beg + (len * seg) / S;
    const int s1 = beg + (len * (seg + 1)) / S;
    if (s0 >= s1) return;
    const float inv = 1.f / fmaxf((float)len, 1.f);
    const int tid = threadIdx.x;
    float a0 = 0.f, a1 = 0.f, a2 = 0.f, a3 = 0.f;
    for (int n = s0; n < s1; ++n) {
        const ushort4v v = *(const ushort4v*)(x + (size_t)n * C + tid * 4);
        a0 += bf2f(v.x); a1 += bf2f(v.y); a2 += bf2f(v.z); a3 += bf2f(v.w);
    }
    float* o = out + ((size_t)g * (LAYERS + 1) + layer) * C + tid * 4;
    atomicAdd(o + 0, a0 * inv);
    atomicAdd(o + 1, a1 * inv);
    atomicAdd(o + 2, a2 * inv);
    atomicAdd(o + 3, a3 * inv);
}

// ---------------- launch ----------------

extern "C" void kernel_launch(void* const* d_in, const int* in_sizes, int n_in, void* d_out,
                              int out_size, void* d_ws, size_t ws_size, hipStream_t stream) {
    const int* drug_x      = (const int*)d_in[0];
    const int* mol_ei      = (const int*)d_in[1];
    const int* mol_batch   = (const int*)d_in[2];
    const float* prot_in   = (const float*)d_in[3];
    const int* prot_ei     = (const int*)d_in[4];
    const int* prot_batch  = (const int*)d_in[5];
    const float* emb       = (const float*)d_in[6];
    const float* mol_W     = (const float*)d_in[7];
    const float* mol_asrc  = (const float*)d_in[8];
    const float* mol_adst  = (const float*)d_in[9];
    const float* mol_bias  = (const float*)d_in[10];
    const float* mol_lng   = (const float*)d_in[11];
    const float* mol_lnb   = (const float*)d_in[12];
    const float* prot_W    = (const float*)d_in[13];
    const float* prot_asrc = (const float*)d_in[14];
    const float* prot_adst = (const float*)d_in[15];
    const float* prot_bias = (const float*)d_in[16];
    const float* prot_lng  = (const float*)d_in[17];
    const float* prot_lnb  = (const float*)d_in[18];

    if (ws_size < (size_t)240500000) return;            // proven lower bound
    const bool BIG = ws_size >= (size_t)262000000;      // dual-GEMM path (~261.3MB used)

    char* base = (char*)d_ws;
    size_t off = 0;
    auto alloc = [&](size_t bytes) -> void* {
        void* r = base + off;
        off = (off + bytes + 255) & ~(size_t)255;
        return r;
    };
    u16* x_mol  = (u16*)alloc((size_t)N_MOL * C_MOL * 2);
    u16* x_prot = (u16*)alloc((size_t)N_PROT * C_PROT * 2);
    u16* aggM   = (u16*)alloc((size_t)3 * MPAD_MOL * C_MOL * 2);
    u16* WtM    = (u16*)alloc((size_t)H_HEADS * C_MOL * C_MOL * 2);
    u16* WtP    = (u16*)alloc((size_t)H_HEADS * C_PROT * C_PROT * 2);
    u16* aggP   = BIG ? (u16*)alloc((size_t)3 * MPAD_PROT * C_PROT * 2) : aggM;
    float* wsrcM = (float*)alloc((size_t)LAYERS * H_HEADS * C_MOL * 4);
    float* wdstM = (float*)alloc((size_t)LAYERS * H_HEADS * C_MOL * 4);
    float* wsrcP = (float*)alloc((size_t)LAYERS * H_HEADS * C_PROT * 4);
    float* wdstP = (float*)alloc((size_t)LAYERS * H_HEADS * C_PROT * 4);
    float* alsM = (float*)alloc((size_t)N_MOL * H_HEADS * 4);
    float* aldM = (float*)alloc((size_t)N_MOL * H_HEADS * 4);
    float* alsP = (float*)alloc((size_t)N_PROT * H_HEADS * 4);
    float* aldP = (float*)alloc((size_t)N_PROT * H_HEADS * 4);
    float* alphaw = (float*)alloc((size_t)(E_MOL + N_MOL) * H_HEADS * 4);
    int* mol_indptr  = (int*)alloc((N_MOL + 1) * 4);
    int* mol_pos     = (int*)alloc(N_MOL * 4);
    int* mol_srcl    = (int*)alloc((E_MOL + N_MOL) * 4);
    int* prot_indptr = (int*)alloc((N_PROT + 1) * 4);
    int* prot_pos    = (int*)alloc(N_PROT * 4);
    int* prot_srcl   = (int*)alloc((E_PROT + N_PROT) * 4);
    int* cnt         = (int*)alloc(N_MOL * 4);
    int* mol_goff    = (int*)alloc((G_MOL + 1) * 4);
    int* prot_goff   = (int*)alloc((G_PROT + 1) * 4);
    int* gcnt        = (int*)alloc(G_MOL * 4);

    float* out_mol  = (float*)d_out;
    float* out_prot = (float*)d_out + (size_t)G_MOL * (LAYERS + 1) * C_MOL;

    zero_f32_kernel<<<(out_size + 255) / 256, 256, 0, stream>>>((float*)d_out, out_size);
    zero_f32_kernel<<<(LAYERS * H_HEADS * C_MOL + 255) / 256, 256, 0, stream>>>(
        wsrcM, LAYERS * H_HEADS * C_MOL);
    zero_f32_kernel<<<(LAYERS * H_HEADS * C_MOL + 255) / 256, 256, 0, stream>>>(
        wdstM, LAYERS * H_HEADS * C_MOL);
    zero_f32_kernel<<<(LAYERS * H_HEADS * C_PROT + 255) / 256, 256, 0, stream>>>(
        wsrcP, LAYERS * H_HEADS * C_PROT);
    zero_f32_kernel<<<(LAYERS * H_HEADS * C_PROT + 255) / 256, 256, 0, stream>>>(
        wdstP, LAYERS * H_HEADS * C_PROT);

    // ---- CSR (incoming lists incl. self loops) ----
    set_int_kernel<<<(N_MOL + 255) / 256, 256, 0, stream>>>(cnt, 1, N_MOL);
    hist_kernel<<<(E_MOL + 255) / 256, 256, 0, stream>>>(mol_ei + E_MOL, E_MOL, cnt);
    scan_kernel<<<1, 1024, 0, stream>>>(cnt, mol_indptr, N_MOL);
    copy_int_kernel<<<(N_MOL + 255) / 256, 256, 0, stream>>>(mol_indptr, mol_pos, N_MOL);
    fill_self_kernel<<<(N_MOL + 255) / 256, 256, 0, stream>>>(mol_pos, mol_srcl, N_MOL);
    fill_edge_kernel<<<(E_MOL + 255) / 256, 256, 0, stream>>>(mol_ei, mol_ei + E_MOL, E_MOL, mol_pos,
                                                              mol_srcl);
    set_int_kernel<<<(N_PROT + 255) / 256, 256, 0, stream>>>(cnt, 1, N_PROT);
    hist_kernel<<<(E_PROT + 255) / 256, 256, 0, stream>>>(prot_ei + E_PROT, E_PROT, cnt);
    scan_kernel<<<1, 1024, 0, stream>>>(cnt, prot_indptr, N_PROT);
    copy_int_kernel<<<(N_PROT + 255) / 256, 256, 0, stream>>>(prot_indptr, prot_pos, N_PROT);
    fill_self_kernel<<<(N_PROT + 255) / 256, 256, 0, stream>>>(prot_pos, prot_srcl, N_PROT);
    fill_edge_kernel<<<(E_PROT + 255) / 256, 256, 0, stream>>>(prot_ei, prot_ei + E_PROT, E_PROT,
                                                               prot_pos, prot_srcl);

    // ---- graph offsets ----
    set_int_kernel<<<(G_MOL + 255) / 256, 256, 0, stream>>>(gcnt, 0, G_MOL);
    hist_kernel<<<(N_MOL + 255) / 256, 256, 0, stream>>>(mol_batch, N_MOL, gcnt);
    scan_kernel<<<1, 1024, 0, stream>>>(gcnt, mol_goff, G_MOL);
    set_int_kernel<<<(G_PROT + 255) / 256, 256, 0, stream>>>(gcnt, 0, G_PROT);
    hist_kernel<<<(N_PROT + 255) / 256, 256, 0, stream>>>(prot_batch, N_PROT, gcnt);
    scan_kernel<<<1, 1024, 0, stream>>>(gcnt, prot_goff, G_PROT);

    // ---- layer-0 transfold ----
    transfold<<<dim3(C_MOL / 32, C_MOL / 32, H_HEADS), 256, 0, stream>>>(
        mol_W, WtM, mol_asrc, mol_adst, wsrcM, wdstM, C_MOL, C_MOL, (size_t)C_MOL, 3 * C_MOL);
    transfold<<<dim3(C_PROT / 32, C_PROT / 32, H_HEADS), 256, 0, stream>>>(
        prot_W, WtP, prot_asrc, prot_adst, wsrcP, wdstP, C_PROT, C_PROT, (size_t)C_PROT,
        3 * C_PROT);

    // ---- layer-0 features + logits ----
    f32_to_bf16<<<(N_PROT * C_PROT + 255) / 256, 256, 0, stream>>>(prot_in, x_prot, N_PROT * C_PROT);
    embed_mean_kernel<<<N_MOL, C_MOL, 0, stream>>>(drug_x, emb, x_mol);
    pool_atomic<C_MOL, 8><<<dim3(G_MOL, 8), C_MOL / 4, 0, stream>>>(x_mol, mol_goff, out_mol, 0);
    pool_atomic<C_PROT, 64><<<dim3(G_PROT, 64), C_PROT / 4, 0, stream>>>(x_prot, prot_goff,
                                                                         out_prot, 0);
    attn_logits<C_MOL><<<N_MOL, 64, 0, stream>>>(x_mol, wsrcM, wdstM, alsM, aldM);
    attn_logits<C_PROT><<<N_PROT, 64, 0, stream>>>(x_prot, wsrcP, wdstP, alsP, aldP);

    const int gMol = (C_MOL / 256) * (MPAD_MOL / 128);    // 626
    const int gProt = (C_PROT / 256) * (MPAD_PROT / 128); // 315

    for (int l = 0; l < LAYERS; ++l) {
        const int last = (l == LAYERS - 1);
        if (BIG) {
            // both aggregates, then one merged GEMM (prot first = heavy-first LPT)
            alpha_kernel2<<<(N_MOL * H_HEADS + 255) / 256, 256, 0, stream>>>(
                alsM, aldM, mol_indptr, mol_srcl, alphaw, N_MOL);
            aggregate_mol<<<N_MOL / 4, 256, 0, stream>>>(x_mol, alphaw, mol_indptr, mol_srcl, aggM);
            alpha_kernel2<<<(N_PROT * H_HEADS + 255) / 256, 256, 0, stream>>>(
                alsP, aldP, prot_indptr, prot_srcl, alphaw, N_PROT);
            aggregate_all3<C_PROT><<<N_PROT, C_PROT / 4, 0, stream>>>(x_prot, alphaw, prot_indptr,
                                                                      prot_srcl, aggP);
            gemm_dual<<<gProt + gMol, 512, 0, stream>>>(
                aggP, WtP, x_prot, C_PROT, 3 * C_PROT, C_PROT / 256, N_PROT, gProt,
                aggM, WtM, x_mol, C_MOL, 3 * C_MOL, C_MOL / 256, N_MOL);
            if (!last) {
                transfold<<<dim3(C_MOL / 32, C_MOL / 32, H_HEADS), 256, 0, stream>>>(
                    mol_W + (size_t)(l + 1) * C_MOL * (H_HEADS * C_MOL), WtM,
                    mol_asrc + (size_t)(l + 1) * H_HEADS * C_MOL,
                    mol_adst + (size_t)(l + 1) * H_HEADS * C_MOL,
                    wsrcM + (size_t)(l + 1) * H_HEADS * C_MOL,
                    wdstM + (size_t)(l + 1) * H_HEADS * C_MOL, C_MOL, C_MOL, (size_t)C_MOL,
                    3 * C_MOL);
                transfold<<<dim3(C_PROT / 32, C_PROT / 32, H_HEADS), 256, 0, stream>>>(
                    prot_W + (size_t)(l + 1) * C_PROT * (H_HEADS * C_PROT), WtP,
                    prot_asrc + (size_t)(l + 1) * H_HEADS * C_PROT,
                    prot_adst + (size_t)(l + 1) * H_HEADS * C_PROT,
                    wsrcP + (size_t)(l + 1) * H_HEADS * C_PROT,
                    wdstP + (size_t)(l + 1) * H_HEADS * C_PROT, C_PROT, C_PROT, (size_t)C_PROT,
                    3 * C_PROT);
                ln_kernel<C_MOL, 1><<<N_MOL, 256, 0, stream>>>(
                    x_mol, mol_bias + (size_t)l * C_MOL, mol_lng + (size_t)l * C_MOL,
                    mol_lnb + (size_t)l * C_MOL, wsrcM + (size_t)(l + 1) * H_HEADS * C_MOL,
                    wdstM + (size_t)(l + 1) * H_HEADS * C_MOL, alsM, aldM);
                ln_kernel<C_PROT, 1><<<N_PROT, 256, 0, stream>>>(
                    x_prot, prot_bias + (size_t)l * C_PROT, prot_lng + (size_t)l * C_PROT,
                    prot_lnb + (size_t)l * C_PROT, wsrcP + (size_t)(l + 1) * H_HEADS * C_PROT,
                    wdstP + (size_t)(l + 1) * H_HEADS * C_PROT, alsP, aldP);
            } else {
                ln_kernel<C_MOL, 0><<<N_MOL, 256, 0, stream>>>(
                    x_mol, mol_bias + (size_t)l * C_MOL, mol_lng + (size_t)l * C_MOL,
                    mol_lnb + (size_t)l * C_MOL, nullptr, nullptr, nullptr, nullptr);
                ln_kernel<C_PROT, 0><<<N_PROT, 256, 0, stream>>>(
                    x_prot, prot_bias + (size_t)l * C_PROT, prot_lng + (size_t)l * C_PROT,
                    prot_lnb + (size_t)l * C_PROT, nullptr, nullptr, nullptr, nullptr);
            }
            pool_atomic<C_MOL, 8><<<dim3(G_MOL, 8), C_MOL / 4, 0, stream>>>(x_mol, mol_goff,
                                                                            out_mol, l + 1);
            pool_atomic<C_PROT, 64><<<dim3(G_PROT, 64), C_PROT / 4, 0, stream>>>(
                x_prot, prot_goff, out_prot, l + 1);
        } else {
            // fallback: R8 serial ordering (aggP aliases aggM)
            alpha_kernel2<<<(N_MOL * H_HEADS + 255) / 256, 256, 0, stream>>>(
                alsM, aldM, mol_indptr, mol_srcl, alphaw, N_MOL);
            aggregate_mol<<<N_MOL / 4, 256, 0, stream>>>(x_mol, alphaw, mol_indptr, mol_srcl, aggM);
            gemm_dual<<<gMol, 512, 0, stream>>>(
                aggM, WtM, x_mol, C_MOL, 3 * C_MOL, C_MOL / 256, N_MOL, gMol,
                aggM, WtM, x_mol, C_MOL, 3 * C_MOL, C_MOL / 256, N_MOL);
            if (!last)
                transfold<<<dim3(C_MOL / 32, C_MOL / 32, H_HEADS), 256, 0, stream>>>(
                    mol_W + (size_t)(l + 1) * C_MOL * (H_HEADS * C_MOL), WtM,
                    mol_asrc + (size_t)(l + 1) * H_HEADS * C_MOL,
                    mol_adst + (size_t)(l + 1) * H_HEADS * C_MOL,
                    wsrcM + (size_t)(l + 1) * H_HEADS * C_MOL,
                    wdstM + (size_t)(l + 1) * H_HEADS * C_MOL, C_MOL, C_MOL, (size_t)C_MOL,
                    3 * C_MOL);
            if (last)
                ln_kernel<C_MOL, 0><<<N_MOL, 256, 0, stream>>>(
                    x_mol, mol_bias + (size_t)l * C_MOL, mol_lng + (size_t)l * C_MOL,
                    mol_lnb + (size_t)l * C_MOL, nullptr, nullptr, nullptr, nullptr);
            else
                ln_kernel<C_MOL, 1><<<N_MOL, 256, 0, stream>>>(
                    x_mol, mol_bias + (size_t)l * C_MOL, mol_lng + (size_t)l * C_MOL,
                    mol_lnb + (size_t)l * C_MOL, wsrcM + (size_t)(l + 1) * H_HEADS * C_MOL,
                    wdstM + (size_t)(l + 1) * H_HEADS * C_MOL, alsM, aldM);
            pool_atomic<C_MOL, 8><<<dim3(G_MOL, 8), C_MOL / 4, 0, stream>>>(x_mol, mol_goff,
                                                                            out_mol, l + 1);
            alpha_kernel2<<<(N_PROT * H_HEADS + 255) / 256, 256, 0, stream>>>(
                alsP, aldP, prot_indptr, prot_srcl, alphaw, N_PROT);
            aggregate_all3<C_PROT><<<N_PROT, C_PROT / 4, 0, stream>>>(x_prot, alphaw, prot_indptr,
                                                                      prot_srcl, aggP);
            gemm_dual<<<gProt, 512, 0, stream>>>(
                aggP, WtP, x_prot, C_PROT, 3 * C_PROT, C_PROT / 256, N_PROT, gProt,
                aggP, WtP, x_prot, C_PROT, 3 * C_PROT, C_PROT / 256, N_PROT);
            if (!last)
                transfold<<<dim3(C_PROT / 32, C_PROT / 32, H_HEADS), 256, 0, stream>>>(
                    prot_W + (size_t)(l + 1) * C_PROT * (H_HEADS * C_PROT), WtP,
                    prot_asrc + (size_t)(l + 1) * H_HEADS * C_PROT,
                    prot_adst + (size_t)(l + 1) * H_HEADS * C_PROT,
                    wsrcP + (size_t)(l + 1) * H_HEADS * C_PROT,
                    wdstP + (size_t)(l + 1) * H_HEADS * C_PROT, C_PROT, C_PROT, (size_t)C_PROT,
                    3 * C_PROT);
            if (last)
                ln_kernel<C_PROT, 0><<<N_PROT, 256, 0, stream>>>(
                    x_prot, prot_bias + (size_t)l * C_PROT, prot_lng + (size_t)l * C_PROT,
                    prot_lnb + (size_t)l * C_PROT, nullptr, nullptr, nullptr, nullptr);
            else
                ln_kernel<C_PROT, 1><<<N_PROT, 256, 0, stream>>>(
                    x_prot, prot_bias + (size_t)l * C_PROT, prot_lng + (size_t)l * C_PROT,
                    prot_lnb + (size_t)l * C_PROT, wsrcP + (size_t)(l + 1) * H_HEADS * C_PROT,
                    wdstP + (size_t)(l + 1) * H_HEADS * C_PROT, alsP, aldP);
            pool_atomic<C_PROT, 64><<<dim3(G_PROT, 64), C_PROT / 4, 0, stream>>>(
                x_prot, prot_goff, out_prot, l + 1);
        }
    }
}

// Round 10
// 2289.917 us; speedup vs baseline: 1.1140x; 1.0235x over previous
//
#include <hip/hip_runtime.h>
#include <cstdint>

// R10: isolated GEMM change — m97-structure 128x128 tile (32KB LDS, 4 waves,
// single-buffer 2-barrier loop) to get 4-5 blocks/CU inter-block overlap
// (R9 showed 1 block/CU = 21% occupancy; dbuf/vmcnt at that residency = neutral).
// Dual-problem dispatch + per-range bijective XCD swizzle kept from R9.
// Everything else identical to R9.

constexpr int H_HEADS = 3;
constexpr float NEG_SLOPE = 0.2f;
constexpr float LN_EPS = 1e-5f;
constexpr int N_MOL = 40000, E_MOL = 80000, C_MOL = 512, G_MOL = 512;
constexpr int N_PROT = 8000, E_PROT = 64000, C_PROT = 1280, G_PROT = 32;
constexpr int LAYERS = 4;
constexpr int MPAD_MOL = 40064;
constexpr int MPAD_PROT = 8064;

typedef unsigned short u16;
typedef __attribute__((ext_vector_type(8))) short short8v;
typedef __attribute__((ext_vector_type(4))) unsigned short ushort4v;
typedef __attribute__((ext_vector_type(4))) float f32x4;

__device__ __forceinline__ float bf2f(u16 s) {
    union { unsigned u; float f; } v; v.u = ((unsigned)s) << 16; return v.f;
}
__device__ __forceinline__ u16 f2bf(float f) {
    union { float f; unsigned u; } v; v.f = f;
    return (u16)((v.u + 0x7fffu + ((v.u >> 16) & 1u)) >> 16);
}

__device__ __forceinline__ void g2l16(const void* g, void* l) {
    __builtin_amdgcn_global_load_lds((const __attribute__((address_space(1))) void*)g,
                                     (__attribute__((address_space(3))) void*)l, 16, 0, 0);
}

// ---------------- small utility kernels ----------------

__global__ void set_int_kernel(int* p, int v, int n) {
    int i = blockIdx.x * blockDim.x + threadIdx.x;
    if (i < n) p[i] = v;
}

__global__ void zero_f32_kernel(float* p, int n) {
    int i = blockIdx.x * blockDim.x + threadIdx.x;
    if (i < n) p[i] = 0.f;
}

__global__ void copy_int_kernel(const int* __restrict__ s, int* __restrict__ d, int n) {
    int i = blockIdx.x * blockDim.x + threadIdx.x;
    if (i < n) d[i] = s[i];
}

__global__ void hist_kernel(const int* __restrict__ keys, int n, int* __restrict__ cnt) {
    int i = blockIdx.x * blockDim.x + threadIdx.x;
    if (i < n) atomicAdd(&cnt[keys[i]], 1);
}

__global__ void scan_kernel(const int* __restrict__ in, int* __restrict__ out, int n) {
    __shared__ int sums[1024];
    const int t = threadIdx.x;
    const int chunk = (n + 1023) / 1024;
    const int start = t * chunk;
    const int end = min(start + chunk, n);
    int s = 0;
    for (int i = start; i < end; ++i) s += in[i];
    sums[t] = s;
    __syncthreads();
    if (t == 0) {
        int acc = 0;
        for (int i = 0; i < 1024; ++i) { int v = sums[i]; sums[i] = acc; acc += v; }
        out[n] = acc;
    }
    __syncthreads();
    int acc = sums[t];
    for (int i = start; i < end; ++i) { out[i] = acc; acc += in[i]; }
}

__global__ void fill_self_kernel(int* __restrict__ pos, int* __restrict__ srcl, int n) {
    int i = blockIdx.x * blockDim.x + threadIdx.x;
    if (i < n) { int slot = atomicAdd(&pos[i], 1); srcl[slot] = i; }
}

__global__ void fill_edge_kernel(const int* __restrict__ src, const int* __restrict__ dst, int e,
                                 int* __restrict__ pos, int* __restrict__ srcl) {
    int i = blockIdx.x * blockDim.x + threadIdx.x;
    if (i < e) { int slot = atomicAdd(&pos[dst[i]], 1); srcl[slot] = src[i]; }
}

__global__ void f32_to_bf16(const float* __restrict__ in, u16* __restrict__ out, int n) {
    int i = blockIdx.x * blockDim.x + threadIdx.x;
    if (i < n) out[i] = f2bf(in[i]);
}

// ---------------- embedding mean -> bf16 ----------------

__global__ void embed_mean_kernel(const int* __restrict__ drug_x, const float* __restrict__ emb,
                                  u16* __restrict__ out) {
    const int n = blockIdx.x;
    __shared__ int idx[9];
    if (threadIdx.x < 9) idx[threadIdx.x] = drug_x[n * 9 + threadIdx.x];
    __syncthreads();
    const int c = threadIdx.x;
    float s = 0.f;
#pragma unroll
    for (int t = 0; t < 9; ++t) s += emb[(size_t)idx[t] * C_MOL + c];
    out[(size_t)n * C_MOL + c] = f2bf(s * (1.f / 9.f));
}

// ---------------- fused transpose + fold ----------------

__global__ __launch_bounds__(256) void transfold(const float* __restrict__ W, u16* __restrict__ Wt,
                                                 const float* __restrict__ asrc,
                                                 const float* __restrict__ adst,
                                                 float* __restrict__ wsrc, float* __restrict__ wdst,
                                                 int CIN, int COUT, size_t headStride, int ldn) {
    __shared__ float t[32][33];
    __shared__ float rs[8][33], rd[8][33];
    const int h = blockIdx.z;
    const int n0 = blockIdx.x * 32, k0 = blockIdx.y * 32;
    const int tx = threadIdx.x & 31, ty = threadIdx.x >> 5;
#pragma unroll
    for (int q = 0; q < 4; ++q)
        t[ty + q * 8][tx] = W[(size_t)(k0 + ty + q * 8) * (H_HEADS * COUT) + h * COUT + n0 + tx];
    __syncthreads();
#pragma unroll
    for (int q = 0; q < 4; ++q)
        Wt[(size_t)h * headStride + (size_t)(n0 + ty + q * 8) * ldn + k0 + tx] =
            f2bf(t[tx][ty + q * 8]);
    float ps = 0.f, pd = 0.f;
    const float* as = asrc + h * COUT + n0;
    const float* ad = adst + h * COUT + n0;
#pragma unroll
    for (int q = 0; q < 4; ++q) {
        const float w = t[tx][ty + q * 8];
        ps += w * as[ty + q * 8];
        pd += w * ad[ty + q * 8];
    }
    rs[ty][tx] = ps;
    rd[ty][tx] = pd;
    __syncthreads();
    if (ty == 0) {
        float s = 0.f, d = 0.f;
#pragma unroll
        for (int j = 0; j < 8; ++j) { s += rs[j][tx]; d += rd[j][tx]; }
        atomicAdd(&wsrc[h * CIN + k0 + tx], s);
        atomicAdd(&wdst[h * CIN + k0 + tx], d);
    }
}

// ---------------- attention logits (layer 0 only) ----------------

template <int C>
__global__ void attn_logits(const u16* __restrict__ x, const float* __restrict__ wsrc,
                            const float* __restrict__ wdst, float* __restrict__ als,
                            float* __restrict__ ald) {
    constexpr int PER = C / 64;
    const int n = blockIdx.x, lane = threadIdx.x;
    const u16* xr = x + (size_t)n * C + lane * PER;
    float xv[PER];
#pragma unroll
    for (int i = 0; i < PER; i += 4) {
        const ushort4v v = *(const ushort4v*)(xr + i);
        xv[i] = bf2f(v.x); xv[i + 1] = bf2f(v.y); xv[i + 2] = bf2f(v.z); xv[i + 3] = bf2f(v.w);
    }
    for (int h = 0; h < H_HEADS; ++h) {
        const float* ws = wsrc + h * C + lane * PER;
        const float* wd = wdst + h * C + lane * PER;
        float ss = 0.f, sd = 0.f;
#pragma unroll
        for (int i = 0; i < PER; i += 4) {
            const float4 a = *(const float4*)(ws + i);
            const float4 b = *(const float4*)(wd + i);
            ss += xv[i] * a.x + xv[i + 1] * a.y + xv[i + 2] * a.z + xv[i + 3] * a.w;
            sd += xv[i] * b.x + xv[i + 1] * b.y + xv[i + 2] * b.z + xv[i + 3] * b.w;
        }
        for (int o = 32; o; o >>= 1) { ss += __shfl_down(ss, o); sd += __shfl_down(sd, o); }
        if (lane == 0) { als[n * H_HEADS + h] = ss; ald[n * H_HEADS + h] = sd; }
    }
}

// ---------------- segment softmax: one thread per (node, head) ----------------

__global__ void alpha_kernel2(const float* __restrict__ als, const float* __restrict__ ald,
                              const int* __restrict__ indptr, const int* __restrict__ srcl,
                              float* __restrict__ alphaw, int n_nodes) {
    const int t = blockIdx.x * blockDim.x + threadIdx.x;
    const int n = t / H_HEADS, h = t - n * H_HEADS;
    if (n >= n_nodes) return;
    const int beg = indptr[n], end = indptr[n + 1];
    const float ad = ald[n * H_HEADS + h];
    float m = -1e30f;
    for (int e = beg; e < end; ++e) {
        float v = als[srcl[e] * H_HEADS + h] + ad;
        v = v >= 0.f ? v : NEG_SLOPE * v;
        m = fmaxf(m, v);
    }
    float z = 0.f;
    for (int e = beg; e < end; ++e) {
        float v = als[srcl[e] * H_HEADS + h] + ad;
        v = v >= 0.f ? v : NEG_SLOPE * v;
        z += __expf(v - m);
    }
    const float zi = 1.f / (z + 1e-16f);
    for (int e = beg; e < end; ++e) {
        float v = als[srcl[e] * H_HEADS + h] + ad;
        v = v >= 0.f ? v : NEG_SLOPE * v;
        alphaw[e * H_HEADS + h] = __expf(v - m) * zi;
    }
}

// ---------------- mol aggregation: wave per node, 16B loads ----------------

__global__ __launch_bounds__(256) void aggregate_mol(const u16* __restrict__ x,
                                                     const float* __restrict__ alphaw,
                                                     const int* __restrict__ indptr,
                                                     const int* __restrict__ srcl,
                                                     u16* __restrict__ agg) {
    const int wv = threadIdx.x >> 6, lane = threadIdx.x & 63;
    const int n = blockIdx.x * 4 + wv;
    const int beg = indptr[n], end = indptr[n + 1];
    float acc[H_HEADS][8];
#pragma unroll
    for (int h = 0; h < H_HEADS; ++h)
#pragma unroll
        for (int j = 0; j < 8; ++j) acc[h][j] = 0.f;
    for (int e = beg; e < end; ++e) {
        const float a0 = alphaw[e * H_HEADS + 0];
        const float a1 = alphaw[e * H_HEADS + 1];
        const float a2 = alphaw[e * H_HEADS + 2];
        const short8v row = *(const short8v*)(x + (size_t)srcl[e] * C_MOL + lane * 8);
#pragma unroll
        for (int j = 0; j < 8; ++j) {
            const float f = bf2f((u16)row[j]);
            acc[0][j] += a0 * f; acc[1][j] += a1 * f; acc[2][j] += a2 * f;
        }
    }
    u16* o = agg + (size_t)n * (3 * C_MOL) + lane * 8;
#pragma unroll
    for (int h = 0; h < H_HEADS; ++h) {
        short8v r;
#pragma unroll
        for (int j = 0; j < 8; ++j) r[j] = (short)f2bf(acc[h][j]);
        *(short8v*)(o + h * C_MOL) = r;
    }
}

// ---------------- prot aggregation: block C/4 = 320 threads per node ----------------

template <int C>
__global__ void aggregate_all3(const u16* __restrict__ x, const float* __restrict__ alphaw,
                               const int* __restrict__ indptr, const int* __restrict__ srcl,
                               u16* __restrict__ agg) {
    const int n = blockIdx.x, tid = threadIdx.x;
    const int beg = indptr[n], end = indptr[n + 1];
    float acc[H_HEADS][4];
#pragma unroll
    for (int h = 0; h < H_HEADS; ++h)
#pragma unroll
        for (int j = 0; j < 4; ++j) acc[h][j] = 0.f;
    for (int e = beg; e < end; ++e) {
        const float a0 = alphaw[e * H_HEADS + 0];
        const float a1 = alphaw[e * H_HEADS + 1];
        const float a2 = alphaw[e * H_HEADS + 2];
        const ushort4v v = *(const ushort4v*)(x + (size_t)srcl[e] * C + tid * 4);
        const float f0 = bf2f(v.x), f1 = bf2f(v.y), f2 = bf2f(v.z), f3 = bf2f(v.w);
        acc[0][0] += a0 * f0; acc[0][1] += a0 * f1; acc[0][2] += a0 * f2; acc[0][3] += a0 * f3;
        acc[1][0] += a1 * f0; acc[1][1] += a1 * f1; acc[1][2] += a1 * f2; acc[1][3] += a1 * f3;
        acc[2][0] += a2 * f0; acc[2][1] += a2 * f1; acc[2][2] += a2 * f2; acc[2][3] += a2 * f3;
    }
    u16* o = agg + (size_t)n * (3 * C) + tid * 4;
#pragma unroll
    for (int h = 0; h < H_HEADS; ++h) {
        ushort4v r;
        r.x = f2bf(acc[h][0]); r.y = f2bf(acc[h][1]); r.z = f2bf(acc[h][2]); r.w = f2bf(acc[h][3]);
        *(ushort4v*)(o + h * C) = r;
    }
}

// ---------------- GEMM: 128x128 tile, BK=64, 4 waves, 32KB LDS, single-buffer ----------------
// m97 structure: small LDS footprint -> 4-5 blocks/CU -> inter-block wave overlap
// hides the barrier drain (m114). Proven R4 inner loop + R5 swizzle + XCD swizzle.

__global__ __launch_bounds__(256) void gemm128d(
    const u16* __restrict__ A0, const u16* __restrict__ B0, u16* __restrict__ C0,
    int N0, int K0, int nx0, int M0, int g0,
    const u16* __restrict__ A1, const u16* __restrict__ B1, u16* __restrict__ C1,
    int N1, int K1, int nx1, int M1) {
    __shared__ u16 lds[16384];  // A[128][64] @0, B[128][64] @8192 (32KB)
    const int tid = threadIdx.x;
    const int w = tid >> 6, l = tid & 63;
    const int wr = w >> 1, wc = w & 1;

    // problem select + per-range bijective XCD swizzle (n-fastest within range)
    const int bid = blockIdx.x;
    const u16 *A, *Bt;
    u16* Cout;
    int N, K, nxch, Mreal, base, sz;
    if (bid < g0) { base = 0; sz = g0; A = A0; Bt = B0; Cout = C0; N = N0; K = K0; nxch = nx0; Mreal = M0; }
    else { base = g0; sz = gridDim.x - g0; A = A1; Bt = B1; Cout = C1; N = N1; K = K1; nxch = nx1; Mreal = M1; }
    const int j = bid - base;
    const int q = sz >> 3, r = sz & 7;
    const int xcd = j & 7, idx = j >> 3;
    const int wg = (xcd < r ? xcd * (q + 1) : r * (q + 1) + (xcd - r) * q) + idx;
    const int nx = wg % nxch, my = wg / nxch;
    const size_t bm = (size_t)my * 128, bn = (size_t)nx * 128;

    const f32x4 zf = {0.f, 0.f, 0.f, 0.f};
    f32x4 acc[4][4];
#pragma unroll
    for (int i = 0; i < 4; ++i)
#pragma unroll
        for (int jj = 0; jj < 4; ++jj) acc[i][jj] = zf;

    // staging: wave w covers rows [w*32, w*32+32) of both A and B tiles
    const int srow = w * 32 + (l >> 3);
    const int sseg = (l & 7) ^ (l >> 3);  // pre-swizzled global segment (row&7 == l>>3)
    const u16* Ab = A + (bm + srow) * (size_t)K + sseg * 8;
    const u16* Bb = Bt + (bn + srow) * (size_t)K + sseg * 8;

    for (int k0 = 0; k0 < K; k0 += 64) {
#pragma unroll
        for (int qq = 0; qq < 4; ++qq)
            g2l16(Ab + k0 + (size_t)qq * 8 * K, lds + (w * 4 + qq) * 512);
#pragma unroll
        for (int qq = 0; qq < 4; ++qq)
            g2l16(Bb + k0 + (size_t)qq * 8 * K, lds + 8192 + (w * 4 + qq) * 512);
        __syncthreads();
#pragma unroll
        for (int kk = 0; kk < 2; ++kk) {
            const int sg = ((kk * 4 + (l >> 4)) ^ (l & 7)) * 8;
            short8v af[4], bf8[4];
#pragma unroll
            for (int fm = 0; fm < 4; ++fm) {
                const int row = wr * 64 + fm * 16 + (l & 15);
                af[fm] = *(const short8v*)&lds[row * 64 + sg];
            }
#pragma unroll
            for (int fn = 0; fn < 4; ++fn) {
                const int row = wc * 64 + fn * 16 + (l & 15);
                bf8[fn] = *(const short8v*)&lds[8192 + row * 64 + sg];
            }
#pragma unroll
            for (int fm = 0; fm < 4; ++fm)
#pragma unroll
                for (int fn = 0; fn < 4; ++fn)
                    acc[fm][fn] = __builtin_amdgcn_mfma_f32_16x16x32_bf16(af[fm], bf8[fn],
                                                                          acc[fm][fn], 0, 0, 0);
        }
        __syncthreads();
    }

    // epilogue: two 64-row halves through LDS (stride 136 u16 = 8704/half, fits 16384)
#pragma unroll
    for (int half = 0; half < 2; ++half) {
        if (wr == half) {
#pragma unroll
            for (int fm = 0; fm < 4; ++fm)
#pragma unroll
                for (int fn = 0; fn < 4; ++fn) {
                    const int col = wc * 64 + fn * 16 + (l & 15);
#pragma unroll
                    for (int rr = 0; rr < 4; ++rr)
                        lds[(fm * 16 + (l >> 4) * 4 + rr) * 136 + col] = f2bf(acc[fm][fn][rr]);
                }
        }
        __syncthreads();
        const int lrow = tid >> 2, lseg = tid & 3;  // 4 threads/row, 64B each
        const size_t grow = bm + half * 64 + lrow;
        if (grow < (size_t)Mreal) {
            u16* Crow = Cout + grow * (size_t)N + bn + lseg * 32;
            const u16* Lr = lds + lrow * 136 + lseg * 32;
#pragma unroll
            for (int ii = 0; ii < 4; ++ii)
                *(float4*)(Crow + ii * 8) = *(const float4*)(Lr + ii * 8);
        }
        __syncthreads();
    }
}

// ---------------- in-place scale + bias + LayerNorm (+ next-layer logits) ----------------

template <int C, int LOGITS>
__global__ __launch_bounds__(256) void ln_kernel(u16* __restrict__ x,
                                                 const float* __restrict__ bias,
                                                 const float* __restrict__ g,
                                                 const float* __restrict__ b,
                                                 const float* __restrict__ wsrc_n,
                                                 const float* __restrict__ wdst_n,
                                                 float* __restrict__ als, float* __restrict__ ald) {
    constexpr int PER = C / 256;
    const int n = blockIdx.x, tid = threadIdx.x;
    u16* xr = x + (size_t)n * C;
    float vals[PER];
    float s1 = 0.f, s2 = 0.f;
    constexpr float invH = 1.f / (float)H_HEADS;
#pragma unroll
    for (int i = 0; i < PER; ++i) {
        const int c = i * 256 + tid;
        const float v = bf2f(xr[c]) * invH + bias[c];
        vals[i] = v;
        s1 += v;
        s2 += v * v;
    }
    __shared__ float red[2][4];
    __shared__ float red2[4][6];
    for (int o = 32; o; o >>= 1) { s1 += __shfl_down(s1, o); s2 += __shfl_down(s2, o); }
    if ((tid & 63) == 0) { red[0][tid >> 6] = s1; red[1][tid >> 6] = s2; }
    __syncthreads();
    const float t1 = red[0][0] + red[0][1] + red[0][2] + red[0][3];
    const float t2 = red[1][0] + red[1][1] + red[1][2] + red[1][3];
    const float mu = t1 / C;
    const float var = t2 / C - mu * mu;
    const float rstd = rsqrtf(var + LN_EPS);
    float ps0 = 0.f, ps1 = 0.f, ps2 = 0.f, pd0 = 0.f, pd1 = 0.f, pd2 = 0.f;
#pragma unroll
    for (int i = 0; i < PER; ++i) {
        const int c = i * 256 + tid;
        const u16 xq16 = f2bf((vals[i] - mu) * rstd * g[c] + b[c]);
        xr[c] = xq16;
        if (LOGITS) {
            const float xq = bf2f(xq16);
            ps0 += xq * wsrc_n[0 * C + c]; pd0 += xq * wdst_n[0 * C + c];
            ps1 += xq * wsrc_n[1 * C + c]; pd1 += xq * wdst_n[1 * C + c];
            ps2 += xq * wsrc_n[2 * C + c]; pd2 += xq * wdst_n[2 * C + c];
        }
    }
    if (LOGITS) {
        for (int o = 32; o; o >>= 1) {
            ps0 += __shfl_down(ps0, o); ps1 += __shfl_down(ps1, o); ps2 += __shfl_down(ps2, o);
            pd0 += __shfl_down(pd0, o); pd1 += __shfl_down(pd1, o); pd2 += __shfl_down(pd2, o);
        }
        __syncthreads();
        if ((tid & 63) == 0) {
            const int wv = tid >> 6;
            red2[wv][0] = ps0; red2[wv][1] = ps1; red2[wv][2] = ps2;
            red2[wv][3] = pd0; red2[wv][4] = pd1; red2[wv][5] = pd2;
        }
        __syncthreads();
        if (tid == 0) {
#pragma unroll
            for (int h = 0; h < H_HEADS; ++h) {
                als[n * H_HEADS + h] = red2[0][h] + red2[1][h] + red2[2][h] + red2[3][h];
                ald[n * H_HEADS + h] =
                    red2[0][3 + h] + red2[1][3 + h] + red2[2][3 + h] + red2[3][3 + h];
            }
        }
    }
}

// ---------------- segmented atomic mean-pool ----------------

template <int C, int S>
__global__ void pool_atomic(const u16* __restrict__ x, const int* __restrict__ goff,
                            float* __restrict__ out, int layer) {
    const int g = blockIdx.x, seg = blockIdx.y;
    const int beg = goff[g], end = goff[g + 1];
    const int len = end - beg;
    const int s0 = beg + (len * seg) / S;
    const int s1 = beg + (len * (seg + 1)) / S;
    if (s0 >= s1) return;
    const float inv = 1.f / fmaxf((float)len, 1.f);
    const int tid = threadIdx.x;
    float a0 = 0.f, a1 = 0.f, a2 = 0.f, a3 = 0.f;
    for (int n = s0; n < s1; ++n) {
        const ushort4v v = *(const ushort4v*)(x + (size_t)n * C + tid * 4);
        a0 += bf2f(v.x); a1 += bf2f(v.y); a2 += bf2f(v.z); a3 += bf2f(v.w);
    }
    float* o = out + ((size_t)g * (LAYERS + 1) + layer) * C + tid * 4;
    atomicAdd(o + 0, a0 * inv);
    atomicAdd(o + 1, a1 * inv);
    atomicAdd(o + 2, a2 * inv);
    atomicAdd(o + 3, a3 * inv);
}

// ---------------- launch ----------------

extern "C" void kernel_launch(void* const* d_in, const int* in_sizes, int n_in, void* d_out,
                              int out_size, void* d_ws, size_t ws_size, hipStream_t stream) {
    const int* drug_x      = (const int*)d_in[0];
    const int* mol_ei      = (const int*)d_in[1];
    const int* mol_batch   = (const int*)d_in[2];
    const float* prot_in   = (const float*)d_in[3];
    const int* prot_ei     = (const int*)d_in[4];
    const int* prot_batch  = (const int*)d_in[5];
    const float* emb       = (const float*)d_in[6];
    const float* mol_W     = (const float*)d_in[7];
    const float* mol_asrc  = (const float*)d_in[8];
    const float* mol_adst  = (const float*)d_in[9];
    const float* mol_bias  = (const float*)d_in[10];
    const float* mol_lng   = (const float*)d_in[11];
    const float* mol_lnb   = (const float*)d_in[12];
    const float* prot_W    = (const float*)d_in[13];
    const float* prot_asrc = (const float*)d_in[14];
    const float* prot_adst = (const float*)d_in[15];
    const float* prot_bias = (const float*)d_in[16];
    const float* prot_lng  = (const float*)d_in[17];
    const float* prot_lnb  = (const float*)d_in[18];

    if (ws_size < (size_t)240500000) return;            // proven lower bound
    const bool BIG = ws_size >= (size_t)262000000;      // dual-GEMM path (proven in R9)

    char* base = (char*)d_ws;
    size_t off = 0;
    auto alloc = [&](size_t bytes) -> void* {
        void* r = base + off;
        off = (off + bytes + 255) & ~(size_t)255;
        return r;
    };
    u16* x_mol  = (u16*)alloc((size_t)N_MOL * C_MOL * 2);
    u16* x_prot = (u16*)alloc((size_t)N_PROT * C_PROT * 2);
    u16* aggM   = (u16*)alloc((size_t)3 * MPAD_MOL * C_MOL * 2);
    u16* WtM    = (u16*)alloc((size_t)H_HEADS * C_MOL * C_MOL * 2);
    u16* WtP    = (u16*)alloc((size_t)H_HEADS * C_PROT * C_PROT * 2);
    u16* aggP   = BIG ? (u16*)alloc((size_t)3 * MPAD_PROT * C_PROT * 2) : aggM;
    float* wsrcM = (float*)alloc((size_t)LAYERS * H_HEADS * C_MOL * 4);
    float* wdstM = (float*)alloc((size_t)LAYERS * H_HEADS * C_MOL * 4);
    float* wsrcP = (float*)alloc((size_t)LAYERS * H_HEADS * C_PROT * 4);
    float* wdstP = (float*)alloc((size_t)LAYERS * H_HEADS * C_PROT * 4);
    float* alsM = (float*)alloc((size_t)N_MOL * H_HEADS * 4);
    float* aldM = (float*)alloc((size_t)N_MOL * H_HEADS * 4);
    float* alsP = (float*)alloc((size_t)N_PROT * H_HEADS * 4);
    float* aldP = (float*)alloc((size_t)N_PROT * H_HEADS * 4);
    float* alphaw = (float*)alloc((size_t)(E_MOL + N_MOL) * H_HEADS * 4);
    int* mol_indptr  = (int*)alloc((N_MOL + 1) * 4);
    int* mol_pos     = (int*)alloc(N_MOL * 4);
    int* mol_srcl    = (int*)alloc((E_MOL + N_MOL) * 4);
    int* prot_indptr = (int*)alloc((N_PROT + 1) * 4);
    int* prot_pos    = (int*)alloc(N_PROT * 4);
    int* prot_srcl   = (int*)alloc((E_PROT + N_PROT) * 4);
    int* cnt         = (int*)alloc(N_MOL * 4);
    int* mol_goff    = (int*)alloc((G_MOL + 1) * 4);
    int* prot_goff   = (int*)alloc((G_PROT + 1) * 4);
    int* gcnt        = (int*)alloc(G_MOL * 4);

    float* out_mol  = (float*)d_out;
    float* out_prot = (float*)d_out + (size_t)G_MOL * (LAYERS + 1) * C_MOL;

    zero_f32_kernel<<<(out_size + 255) / 256, 256, 0, stream>>>((float*)d_out, out_size);
    zero_f32_kernel<<<(LAYERS * H_HEADS * C_MOL + 255) / 256, 256, 0, stream>>>(
        wsrcM, LAYERS * H_HEADS * C_MOL);
    zero_f32_kernel<<<(LAYERS * H_HEADS * C_MOL + 255) / 256, 256, 0, stream>>>(
        wdstM, LAYERS * H_HEADS * C_MOL);
    zero_f32_kernel<<<(LAYERS * H_HEADS * C_PROT + 255) / 256, 256, 0, stream>>>(
        wsrcP, LAYERS * H_HEADS * C_PROT);
    zero_f32_kernel<<<(LAYERS * H_HEADS * C_PROT + 255) / 256, 256, 0, stream>>>(
        wdstP, LAYERS * H_HEADS * C_PROT);

    // ---- CSR (incoming lists incl. self loops) ----
    set_int_kernel<<<(N_MOL + 255) / 256, 256, 0, stream>>>(cnt, 1, N_MOL);
    hist_kernel<<<(E_MOL + 255) / 256, 256, 0, stream>>>(mol_ei + E_MOL, E_MOL, cnt);
    scan_kernel<<<1, 1024, 0, stream>>>(cnt, mol_indptr, N_MOL);
    copy_int_kernel<<<(N_MOL + 255) / 256, 256, 0, stream>>>(mol_indptr, mol_pos, N_MOL);
    fill_self_kernel<<<(N_MOL + 255) / 256, 256, 0, stream>>>(mol_pos, mol_srcl, N_MOL);
    fill_edge_kernel<<<(E_MOL + 255) / 256, 256, 0, stream>>>(mol_ei, mol_ei + E_MOL, E_MOL, mol_pos,
                                                              mol_srcl);
    set_int_kernel<<<(N_PROT + 255) / 256, 256, 0, stream>>>(cnt, 1, N_PROT);
    hist_kernel<<<(E_PROT + 255) / 256, 256, 0, stream>>>(prot_ei + E_PROT, E_PROT, cnt);
    scan_kernel<<<1, 1024, 0, stream>>>(cnt, prot_indptr, N_PROT);
    copy_int_kernel<<<(N_PROT + 255) / 256, 256, 0, stream>>>(prot_indptr, prot_pos, N_PROT);
    fill_self_kernel<<<(N_PROT + 255) / 256, 256, 0, stream>>>(prot_pos, prot_srcl, N_PROT);
    fill_edge_kernel<<<(E_PROT + 255) / 256, 256, 0, stream>>>(prot_ei, prot_ei + E_PROT, E_PROT,
                                                               prot_pos, prot_srcl);

    // ---- graph offsets ----
    set_int_kernel<<<(G_MOL + 255) / 256, 256, 0, stream>>>(gcnt, 0, G_MOL);
    hist_kernel<<<(N_MOL + 255) / 256, 256, 0, stream>>>(mol_batch, N_MOL, gcnt);
    scan_kernel<<<1, 1024, 0, stream>>>(gcnt, mol_goff, G_MOL);
    set_int_kernel<<<(G_PROT + 255) / 256, 256, 0, stream>>>(gcnt, 0, G_PROT);
    hist_kernel<<<(N_PROT + 255) / 256, 256, 0, stream>>>(prot_batch, N_PROT, gcnt);
    scan_kernel<<<1, 1024, 0, stream>>>(gcnt, prot_goff, G_PROT);

    // ---- layer-0 transfold ----
    transfold<<<dim3(C_MOL / 32, C_MOL / 32, H_HEADS), 256, 0, stream>>>(
        mol_W, WtM, mol_asrc, mol_adst, wsrcM, wdstM, C_MOL, C_MOL, (size_t)C_MOL, 3 * C_MOL);
    transfold<<<dim3(C_PROT / 32, C_PROT / 32, H_HEADS), 256, 0, stream>>>(
        prot_W, WtP, prot_asrc, prot_adst, wsrcP, wdstP, C_PROT, C_PROT, (size_t)C_PROT,
        3 * C_PROT);

    // ---- layer-0 features + logits ----
    f32_to_bf16<<<(N_PROT * C_PROT + 255) / 256, 256, 0, stream>>>(prot_in, x_prot, N_PROT * C_PROT);
    embed_mean_kernel<<<N_MOL, C_MOL, 0, stream>>>(drug_x, emb, x_mol);
    pool_atomic<C_MOL, 8><<<dim3(G_MOL, 8), C_MOL / 4, 0, stream>>>(x_mol, mol_goff, out_mol, 0);
    pool_atomic<C_PROT, 64><<<dim3(G_PROT, 64), C_PROT / 4, 0, stream>>>(x_prot, prot_goff,
                                                                         out_prot, 0);
    attn_logits<C_MOL><<<N_MOL, 64, 0, stream>>>(x_mol, wsrcM, wdstM, alsM, aldM);
    attn_logits<C_PROT><<<N_PROT, 64, 0, stream>>>(x_prot, wsrcP, wdstP, alsP, aldP);

    const int gMol = (MPAD_MOL / 128) * (C_MOL / 128);    // 313*4 = 1252
    const int gProt = (MPAD_PROT / 128) * (C_PROT / 128); // 63*10 = 630

    for (int l = 0; l < LAYERS; ++l) {
        const int last = (l == LAYERS - 1);
        if (BIG) {
            alpha_kernel2<<<(N_MOL * H_HEADS + 255) / 256, 256, 0, stream>>>(
                alsM, aldM, mol_indptr, mol_srcl, alphaw, N_MOL);
            aggregate_mol<<<N_MOL / 4, 256, 0, stream>>>(x_mol, alphaw, mol_indptr, mol_srcl, aggM);
            alpha_kernel2<<<(N_PROT * H_HEADS + 255) / 256, 256, 0, stream>>>(
                alsP, aldP, prot_indptr, prot_srcl, alphaw, N_PROT);
            aggregate_all3<C_PROT><<<N_PROT, C_PROT / 4, 0, stream>>>(x_prot, alphaw, prot_indptr,
                                                                      prot_srcl, aggP);
            gemm128d<<<gProt + gMol, 256, 0, stream>>>(
                aggP, WtP, x_prot, C_PROT, 3 * C_PROT, C_PROT / 128, N_PROT, gProt,
                aggM, WtM, x_mol, C_MOL, 3 * C_MOL, C_MOL / 128, N_MOL);
            if (!last) {
                transfold<<<dim3(C_MOL / 32, C_MOL / 32, H_HEADS), 256, 0, stream>>>(
                    mol_W + (size_t)(l + 1) * C_MOL * (H_HEADS * C_MOL), WtM,
                    mol_asrc + (size_t)(l + 1) * H_HEADS * C_MOL,
                    mol_adst + (size_t)(l + 1) * H_HEADS * C_MOL,
                    wsrcM + (size_t)(l + 1) * H_HEADS * C_MOL,
                    wdstM + (size_t)(l + 1) * H_HEADS * C_MOL, C_MOL, C_MOL, (size_t)C_MOL,
                    3 * C_MOL);
                transfold<<<dim3(C_PROT / 32, C_PROT / 32, H_HEADS), 256, 0, stream>>>(
                    prot_W + (size_t)(l + 1) * C_PROT * (H_HEADS * C_PROT), WtP,
                    prot_asrc + (size_t)(l + 1) * H_HEADS * C_PROT,
                    prot_adst + (size_t)(l + 1) * H_HEADS * C_PROT,
                    wsrcP + (size_t)(l + 1) * H_HEADS * C_PROT,
                    wdstP + (size_t)(l + 1) * H_HEADS * C_PROT, C_PROT, C_PROT, (size_t)C_PROT,
                    3 * C_PROT);
                ln_kernel<C_MOL, 1><<<N_MOL, 256, 0, stream>>>(
                    x_mol, mol_bias + (size_t)l * C_MOL, mol_lng + (size_t)l * C_MOL,
                    mol_lnb + (size_t)l * C_MOL, wsrcM + (size_t)(l + 1) * H_HEADS * C_MOL,
                    wdstM + (size_t)(l + 1) * H_HEADS * C_MOL, alsM, aldM);
                ln_kernel<C_PROT, 1><<<N_PROT, 256, 0, stream>>>(
                    x_prot, prot_bias + (size_t)l * C_PROT, prot_lng + (size_t)l * C_PROT,
                    prot_lnb + (size_t)l * C_PROT, wsrcP + (size_t)(l + 1) * H_HEADS * C_PROT,
                    wdstP + (size_t)(l + 1) * H_HEADS * C_PROT, alsP, aldP);
            } else {
                ln_kernel<C_MOL, 0><<<N_MOL, 256, 0, stream>>>(
                    x_mol, mol_bias + (size_t)l * C_MOL, mol_lng + (size_t)l * C_MOL,
                    mol_lnb + (size_t)l * C_MOL, nullptr, nullptr, nullptr, nullptr);
                ln_kernel<C_PROT, 0><<<N_PROT, 256, 0, stream>>>(
                    x_prot, prot_bias + (size_t)l * C_PROT, prot_lng + (size_t)l * C_PROT,
                    prot_lnb + (size_t)l * C_PROT, nullptr, nullptr, nullptr, nullptr);
            }
            pool_atomic<C_MOL, 8><<<dim3(G_MOL, 8), C_MOL / 4, 0, stream>>>(x_mol, mol_goff,
                                                                            out_mol, l + 1);
            pool_atomic<C_PROT, 64><<<dim3(G_PROT, 64), C_PROT / 4, 0, stream>>>(
                x_prot, prot_goff, out_prot, l + 1);
        } else {
            // fallback: serial ordering (aggP aliases aggM)
            alpha_kernel2<<<(N_MOL * H_HEADS + 255) / 256, 256, 0, stream>>>(
                alsM, aldM, mol_indptr, mol_srcl, alphaw, N_MOL);
            aggregate_mol<<<N_MOL / 4, 256, 0, stream>>>(x_mol, alphaw, mol_indptr, mol_srcl, aggM);
            gemm128d<<<gMol, 256, 0, stream>>>(
                aggM, WtM, x_mol, C_MOL, 3 * C_MOL, C_MOL / 128, N_MOL, gMol,
                aggM, WtM, x_mol, C_MOL, 3 * C_MOL, C_MOL / 128, N_MOL);
            if (!last)
                transfold<<<dim3(C_MOL / 32, C_MOL / 32, H_HEADS), 256, 0, stream>>>(
                    mol_W + (size_t)(l + 1) * C_MOL * (H_HEADS * C_MOL), WtM,
                    mol_asrc + (size_t)(l + 1) * H_HEADS * C_MOL,
                    mol_adst + (size_t)(l + 1) * H_HEADS * C_MOL,
                    wsrcM + (size_t)(l + 1) * H_HEADS * C_MOL,
                    wdstM + (size_t)(l + 1) * H_HEADS * C_MOL, C_MOL, C_MOL, (size_t)C_MOL,
                    3 * C_MOL);
            if (last)
                ln_kernel<C_MOL, 0><<<N_MOL, 256, 0, stream>>>(
                    x_mol, mol_bias + (size_t)l * C_MOL, mol_lng + (size_t)l * C_MOL,
                    mol_lnb + (size_t)l * C_MOL, nullptr, nullptr, nullptr, nullptr);
            else
                ln_kernel<C_MOL, 1><<<N_MOL, 256, 0, stream>>>(
                    x_mol, mol_bias + (size_t)l * C_MOL, mol_lng + (size_t)l * C_MOL,
                    mol_lnb + (size_t)l * C_MOL, wsrcM + (size_t)(l + 1) * H_HEADS * C_MOL,
                    wdstM + (size_t)(l + 1) * H_HEADS * C_MOL, alsM, aldM);
            pool_atomic<C_MOL, 8><<<dim3(G_MOL, 8), C_MOL / 4, 0, stream>>>(x_mol, mol_goff,
                                                                            out_mol, l + 1);
            alpha_kernel2<<<(N_PROT * H_HEADS + 255) / 256, 256, 0, stream>>>(
                alsP, aldP, prot_indptr, prot_srcl, alphaw, N_PROT);
            aggregate_all3<C_PROT><<<N_PROT, C_PROT / 4, 0, stream>>>(x_prot, alphaw, prot_indptr,
                                                                      prot_srcl, aggP);
            gemm128d<<<gProt, 256, 0, stream>>>(
                aggP, WtP, x_prot, C_PROT, 3 * C_PROT, C_PROT / 128, N_PROT, gProt,
                aggP, WtP, x_prot, C_PROT, 3 * C_PROT, C_PROT / 128, N_PROT);
            if (!last)
                transfold<<<dim3(C_PROT / 32, C_PROT / 32, H_HEADS), 256, 0, stream>>>(
                    prot_W + (size_t)(l + 1) * C_PROT * (H_HEADS * C_PROT), WtP,
                    prot_asrc + (size_t)(l + 1) * H_HEADS * C_PROT,
                    prot_adst + (size_t)(l + 1) * H_HEADS * C_PROT,
                    wsrcP + (size_t)(l + 1) * H_HEADS * C_PROT,
                    wdstP + (size_t)(l + 1) * H_HEADS * C_PROT, C_PROT, C_PROT, (size_t)C_PROT,
                    3 * C_PROT);
            if (last)
                ln_kernel<C_PROT, 0><<<N_PROT, 256, 0, stream>>>(
                    x_prot, prot_bias + (size_t)l * C_PROT, prot_lng + (size_t)l * C_PROT,
                    prot_lnb + (size_t)l * C_PROT, nullptr, nullptr, nullptr, nullptr);
            else
                ln_kernel<C_PROT, 1><<<N_PROT, 256, 0, stream>>>(
                    x_prot, prot_bias + (size_t)l * C_PROT, prot_lng + (size_t)l * C_PROT,
                    prot_lnb + (size_t)l * C_PROT, wsrcP + (size_t)(l + 1) * H_HEADS * C_PROT,
                    wdstP + (size_t)(l + 1) * H_HEADS * C_PROT, alsP, aldP);
            pool_atomic<C_PROT, 64><<<dim3(G_PROT, 64), C_PROT / 4, 0, stream>>>(
                x_prot, prot_goff, out_prot, l + 1);
        }
    }
}

// Round 11
// 2271.384 us; speedup vs baseline: 1.1231x; 1.0082x over previous
//
#include <hip/hip_runtime.h>
#include <cstdint>

// R11: safe bundle, GEMM untouched (R10 gemm128d proven 183us merged).
// 1) alpha fused into aggregates via per-block LDS alpha-table (computed once,
//    broadcast-read) -- removes 8 alpha dispatches + alphaw buffer. R6's mistake
//    (per-thread exp recompute) avoided.
// 2) ln_kernel vectorized: block C/4 threads, ushort4 x-loads/stores, float4 params.

constexpr int H_HEADS = 3;
constexpr float NEG_SLOPE = 0.2f;
constexpr float LN_EPS = 1e-5f;
constexpr int N_MOL = 40000, E_MOL = 80000, C_MOL = 512, G_MOL = 512;
constexpr int N_PROT = 8000, E_PROT = 64000, C_PROT = 1280, G_PROT = 32;
constexpr int LAYERS = 4;
constexpr int MPAD_MOL = 40064;
constexpr int MPAD_PROT = 8064;

typedef unsigned short u16;
typedef __attribute__((ext_vector_type(8))) short short8v;
typedef __attribute__((ext_vector_type(4))) unsigned short ushort4v;
typedef __attribute__((ext_vector_type(4))) float f32x4;

__device__ __forceinline__ float bf2f(u16 s) {
    union { unsigned u; float f; } v; v.u = ((unsigned)s) << 16; return v.f;
}
__device__ __forceinline__ u16 f2bf(float f) {
    union { float f; unsigned u; } v; v.f = f;
    return (u16)((v.u + 0x7fffu + ((v.u >> 16) & 1u)) >> 16);
}

__device__ __forceinline__ void g2l16(const void* g, void* l) {
    __builtin_amdgcn_global_load_lds((const __attribute__((address_space(1))) void*)g,
                                     (__attribute__((address_space(3))) void*)l, 16, 0, 0);
}

// ---------------- small utility kernels ----------------

__global__ void set_int_kernel(int* p, int v, int n) {
    int i = blockIdx.x * blockDim.x + threadIdx.x;
    if (i < n) p[i] = v;
}

__global__ void zero_f32_kernel(float* p, int n) {
    int i = blockIdx.x * blockDim.x + threadIdx.x;
    if (i < n) p[i] = 0.f;
}

__global__ void copy_int_kernel(const int* __restrict__ s, int* __restrict__ d, int n) {
    int i = blockIdx.x * blockDim.x + threadIdx.x;
    if (i < n) d[i] = s[i];
}

__global__ void hist_kernel(const int* __restrict__ keys, int n, int* __restrict__ cnt) {
    int i = blockIdx.x * blockDim.x + threadIdx.x;
    if (i < n) atomicAdd(&cnt[keys[i]], 1);
}

__global__ void scan_kernel(const int* __restrict__ in, int* __restrict__ out, int n) {
    __shared__ int sums[1024];
    const int t = threadIdx.x;
    const int chunk = (n + 1023) / 1024;
    const int start = t * chunk;
    const int end = min(start + chunk, n);
    int s = 0;
    for (int i = start; i < end; ++i) s += in[i];
    sums[t] = s;
    __syncthreads();
    if (t == 0) {
        int acc = 0;
        for (int i = 0; i < 1024; ++i) { int v = sums[i]; sums[i] = acc; acc += v; }
        out[n] = acc;
    }
    __syncthreads();
    int acc = sums[t];
    for (int i = start; i < end; ++i) { out[i] = acc; acc += in[i]; }
}

__global__ void fill_self_kernel(int* __restrict__ pos, int* __restrict__ srcl, int n) {
    int i = blockIdx.x * blockDim.x + threadIdx.x;
    if (i < n) { int slot = atomicAdd(&pos[i], 1); srcl[slot] = i; }
}

__global__ void fill_edge_kernel(const int* __restrict__ src, const int* __restrict__ dst, int e,
                                 int* __restrict__ pos, int* __restrict__ srcl) {
    int i = blockIdx.x * blockDim.x + threadIdx.x;
    if (i < e) { int slot = atomicAdd(&pos[dst[i]], 1); srcl[slot] = src[i]; }
}

__global__ void f32_to_bf16(const float* __restrict__ in, u16* __restrict__ out, int n) {
    int i = blockIdx.x * blockDim.x + threadIdx.x;
    if (i < n) out[i] = f2bf(in[i]);
}

// ---------------- embedding mean -> bf16 ----------------

__global__ void embed_mean_kernel(const int* __restrict__ drug_x, const float* __restrict__ emb,
                                  u16* __restrict__ out) {
    const int n = blockIdx.x;
    __shared__ int idx[9];
    if (threadIdx.x < 9) idx[threadIdx.x] = drug_x[n * 9 + threadIdx.x];
    __syncthreads();
    const int c = threadIdx.x;
    float s = 0.f;
#pragma unroll
    for (int t = 0; t < 9; ++t) s += emb[(size_t)idx[t] * C_MOL + c];
    out[(size_t)n * C_MOL + c] = f2bf(s * (1.f / 9.f));
}

// ---------------- fused transpose + fold ----------------

__global__ __launch_bounds__(256) void transfold(const float* __restrict__ W, u16* __restrict__ Wt,
                                                 const float* __restrict__ asrc,
                                                 const float* __restrict__ adst,
                                                 float* __restrict__ wsrc, float* __restrict__ wdst,
                                                 int CIN, int COUT, size_t headStride, int ldn) {
    __shared__ float t[32][33];
    __shared__ float rs[8][33], rd[8][33];
    const int h = blockIdx.z;
    const int n0 = blockIdx.x * 32, k0 = blockIdx.y * 32;
    const int tx = threadIdx.x & 31, ty = threadIdx.x >> 5;
#pragma unroll
    for (int q = 0; q < 4; ++q)
        t[ty + q * 8][tx] = W[(size_t)(k0 + ty + q * 8) * (H_HEADS * COUT) + h * COUT + n0 + tx];
    __syncthreads();
#pragma unroll
    for (int q = 0; q < 4; ++q)
        Wt[(size_t)h * headStride + (size_t)(n0 + ty + q * 8) * ldn + k0 + tx] =
            f2bf(t[tx][ty + q * 8]);
    float ps = 0.f, pd = 0.f;
    const float* as = asrc + h * COUT + n0;
    const float* ad = adst + h * COUT + n0;
#pragma unroll
    for (int q = 0; q < 4; ++q) {
        const float w = t[tx][ty + q * 8];
        ps += w * as[ty + q * 8];
        pd += w * ad[ty + q * 8];
    }
    rs[ty][tx] = ps;
    rd[ty][tx] = pd;
    __syncthreads();
    if (ty == 0) {
        float s = 0.f, d = 0.f;
#pragma unroll
        for (int j = 0; j < 8; ++j) { s += rs[j][tx]; d += rd[j][tx]; }
        atomicAdd(&wsrc[h * CIN + k0 + tx], s);
        atomicAdd(&wdst[h * CIN + k0 + tx], d);
    }
}

// ---------------- attention logits (layer 0 only) ----------------

template <int C>
__global__ void attn_logits(const u16* __restrict__ x, const float* __restrict__ wsrc,
                            const float* __restrict__ wdst, float* __restrict__ als,
                            float* __restrict__ ald) {
    constexpr int PER = C / 64;
    const int n = blockIdx.x, lane = threadIdx.x;
    const u16* xr = x + (size_t)n * C + lane * PER;
    float xv[PER];
#pragma unroll
    for (int i = 0; i < PER; i += 4) {
        const ushort4v v = *(const ushort4v*)(xr + i);
        xv[i] = bf2f(v.x); xv[i + 1] = bf2f(v.y); xv[i + 2] = bf2f(v.z); xv[i + 3] = bf2f(v.w);
    }
    for (int h = 0; h < H_HEADS; ++h) {
        const float* ws = wsrc + h * C + lane * PER;
        const float* wd = wdst + h * C + lane * PER;
        float ss = 0.f, sd = 0.f;
#pragma unroll
        for (int i = 0; i < PER; i += 4) {
            const float4 a = *(const float4*)(ws + i);
            const float4 b = *(const float4*)(wd + i);
            ss += xv[i] * a.x + xv[i + 1] * a.y + xv[i + 2] * a.z + xv[i + 3] * a.w;
            sd += xv[i] * b.x + xv[i + 1] * b.y + xv[i + 2] * b.z + xv[i + 3] * b.w;
        }
        for (int o = 32; o; o >>= 1) { ss += __shfl_down(ss, o); sd += __shfl_down(sd, o); }
        if (lane == 0) { als[n * H_HEADS + h] = ss; ald[n * H_HEADS + h] = sd; }
    }
}

// ---------------- mol: fused alpha + aggregate, wave per node, LDS alpha-table ----------------

__global__ __launch_bounds__(256) void agg_mol_f(const u16* __restrict__ x,
                                                 const float* __restrict__ als,
                                                 const float* __restrict__ ald,
                                                 const int* __restrict__ indptr,
                                                 const int* __restrict__ srcl,
                                                 u16* __restrict__ agg) {
    constexpr int MAXD = 128;
    const int wv = threadIdx.x >> 6, lane = threadIdx.x & 63;
    const int n = blockIdx.x * 4 + wv;
    const int beg = indptr[n], end = indptr[n + 1];
    const int deg = end - beg;
    __shared__ float atab[4][MAXD * 3];
    // per-head m, 1/z (serial, reference edge order) on lanes 0..2
    float m = -1e30f, zi = 0.f;
    if (lane < H_HEADS) {
        const float ad = ald[n * H_HEADS + lane];
        for (int e = beg; e < end; ++e) {
            float v = als[srcl[e] * H_HEADS + lane] + ad;
            v = v >= 0.f ? v : NEG_SLOPE * v;
            m = fmaxf(m, v);
        }
        float z = 0.f;
        for (int e = beg; e < end; ++e) {
            float v = als[srcl[e] * H_HEADS + lane] + ad;
            v = v >= 0.f ? v : NEG_SLOPE * v;
            z += __expf(v - m);
        }
        zi = 1.f / (z + 1e-16f);
    }
    const float m0 = __shfl(m, 0), m1 = __shfl(m, 1), m2 = __shfl(m, 2);
    const float z0 = __shfl(zi, 0), z1 = __shfl(zi, 1), z2 = __shfl(zi, 2);
    const float ad0 = ald[n * H_HEADS + 0], ad1 = ald[n * H_HEADS + 1], ad2 = ald[n * H_HEADS + 2];
    const bool fits = deg <= MAXD;
    if (fits) {
        for (int i = lane; i < deg * 3; i += 64) {
            const int e = i / 3, h = i - e * 3;
            float v = als[srcl[beg + e] * H_HEADS + h] + (h == 0 ? ad0 : (h == 1 ? ad1 : ad2));
            v = v >= 0.f ? v : NEG_SLOPE * v;
            const float mh = h == 0 ? m0 : (h == 1 ? m1 : m2);
            const float zh = h == 0 ? z0 : (h == 1 ? z1 : z2);
            atab[wv][i] = __expf(v - mh) * zh;
        }
    }
    __syncthreads();
    float acc[H_HEADS][8];
#pragma unroll
    for (int h = 0; h < H_HEADS; ++h)
#pragma unroll
        for (int j = 0; j < 8; ++j) acc[h][j] = 0.f;
    for (int e = 0; e < deg; ++e) {
        const int s = srcl[beg + e];
        float a0, a1, a2;
        if (fits) {
            a0 = atab[wv][e * 3 + 0];
            a1 = atab[wv][e * 3 + 1];
            a2 = atab[wv][e * 3 + 2];
        } else {
            float v0 = als[s * H_HEADS + 0] + ad0; v0 = v0 >= 0.f ? v0 : NEG_SLOPE * v0;
            float v1 = als[s * H_HEADS + 1] + ad1; v1 = v1 >= 0.f ? v1 : NEG_SLOPE * v1;
            float v2 = als[s * H_HEADS + 2] + ad2; v2 = v2 >= 0.f ? v2 : NEG_SLOPE * v2;
            a0 = __expf(v0 - m0) * z0;
            a1 = __expf(v1 - m1) * z1;
            a2 = __expf(v2 - m2) * z2;
        }
        const short8v row = *(const short8v*)(x + (size_t)s * C_MOL + lane * 8);
#pragma unroll
        for (int j = 0; j < 8; ++j) {
            const float f = bf2f((u16)row[j]);
            acc[0][j] += a0 * f; acc[1][j] += a1 * f; acc[2][j] += a2 * f;
        }
    }
    u16* o = agg + (size_t)n * (3 * C_MOL) + lane * 8;
#pragma unroll
    for (int h = 0; h < H_HEADS; ++h) {
        short8v r;
#pragma unroll
        for (int j = 0; j < 8; ++j) r[j] = (short)f2bf(acc[h][j]);
        *(short8v*)(o + h * C_MOL) = r;
    }
}

// ---------------- prot: fused alpha + aggregate, block per node, LDS alpha-table ----------------

__global__ __launch_bounds__(320) void agg_prot_f(const u16* __restrict__ x,
                                                  const float* __restrict__ als,
                                                  const float* __restrict__ ald,
                                                  const int* __restrict__ indptr,
                                                  const int* __restrict__ srcl,
                                                  u16* __restrict__ agg) {
    constexpr int MAXD = 512;
    const int n = blockIdx.x, tid = threadIdx.x;
    const int beg = indptr[n], end = indptr[n + 1];
    const int deg = end - beg;
    __shared__ float mz[6];
    __shared__ float atab[MAXD * 3];
    if (tid < H_HEADS) {
        const float ad = ald[n * H_HEADS + tid];
        float m = -1e30f;
        for (int e = beg; e < end; ++e) {
            float v = als[srcl[e] * H_HEADS + tid] + ad;
            v = v >= 0.f ? v : NEG_SLOPE * v;
            m = fmaxf(m, v);
        }
        float z = 0.f;
        for (int e = beg; e < end; ++e) {
            float v = als[srcl[e] * H_HEADS + tid] + ad;
            v = v >= 0.f ? v : NEG_SLOPE * v;
            z += __expf(v - m);
        }
        mz[tid] = m;
        mz[3 + tid] = 1.f / (z + 1e-16f);
    }
    __syncthreads();
    const bool fits = deg <= MAXD;
    if (fits) {
        for (int i = tid; i < deg * 3; i += 320) {
            const int e = i / 3, h = i - e * 3;
            float v = als[srcl[beg + e] * H_HEADS + h] + ald[n * H_HEADS + h];
            v = v >= 0.f ? v : NEG_SLOPE * v;
            atab[i] = __expf(v - mz[h]) * mz[3 + h];
        }
    }
    __syncthreads();
    const float m0 = mz[0], m1 = mz[1], m2 = mz[2];
    const float z0 = mz[3], z1 = mz[4], z2 = mz[5];
    const float ad0 = ald[n * H_HEADS + 0], ad1 = ald[n * H_HEADS + 1], ad2 = ald[n * H_HEADS + 2];
    float acc[H_HEADS][4];
#pragma unroll
    for (int h = 0; h < H_HEADS; ++h)
#pragma unroll
        for (int j = 0; j < 4; ++j) acc[h][j] = 0.f;
    for (int e = 0; e < deg; ++e) {
        const int s = srcl[beg + e];
        float a0, a1, a2;
        if (fits) {
            a0 = atab[e * 3 + 0];
            a1 = atab[e * 3 + 1];
            a2 = atab[e * 3 + 2];
        } else {
            float v0 = als[s * H_HEADS + 0] + ad0; v0 = v0 >= 0.f ? v0 : NEG_SLOPE * v0;
            float v1 = als[s * H_HEADS + 1] + ad1; v1 = v1 >= 0.f ? v1 : NEG_SLOPE * v1;
            float v2 = als[s * H_HEADS + 2] + ad2; v2 = v2 >= 0.f ? v2 : NEG_SLOPE * v2;
            a0 = __expf(v0 - m0) * z0;
            a1 = __expf(v1 - m1) * z1;
            a2 = __expf(v2 - m2) * z2;
        }
        const ushort4v v = *(const ushort4v*)(x + (size_t)s * C_PROT + tid * 4);
        const float f0 = bf2f(v.x), f1 = bf2f(v.y), f2 = bf2f(v.z), f3 = bf2f(v.w);
        acc[0][0] += a0 * f0; acc[0][1] += a0 * f1; acc[0][2] += a0 * f2; acc[0][3] += a0 * f3;
        acc[1][0] += a1 * f0; acc[1][1] += a1 * f1; acc[1][2] += a1 * f2; acc[1][3] += a1 * f3;
        acc[2][0] += a2 * f0; acc[2][1] += a2 * f1; acc[2][2] += a2 * f2; acc[2][3] += a2 * f3;
    }
    u16* o = agg + (size_t)n * (3 * C_PROT) + tid * 4;
#pragma unroll
    for (int h = 0; h < H_HEADS; ++h) {
        ushort4v r;
        r.x = f2bf(acc[h][0]); r.y = f2bf(acc[h][1]); r.z = f2bf(acc[h][2]); r.w = f2bf(acc[h][3]);
        *(ushort4v*)(o + h * C_PROT) = r;
    }
}

// ---------------- GEMM: 128x128 tile, BK=64, 4 waves, 32KB LDS (R10 proven) ----------------

__global__ __launch_bounds__(256) void gemm128d(
    const u16* __restrict__ A0, const u16* __restrict__ B0, u16* __restrict__ C0,
    int N0, int K0, int nx0, int M0, int g0,
    const u16* __restrict__ A1, const u16* __restrict__ B1, u16* __restrict__ C1,
    int N1, int K1, int nx1, int M1) {
    __shared__ u16 lds[16384];
    const int tid = threadIdx.x;
    const int w = tid >> 6, l = tid & 63;
    const int wr = w >> 1, wc = w & 1;

    const int bid = blockIdx.x;
    const u16 *A, *Bt;
    u16* Cout;
    int N, K, nxch, Mreal, base, sz;
    if (bid < g0) { base = 0; sz = g0; A = A0; Bt = B0; Cout = C0; N = N0; K = K0; nxch = nx0; Mreal = M0; }
    else { base = g0; sz = gridDim.x - g0; A = A1; Bt = B1; Cout = C1; N = N1; K = K1; nxch = nx1; Mreal = M1; }
    const int j = bid - base;
    const int q = sz >> 3, r = sz & 7;
    const int xcd = j & 7, idx = j >> 3;
    const int wg = (xcd < r ? xcd * (q + 1) : r * (q + 1) + (xcd - r) * q) + idx;
    const int nx = wg % nxch, my = wg / nxch;
    const size_t bm = (size_t)my * 128, bn = (size_t)nx * 128;

    const f32x4 zf = {0.f, 0.f, 0.f, 0.f};
    f32x4 acc[4][4];
#pragma unroll
    for (int i = 0; i < 4; ++i)
#pragma unroll
        for (int jj = 0; jj < 4; ++jj) acc[i][jj] = zf;

    const int srow = w * 32 + (l >> 3);
    const int sseg = (l & 7) ^ (l >> 3);
    const u16* Ab = A + (bm + srow) * (size_t)K + sseg * 8;
    const u16* Bb = Bt + (bn + srow) * (size_t)K + sseg * 8;

    for (int k0 = 0; k0 < K; k0 += 64) {
#pragma unroll
        for (int qq = 0; qq < 4; ++qq)
            g2l16(Ab + k0 + (size_t)qq * 8 * K, lds + (w * 4 + qq) * 512);
#pragma unroll
        for (int qq = 0; qq < 4; ++qq)
            g2l16(Bb + k0 + (size_t)qq * 8 * K, lds + 8192 + (w * 4 + qq) * 512);
        __syncthreads();
#pragma unroll
        for (int kk = 0; kk < 2; ++kk) {
            const int sg = ((kk * 4 + (l >> 4)) ^ (l & 7)) * 8;
            short8v af[4], bf8[4];
#pragma unroll
            for (int fm = 0; fm < 4; ++fm) {
                const int row = wr * 64 + fm * 16 + (l & 15);
                af[fm] = *(const short8v*)&lds[row * 64 + sg];
            }
#pragma unroll
            for (int fn = 0; fn < 4; ++fn) {
                const int row = wc * 64 + fn * 16 + (l & 15);
                bf8[fn] = *(const short8v*)&lds[8192 + row * 64 + sg];
            }
#pragma unroll
            for (int fm = 0; fm < 4; ++fm)
#pragma unroll
                for (int fn = 0; fn < 4; ++fn)
                    acc[fm][fn] = __builtin_amdgcn_mfma_f32_16x16x32_bf16(af[fm], bf8[fn],
                                                                          acc[fm][fn], 0, 0, 0);
        }
        __syncthreads();
    }

#pragma unroll
    for (int half = 0; half < 2; ++half) {
        if (wr == half) {
#pragma unroll
            for (int fm = 0; fm < 4; ++fm)
#pragma unroll
                for (int fn = 0; fn < 4; ++fn) {
                    const int col = wc * 64 + fn * 16 + (l & 15);
#pragma unroll
                    for (int rr = 0; rr < 4; ++rr)
                        lds[(fm * 16 + (l >> 4) * 4 + rr) * 136 + col] = f2bf(acc[fm][fn][rr]);
                }
        }
        __syncthreads();
        const int lrow = tid >> 2, lseg = tid & 3;
        const size_t grow = bm + half * 64 + lrow;
        if (grow < (size_t)Mreal) {
            u16* Crow = Cout + grow * (size_t)N + bn + lseg * 32;
            const u16* Lr = lds + lrow * 136 + lseg * 32;
#pragma unroll
            for (int ii = 0; ii < 4; ++ii)
                *(float4*)(Crow + ii * 8) = *(const float4*)(Lr + ii * 8);
        }
        __syncthreads();
    }
}

// ---------------- in-place LN, vectorized (block C/4, ushort4) + next-layer logits ----------------

template <int C, int LOGITS>
__global__ __launch_bounds__(C / 4) void ln_kernel(u16* __restrict__ x,
                                                   const float* __restrict__ bias,
                                                   const float* __restrict__ g,
                                                   const float* __restrict__ b,
                                                   const float* __restrict__ wsrc_n,
                                                   const float* __restrict__ wdst_n,
                                                   float* __restrict__ als,
                                                   float* __restrict__ ald) {
    constexpr int NT = C / 4;
    constexpr int NW = NT / 64;
    const int n = blockIdx.x, tid = threadIdx.x;
    u16* xr = x + (size_t)n * C + tid * 4;
    constexpr float invH = 1.f / (float)H_HEADS;
    const ushort4v xv = *(const ushort4v*)xr;
    const float4 bi = *(const float4*)(bias + tid * 4);
    const float v0 = bf2f(xv.x) * invH + bi.x;
    const float v1 = bf2f(xv.y) * invH + bi.y;
    const float v2 = bf2f(xv.z) * invH + bi.z;
    const float v3 = bf2f(xv.w) * invH + bi.w;
    float s1 = v0 + v1 + v2 + v3;
    float s2 = v0 * v0 + v1 * v1 + v2 * v2 + v3 * v3;
    __shared__ float red[2][NW];
    __shared__ float red2[NW][6];
    for (int o = 32; o; o >>= 1) { s1 += __shfl_down(s1, o); s2 += __shfl_down(s2, o); }
    if ((tid & 63) == 0) { red[0][tid >> 6] = s1; red[1][tid >> 6] = s2; }
    __syncthreads();
    float t1 = 0.f, t2 = 0.f;
#pragma unroll
    for (int i = 0; i < NW; ++i) { t1 += red[0][i]; t2 += red[1][i]; }
    const float mu = t1 / C;
    const float var = t2 / C - mu * mu;
    const float rstd = rsqrtf(var + LN_EPS);
    const float4 gg = *(const float4*)(g + tid * 4);
    const float4 bb = *(const float4*)(b + tid * 4);
    ushort4v ov;
    ov.x = f2bf((v0 - mu) * rstd * gg.x + bb.x);
    ov.y = f2bf((v1 - mu) * rstd * gg.y + bb.y);
    ov.z = f2bf((v2 - mu) * rstd * gg.z + bb.z);
    ov.w = f2bf((v3 - mu) * rstd * gg.w + bb.w);
    *(ushort4v*)xr = ov;
    if (LOGITS) {
        const float q0 = bf2f(ov.x), q1 = bf2f(ov.y), q2 = bf2f(ov.z), q3 = bf2f(ov.w);
        float ps[3], pd[3];
#pragma unroll
        for (int h = 0; h < 3; ++h) {
            const float4 a = *(const float4*)(wsrc_n + h * C + tid * 4);
            const float4 d = *(const float4*)(wdst_n + h * C + tid * 4);
            ps[h] = q0 * a.x + q1 * a.y + q2 * a.z + q3 * a.w;
            pd[h] = q0 * d.x + q1 * d.y + q2 * d.z + q3 * d.w;
        }
        for (int o = 32; o; o >>= 1) {
#pragma unroll
            for (int h = 0; h < 3; ++h) {
                ps[h] += __shfl_down(ps[h], o);
                pd[h] += __shfl_down(pd[h], o);
            }
        }
        if ((tid & 63) == 0) {
            const int wv = tid >> 6;
#pragma unroll
            for (int h = 0; h < 3; ++h) { red2[wv][h] = ps[h]; red2[wv][3 + h] = pd[h]; }
        }
        __syncthreads();
        if (tid == 0) {
#pragma unroll
            for (int h = 0; h < 3; ++h) {
                float as = 0.f, ad = 0.f;
#pragma unroll
                for (int i = 0; i < NW; ++i) { as += red2[i][h]; ad += red2[i][3 + h]; }
                als[n * H_HEADS + h] = as;
                ald[n * H_HEADS + h] = ad;
            }
        }
    }
}

// ---------------- segmented atomic mean-pool ----------------

template <int C, int S>
__global__ void pool_atomic(const u16* __restrict__ x, const int* __restrict__ goff,
                            float* __restrict__ out, int layer) {
    const int g = blockIdx.x, seg = blockIdx.y;
    const int beg = goff[g], end = goff[g + 1];
    const int len = end - beg;
    const int s0 = beg + (len * seg) / S;
    const int s1 = beg + (len * (seg + 1)) / S;
    if (s0 >= s1) return;
    const float inv = 1.f / fmaxf((float)len, 1.f);
    const int tid = threadIdx.x;
    float a0 = 0.f, a1 = 0.f, a2 = 0.f, a3 = 0.f;
    for (int n = s0; n < s1; ++n) {
        const ushort4v v = *(const ushort4v*)(x + (size_t)n * C + tid * 4);
        a0 += bf2f(v.x); a1 += bf2f(v.y); a2 += bf2f(v.z); a3 += bf2f(v.w);
    }
    float* o = out + ((size_t)g * (LAYERS + 1) + layer) * C + tid * 4;
    atomicAdd(o + 0, a0 * inv);
    atomicAdd(o + 1, a1 * inv);
    atomicAdd(o + 2, a2 * inv);
    atomicAdd(o + 3, a3 * inv);
}

// ---------------- launch ----------------

extern "C" void kernel_launch(void* const* d_in, const int* in_sizes, int n_in, void* d_out,
                              int out_size, void* d_ws, size_t ws_size, hipStream_t stream) {
    const int* drug_x      = (const int*)d_in[0];
    const int* mol_ei      = (const int*)d_in[1];
    const int* mol_batch   = (const int*)d_in[2];
    const float* prot_in   = (const float*)d_in[3];
    const int* prot_ei     = (const int*)d_in[4];
    const int* prot_batch  = (const int*)d_in[5];
    const float* emb       = (const float*)d_in[6];
    const float* mol_W     = (const float*)d_in[7];
    const float* mol_asrc  = (const float*)d_in[8];
    const float* mol_adst  = (const float*)d_in[9];
    const float* mol_bias  = (const float*)d_in[10];
    const float* mol_lng   = (const float*)d_in[11];
    const float* mol_lnb   = (const float*)d_in[12];
    const float* prot_W    = (const float*)d_in[13];
    const float* prot_asrc = (const float*)d_in[14];
    const float* prot_adst = (const float*)d_in[15];
    const float* prot_bias = (const float*)d_in[16];
    const float* prot_lng  = (const float*)d_in[17];
    const float* prot_lnb  = (const float*)d_in[18];

    if (ws_size < (size_t)240500000) return;
    const bool BIG = ws_size >= (size_t)262000000;

    char* base = (char*)d_ws;
    size_t off = 0;
    auto alloc = [&](size_t bytes) -> void* {
        void* r = base + off;
        off = (off + bytes + 255) & ~(size_t)255;
        return r;
    };
    u16* x_mol  = (u16*)alloc((size_t)N_MOL * C_MOL * 2);
    u16* x_prot = (u16*)alloc((size_t)N_PROT * C_PROT * 2);
    u16* aggM   = (u16*)alloc((size_t)3 * MPAD_MOL * C_MOL * 2);
    u16* WtM    = (u16*)alloc((size_t)H_HEADS * C_MOL * C_MOL * 2);
    u16* WtP    = (u16*)alloc((size_t)H_HEADS * C_PROT * C_PROT * 2);
    u16* aggP   = BIG ? (u16*)alloc((size_t)3 * MPAD_PROT * C_PROT * 2) : aggM;
    float* wsrcM = (float*)alloc((size_t)LAYERS * H_HEADS * C_MOL * 4);
    float* wdstM = (float*)alloc((size_t)LAYERS * H_HEADS * C_MOL * 4);
    float* wsrcP = (float*)alloc((size_t)LAYERS * H_HEADS * C_PROT * 4);
    float* wdstP = (float*)alloc((size_t)LAYERS * H_HEADS * C_PROT * 4);
    float* alsM = (float*)alloc((size_t)N_MOL * H_HEADS * 4);
    float* aldM = (float*)alloc((size_t)N_MOL * H_HEADS * 4);
    float* alsP = (float*)alloc((size_t)N_PROT * H_HEADS * 4);
    float* aldP = (float*)alloc((size_t)N_PROT * H_HEADS * 4);
    int* mol_indptr  = (int*)alloc((N_MOL + 1) * 4);
    int* mol_pos     = (int*)alloc(N_MOL * 4);
    int* mol_srcl    = (int*)alloc((E_MOL + N_MOL) * 4);
    int* prot_indptr = (int*)alloc((N_PROT + 1) * 4);
    int* prot_pos    = (int*)alloc(N_PROT * 4);
    int* prot_srcl   = (int*)alloc((E_PROT + N_PROT) * 4);
    int* cnt         = (int*)alloc(N_MOL * 4);
    int* mol_goff    = (int*)alloc((G_MOL + 1) * 4);
    int* prot_goff   = (int*)alloc((G_PROT + 1) * 4);
    int* gcnt        = (int*)alloc(G_MOL * 4);

    float* out_mol  = (float*)d_out;
    float* out_prot = (float*)d_out + (size_t)G_MOL * (LAYERS + 1) * C_MOL;

    zero_f32_kernel<<<(out_size + 255) / 256, 256, 0, stream>>>((float*)d_out, out_size);
    zero_f32_kernel<<<(LAYERS * H_HEADS * C_MOL + 255) / 256, 256, 0, stream>>>(
        wsrcM, LAYERS * H_HEADS * C_MOL);
    zero_f32_kernel<<<(LAYERS * H_HEADS * C_MOL + 255) / 256, 256, 0, stream>>>(
        wdstM, LAYERS * H_HEADS * C_MOL);
    zero_f32_kernel<<<(LAYERS * H_HEADS * C_PROT + 255) / 256, 256, 0, stream>>>(
        wsrcP, LAYERS * H_HEADS * C_PROT);
    zero_f32_kernel<<<(LAYERS * H_HEADS * C_PROT + 255) / 256, 256, 0, stream>>>(
        wdstP, LAYERS * H_HEADS * C_PROT);

    // ---- CSR (incoming lists incl. self loops) ----
    set_int_kernel<<<(N_MOL + 255) / 256, 256, 0, stream>>>(cnt, 1, N_MOL);
    hist_kernel<<<(E_MOL + 255) / 256, 256, 0, stream>>>(mol_ei + E_MOL, E_MOL, cnt);
    scan_kernel<<<1, 1024, 0, stream>>>(cnt, mol_indptr, N_MOL);
    copy_int_kernel<<<(N_MOL + 255) / 256, 256, 0, stream>>>(mol_indptr, mol_pos, N_MOL);
    fill_self_kernel<<<(N_MOL + 255) / 256, 256, 0, stream>>>(mol_pos, mol_srcl, N_MOL);
    fill_edge_kernel<<<(E_MOL + 255) / 256, 256, 0, stream>>>(mol_ei, mol_ei + E_MOL, E_MOL, mol_pos,
                                                              mol_srcl);
    set_int_kernel<<<(N_PROT + 255) / 256, 256, 0, stream>>>(cnt, 1, N_PROT);
    hist_kernel<<<(E_PROT + 255) / 256, 256, 0, stream>>>(prot_ei + E_PROT, E_PROT, cnt);
    scan_kernel<<<1, 1024, 0, stream>>>(cnt, prot_indptr, N_PROT);
    copy_int_kernel<<<(N_PROT + 255) / 256, 256, 0, stream>>>(prot_indptr, prot_pos, N_PROT);
    fill_self_kernel<<<(N_PROT + 255) / 256, 256, 0, stream>>>(prot_pos, prot_srcl, N_PROT);
    fill_edge_kernel<<<(E_PROT + 255) / 256, 256, 0, stream>>>(prot_ei, prot_ei + E_PROT, E_PROT,
                                                               prot_pos, prot_srcl);

    // ---- graph offsets ----
    set_int_kernel<<<(G_MOL + 255) / 256, 256, 0, stream>>>(gcnt, 0, G_MOL);
    hist_kernel<<<(N_MOL + 255) / 256, 256, 0, stream>>>(mol_batch, N_MOL, gcnt);
    scan_kernel<<<1, 1024, 0, stream>>>(gcnt, mol_goff, G_MOL);
    set_int_kernel<<<(G_PROT + 255) / 256, 256, 0, stream>>>(gcnt, 0, G_PROT);
    hist_kernel<<<(N_PROT + 255) / 256, 256, 0, stream>>>(prot_batch, N_PROT, gcnt);
    scan_kernel<<<1, 1024, 0, stream>>>(gcnt, prot_goff, G_PROT);

    // ---- layer-0 transfold ----
    transfold<<<dim3(C_MOL / 32, C_MOL / 32, H_HEADS), 256, 0, stream>>>(
        mol_W, WtM, mol_asrc, mol_adst, wsrcM, wdstM, C_MOL, C_MOL, (size_t)C_MOL, 3 * C_MOL);
    transfold<<<dim3(C_PROT / 32, C_PROT / 32, H_HEADS), 256, 0, stream>>>(
        prot_W, WtP, prot_asrc, prot_adst, wsrcP, wdstP, C_PROT, C_PROT, (size_t)C_PROT,
        3 * C_PROT);

    // ---- layer-0 features + logits ----
    f32_to_bf16<<<(N_PROT * C_PROT + 255) / 256, 256, 0, stream>>>(prot_in, x_prot, N_PROT * C_PROT);
    embed_mean_kernel<<<N_MOL, C_MOL, 0, stream>>>(drug_x, emb, x_mol);
    pool_atomic<C_MOL, 8><<<dim3(G_MOL, 8), C_MOL / 4, 0, stream>>>(x_mol, mol_goff, out_mol, 0);
    pool_atomic<C_PROT, 64><<<dim3(G_PROT, 64), C_PROT / 4, 0, stream>>>(x_prot, prot_goff,
                                                                         out_prot, 0);
    attn_logits<C_MOL><<<N_MOL, 64, 0, stream>>>(x_mol, wsrcM, wdstM, alsM, aldM);
    attn_logits<C_PROT><<<N_PROT, 64, 0, stream>>>(x_prot, wsrcP, wdstP, alsP, aldP);

    const int gMol = (MPAD_MOL / 128) * (C_MOL / 128);    // 1252
    const int gProt = (MPAD_PROT / 128) * (C_PROT / 128); // 630

    for (int l = 0; l < LAYERS; ++l) {
        const int last = (l == LAYERS - 1);
        if (BIG) {
            agg_mol_f<<<N_MOL / 4, 256, 0, stream>>>(x_mol, alsM, aldM, mol_indptr, mol_srcl, aggM);
            agg_prot_f<<<N_PROT, 320, 0, stream>>>(x_prot, alsP, aldP, prot_indptr, prot_srcl,
                                                   aggP);
            gemm128d<<<gProt + gMol, 256, 0, stream>>>(
                aggP, WtP, x_prot, C_PROT, 3 * C_PROT, C_PROT / 128, N_PROT, gProt,
                aggM, WtM, x_mol, C_MOL, 3 * C_MOL, C_MOL / 128, N_MOL);
            if (!last) {
                transfold<<<dim3(C_MOL / 32, C_MOL / 32, H_HEADS), 256, 0, stream>>>(
                    mol_W + (size_t)(l + 1) * C_MOL * (H_HEADS * C_MOL), WtM,
                    mol_asrc + (size_t)(l + 1) * H_HEADS * C_MOL,
                    mol_adst + (size_t)(l + 1) * H_HEADS * C_MOL,
                    wsrcM + (size_t)(l + 1) * H_HEADS * C_MOL,
                    wdstM + (size_t)(l + 1) * H_HEADS * C_MOL, C_MOL, C_MOL, (size_t)C_MOL,
                    3 * C_MOL);
                transfold<<<dim3(C_PROT / 32, C_PROT / 32, H_HEADS), 256, 0, stream>>>(
                    prot_W + (size_t)(l + 1) * C_PROT * (H_HEADS * C_PROT), WtP,
                    prot_asrc + (size_t)(l + 1) * H_HEADS * C_PROT,
                    prot_adst + (size_t)(l + 1) * H_HEADS * C_PROT,
                    wsrcP + (size_t)(l + 1) * H_HEADS * C_PROT,
                    wdstP + (size_t)(l + 1) * H_HEADS * C_PROT, C_PROT, C_PROT, (size_t)C_PROT,
                    3 * C_PROT);
                ln_kernel<C_MOL, 1><<<N_MOL, C_MOL / 4, 0, stream>>>(
                    x_mol, mol_bias + (size_t)l * C_MOL, mol_lng + (size_t)l * C_MOL,
                    mol_lnb + (size_t)l * C_MOL, wsrcM + (size_t)(l + 1) * H_HEADS * C_MOL,
                    wdstM + (size_t)(l + 1) * H_HEADS * C_MOL, alsM, aldM);
                ln_kernel<C_PROT, 1><<<N_PROT, C_PROT / 4, 0, stream>>>(
                    x_prot, prot_bias + (size_t)l * C_PROT, prot_lng + (size_t)l * C_PROT,
                    prot_lnb + (size_t)l * C_PROT, wsrcP + (size_t)(l + 1) * H_HEADS * C_PROT,
                    wdstP + (size_t)(l + 1) * H_HEADS * C_PROT, alsP, aldP);
            } else {
                ln_kernel<C_MOL, 0><<<N_MOL, C_MOL / 4, 0, stream>>>(
                    x_mol, mol_bias + (size_t)l * C_MOL, mol_lng + (size_t)l * C_MOL,
                    mol_lnb + (size_t)l * C_MOL, nullptr, nullptr, nullptr, nullptr);
                ln_kernel<C_PROT, 0><<<N_PROT, C_PROT / 4, 0, stream>>>(
                    x_prot, prot_bias + (size_t)l * C_PROT, prot_lng + (size_t)l * C_PROT,
                    prot_lnb + (size_t)l * C_PROT, nullptr, nullptr, nullptr, nullptr);
            }
            pool_atomic<C_MOL, 8><<<dim3(G_MOL, 8), C_MOL / 4, 0, stream>>>(x_mol, mol_goff,
                                                                            out_mol, l + 1);
            pool_atomic<C_PROT, 64><<<dim3(G_PROT, 64), C_PROT / 4, 0, stream>>>(
                x_prot, prot_goff, out_prot, l + 1);
        } else {
            // fallback: aliased agg buffer -> mol chain fully, then prot chain
            agg_mol_f<<<N_MOL / 4, 256, 0, stream>>>(x_mol, alsM, aldM, mol_indptr, mol_srcl, aggM);
            gemm128d<<<gMol, 256, 0, stream>>>(
                aggM, WtM, x_mol, C_MOL, 3 * C_MOL, C_MOL / 128, N_MOL, gMol,
                aggM, WtM, x_mol, C_MOL, 3 * C_MOL, C_MOL / 128, N_MOL);
            if (!last)
                transfold<<<dim3(C_MOL / 32, C_MOL / 32, H_HEADS), 256, 0, stream>>>(
                    mol_W + (size_t)(l + 1) * C_MOL * (H_HEADS * C_MOL), WtM,
                    mol_asrc + (size_t)(l + 1) * H_HEADS * C_MOL,
                    mol_adst + (size_t)(l + 1) * H_HEADS * C_MOL,
                    wsrcM + (size_t)(l + 1) * H_HEADS * C_MOL,
                    wdstM + (size_t)(l + 1) * H_HEADS * C_MOL, C_MOL, C_MOL, (size_t)C_MOL,
                    3 * C_MOL);
            if (last)
                ln_kernel<C_MOL, 0><<<N_MOL, C_MOL / 4, 0, stream>>>(
                    x_mol, mol_bias + (size_t)l * C_MOL, mol_lng + (size_t)l * C_MOL,
                    mol_lnb + (size_t)l * C_MOL, nullptr, nullptr, nullptr, nullptr);
            else
                ln_kernel<C_MOL, 1><<<N_MOL, C_MOL / 4, 0, stream>>>(
                    x_mol, mol_bias + (size_t)l * C_MOL, mol_lng + (size_t)l * C_MOL,
                    mol_lnb + (size_t)l * C_MOL, wsrcM + (size_t)(l + 1) * H_HEADS * C_MOL,
                    wdstM + (size_t)(l + 1) * H_HEADS * C_MOL, alsM, aldM);
            pool_atomic<C_MOL, 8><<<dim3(G_MOL, 8), C_MOL / 4, 0, stream>>>(x_mol, mol_goff,
                                                                            out_mol, l + 1);
            agg_prot_f<<<N_PROT, 320, 0, stream>>>(x_prot, alsP, aldP, prot_indptr, prot_srcl,
                                                   aggP);
            gemm128d<<<gProt, 256, 0, stream>>>(
                aggP, WtP, x_prot, C_PROT, 3 * C_PROT, C_PROT / 128, N_PROT, gProt,
                aggP, WtP, x_prot, C_PROT, 3 * C_PROT, C_PROT / 128, N_PROT);
            if (!last)
                transfold<<<dim3(C_PROT / 32, C_PROT / 32, H_HEADS), 256, 0, stream>>>(
                    prot_W + (size_t)(l + 1) * C_PROT * (H_HEADS * C_PROT), WtP,
                    prot_asrc + (size_t)(l + 1) * H_HEADS * C_PROT,
                    prot_adst + (size_t)(l + 1) * H_HEADS * C_PROT,
                    wsrcP + (size_t)(l + 1) * H_HEADS * C_PROT,
                    wdstP + (size_t)(l + 1) * H_HEADS * C_PROT, C_PROT, C_PROT, (size_t)C_PROT,
                    3 * C_PROT);
            if (last)
                ln_kernel<C_PROT, 0><<<N_PROT, C_PROT / 4, 0, stream>>>(
                    x_prot, prot_bias + (size_t)l * C_PROT, prot_lng + (size_t)l * C_PROT,
                    prot_lnb + (size_t)l * C_PROT, nullptr, nullptr, nullptr, nullptr);
            else
                ln_kernel<C_PROT, 1><<<N_PROT, C_PROT / 4, 0, stream>>>(
                    x_prot, prot_bias + (size_t)l * C_PROT, prot_lng + (size_t)l * C_PROT,
                    prot_lnb + (size_t)l * C_PROT, wsrcP + (size_t)(l + 1) * H_HEADS * C_PROT,
                    wdstP + (size_t)(l + 1) * H_HEADS * C_PROT, alsP, aldP);
            pool_atomic<C_PROT, 64><<<dim3(G_PROT, 64), C_PROT / 4, 0, stream>>>(
                x_prot, prot_goff, out_prot, l + 1);
        }
    }
}